// Round 5
// baseline (508.673 us; speedup 1.0000x reference)
//
#include <hip/hip_runtime.h>
#include <hip/hip_bf16.h>
#include <float.h>

// Problem constants
#define Bz   4
#define Nn   384
#define Dd   256
#define Hh   4
#define DHh  64
#define HIDn 64
#define NSQ  (384*384)
#define NEG_MAX (-3.40282346638528859812e+38f)

typedef __attribute__((ext_vector_type(8))) short short8;
typedef __attribute__((ext_vector_type(4))) float f32x4;

__device__ __forceinline__ float gelu_f(float x){
  return 0.5f * x * (1.0f + erff(x * 0.70710678118654752f));
}
__device__ __forceinline__ float wsum(float v){
  #pragma unroll
  for (int o = 32; o > 0; o >>= 1) v += __shfl_xor(v, o, 64);
  return v;
}
__device__ __forceinline__ float wmax(float v){
  #pragma unroll
  for (int o = 32; o > 0; o >>= 1) v = fmaxf(v, __shfl_xor(v, o, 64));
  return v;
}
__device__ __forceinline__ float4 ld4(const float* p){ return *(const float4*)p; }

// fp32 -> bf16 (RNE, finite inputs)
__device__ __forceinline__ unsigned short f2bfu(float f){
  union { float f; unsigned u; } v; v.f = f;
  unsigned r = v.u + 0x7FFFu + ((v.u >> 16) & 1u);
  return (unsigned short)(r >> 16);
}
__device__ __forceinline__ short f2bf(float f){ return (short)f2bfu(f); }

// ---------------------------------------------------------------------------
// prep:
//  dc  [row][c] = E_deg[deg[row]][c] + E_cell[cell[row]][c]        (j-side)
//  dcb [row][c] = dc[row][c] + b2[c]                               (i-side)
//  w2bf[c][k]   = bf16(W2[c][k])                                   (A-frags)
//  w1p [k][8]   = {W1[k][0..5], b1[k], 0}
// ---------------------------------------------------------------------------
__global__ __launch_bounds__(256) void prep_kernel(
    const int* __restrict__ dgk, const int* __restrict__ ctk,
    const float* __restrict__ Edg, const float* __restrict__ Ec,
    const float* __restrict__ b2,
    const float* __restrict__ W1, const float* __restrict__ b1,
    const float* __restrict__ W2,
    float* __restrict__ dc, float* __restrict__ dcb,
    float* __restrict__ w1p, unsigned short* __restrict__ w2bf)
{
  const int idx = blockIdx.x * 256 + threadIdx.x;
  if (idx < Bz * Nn * 16) {
    const int row = idx >> 4;
    const int q   = (idx & 15) << 2;
    const float4 a = ld4(Edg + (dgk[row] << 6) + q);
    const float4 b = ld4(Ec  + (ctk[row] << 6) + q);
    float4 o; o.x = a.x + b.x; o.y = a.y + b.y; o.z = a.z + b.z; o.w = a.w + b.w;
    *(float4*)(dc + ((size_t)row << 6) + q) = o;
    const float4 bb4 = ld4(b2 + q);
    float4 o2; o2.x = o.x + bb4.x; o2.y = o.y + bb4.y;
    o2.z = o.z + bb4.z; o2.w = o.w + bb4.w;
    *(float4*)(dcb + ((size_t)row << 6) + q) = o2;
  } else if (idx < Bz * Nn * 16 + 2048) {
    const int t = idx - Bz * Nn * 16;
    const int c = t >> 5, k2 = (t & 31) << 1;
    w2bf[c * 64 + k2]     = f2bfu(W2[c * 64 + k2]);
    w2bf[c * 64 + k2 + 1] = f2bfu(W2[c * 64 + k2 + 1]);
  } else if (idx < Bz * Nn * 16 + 2048 + 64) {
    const int k = idx - (Bz * Nn * 16 + 2048);
    #pragma unroll
    for (int d = 0; d < 6; ++d) w1p[k * 8 + d] = W1[k * 6 + d];
    w1p[k * 8 + 6] = b1[k];
    w1p[k * 8 + 7] = 0.f;
  }
}

// ---------------------------------------------------------------------------
// Fused pair kernel v5 (MFMA): wave = 16 pairs (same b,i row).
//   pr^T (64ch x 16pair) = W2 @ H1^T via 4 m-tiles x 2 k-steps of
//   mfma_f32_16x16x32_bf16, with the embedding sum gathered directly into
//   the C operand at D-layout positions (ch = mt*16+lg*4+r, pair = l15).
//   Lane computes its own B-frag h1 values (k = ks*32+lg*8+j, pair = l15).
//   LN over channels = 2 shuffles (xor16/32); head-dot same; lane stores
//   head lg of pair l15 (coalesced).  No LDS, no barriers, ~100 VGPR.
// ---------------------------------------------------------------------------
__global__ __launch_bounds__(256, 4) void pair_kernel(
    const float* __restrict__ cont, const int* __restrict__ pm,
    const int* __restrict__ dbk, const int* __restrict__ drk,
    const int* __restrict__ rpk, const int* __restrict__ hdk,
    const int* __restrict__ etk, const int* __restrict__ spk,
    const int* __restrict__ sck,
    const float* __restrict__ w1p, const unsigned short* __restrict__ w2bf,
    const float* __restrict__ Ed, const float* __restrict__ Edi,
    const float* __restrict__ Er, const float* __restrict__ Eh,
    const float* __restrict__ Ee, const float* __restrict__ Esp,
    const float* __restrict__ Es,
    const float* __restrict__ lng, const float* __restrict__ lnb,
    const float* __restrict__ bW, const float* __restrict__ bb,
    const float* __restrict__ dc, const float* __restrict__ dcb,
    float* __restrict__ biasOut)
{
  const int tid  = threadIdx.x;
  const int lane = tid & 63;
  const int l15  = lane & 15, lg = lane >> 4;
  const int wid  = blockIdx.x * 4 + (tid >> 6);              // [0, 36864)
  const int rowU = __builtin_amdgcn_readfirstlane(wid / 24); // b*N+i
  const int jb   = wid - rowU * 24;
  const int b    = rowU / Nn;
  const int i    = rowU - b * Nn;
  const int j    = jb * 16 + l15;                            // lane's pair
  const size_t p = (size_t)rowU * Nn + j;
  const int colOff = lg << 2;                                // channel sub-base

  // per-pair indices (4-way dup across lg; L1 broadcast)
  const int xdb = dbk[p] << 6, xdr = drk[p] << 6, xrp = rpk[p] << 6;
  const int xhd = hdk[p] << 6, xet = etk[p] << 6, xsp = spk[p] << 6;
  const int xsc = sck[p] << 6;
  const int mkI = pm[p];
  const float* dcjp = dc  + ((size_t)(b * Nn + j) << 6);
  const float* dcbp = dcb + ((size_t)rowU << 6);

  // gather embedding sums straight into MFMA C operand
  f32x4 acc[4];
  #pragma unroll
  for (int mt = 0; mt < 4; ++mt) {
    const int c0 = (mt << 4) + colOff;
    float4 a = ld4(dcbp + c0);          // i-side degcell + b2
    float4 t;
    t = ld4(dcjp + c0);      a.x += t.x; a.y += t.y; a.z += t.z; a.w += t.w;
    t = ld4(Ed  + xdb + c0); a.x += t.x; a.y += t.y; a.z += t.z; a.w += t.w;
    t = ld4(Edi + xdr + c0); a.x += t.x; a.y += t.y; a.z += t.z; a.w += t.w;
    t = ld4(Er  + xrp + c0); a.x += t.x; a.y += t.y; a.z += t.z; a.w += t.w;
    t = ld4(Eh  + xhd + c0); a.x += t.x; a.y += t.y; a.z += t.z; a.w += t.w;
    t = ld4(Ee  + xet + c0); a.x += t.x; a.y += t.y; a.z += t.z; a.w += t.w;
    t = ld4(Esp + xsp + c0); a.x += t.x; a.y += t.y; a.z += t.z; a.w += t.w;
    t = ld4(Es  + xsc + c0); a.x += t.x; a.y += t.y; a.z += t.z; a.w += t.w;
    acc[mt][0] = a.x; acc[mt][1] = a.y; acc[mt][2] = a.z; acc[mt][3] = a.w;
  }

  // continuous features of lane's pair (8B-aligned float2 loads)
  const float* cp = cont + p * 6;
  const float2 fA = *(const float2*)cp;
  const float2 fB = *(const float2*)(cp + 2);
  const float2 fC = *(const float2*)(cp + 4);

  // B-fragments: h1[pair l15][k], k = ks*32 + lg*8 + j
  short8 bfr0, bfr1;
  #pragma unroll
  for (int jj = 0; jj < 8; ++jj) {
    {
      const int k = (lg << 3) + jj;
      const float4 wa = ld4(w1p + k * 8);
      const float4 wb = ld4(w1p + k * 8 + 4);
      float s = wb.z;
      s = fmaf(wa.x, fA.x, s); s = fmaf(wa.y, fA.y, s);
      s = fmaf(wa.z, fB.x, s); s = fmaf(wa.w, fB.y, s);
      s = fmaf(wb.x, fC.x, s); s = fmaf(wb.y, fC.y, s);
      bfr0[jj] = f2bf(gelu_f(s));
    }
    {
      const int k = 32 + (lg << 3) + jj;
      const float4 wa = ld4(w1p + k * 8);
      const float4 wb = ld4(w1p + k * 8 + 4);
      float s = wb.z;
      s = fmaf(wa.x, fA.x, s); s = fmaf(wa.y, fA.y, s);
      s = fmaf(wa.z, fB.x, s); s = fmaf(wa.w, fB.y, s);
      s = fmaf(wb.x, fC.x, s); s = fmaf(wb.y, fC.y, s);
      bfr1[jj] = f2bf(gelu_f(s));
    }
  }

  // pr^T tile = W2 @ H1^T + esum  (A row = channel mt*16+l15)
  #pragma unroll
  for (int mt = 0; mt < 4; ++mt) {
    const unsigned short* wrow = w2bf + (size_t)((mt << 4) + l15) * 64;
    const short8 a0 = *(const short8*)(wrow + (lg << 3));
    const short8 a1 = *(const short8*)(wrow + 32 + (lg << 3));
    acc[mt] = __builtin_amdgcn_mfma_f32_16x16x32_bf16(a0, bfr0, acc[mt], 0, 0, 0);
    acc[mt] = __builtin_amdgcn_mfma_f32_16x16x32_bf16(a1, bfr1, acc[mt], 0, 0, 0);
  }

  // LN stats: pair's 64 channels live on 4 lanes (same l15, lg varies)
  float sum = 0.f, sq = 0.f;
  #pragma unroll
  for (int mt = 0; mt < 4; ++mt)
    #pragma unroll
    for (int r = 0; r < 4; ++r) {
      const float v = acc[mt][r];
      sum += v; sq = fmaf(v, v, sq);
    }
  sum += __shfl_xor(sum, 16, 64); sum += __shfl_xor(sum, 32, 64);
  sq  += __shfl_xor(sq,  16, 64); sq  += __shfl_xor(sq,  32, 64);
  const float mean = sum * (1.f / 64.f);
  const float var  = sq * (1.f / 64.f) - mean * mean;
  const float inv  = rsqrtf(var + 1e-5f);

  // gelu(LN) -> 4-head partial dots over own 16 channels
  float bh0 = 0.f, bh1 = 0.f, bh2 = 0.f, bh3 = 0.f;
  #pragma unroll
  for (int mt = 0; mt < 4; ++mt) {
    const int c0 = (mt << 4) + colOff;
    const float4 g4 = ld4(lng + c0);
    const float4 b4 = ld4(lnb + c0);
    const float4 w0 = ld4(bW + c0);
    const float4 w1_ = ld4(bW + 64 + c0);
    const float4 w2_ = ld4(bW + 128 + c0);
    const float4 w3_ = ld4(bW + 192 + c0);
    float g;
    g = gelu_f((acc[mt][0] - mean) * inv * g4.x + b4.x);
    bh0 = fmaf(w0.x, g, bh0); bh1 = fmaf(w1_.x, g, bh1);
    bh2 = fmaf(w2_.x, g, bh2); bh3 = fmaf(w3_.x, g, bh3);
    g = gelu_f((acc[mt][1] - mean) * inv * g4.y + b4.y);
    bh0 = fmaf(w0.y, g, bh0); bh1 = fmaf(w1_.y, g, bh1);
    bh2 = fmaf(w2_.y, g, bh2); bh3 = fmaf(w3_.y, g, bh3);
    g = gelu_f((acc[mt][2] - mean) * inv * g4.z + b4.z);
    bh0 = fmaf(w0.z, g, bh0); bh1 = fmaf(w1_.z, g, bh1);
    bh2 = fmaf(w2_.z, g, bh2); bh3 = fmaf(w3_.z, g, bh3);
    g = gelu_f((acc[mt][3] - mean) * inv * g4.w + b4.w);
    bh0 = fmaf(w0.w, g, bh0); bh1 = fmaf(w1_.w, g, bh1);
    bh2 = fmaf(w2_.w, g, bh2); bh3 = fmaf(w3_.w, g, bh3);
  }
  bh0 += __shfl_xor(bh0, 16, 64); bh0 += __shfl_xor(bh0, 32, 64);
  bh1 += __shfl_xor(bh1, 16, 64); bh1 += __shfl_xor(bh1, 32, 64);
  bh2 += __shfl_xor(bh2, 16, 64); bh2 += __shfl_xor(bh2, 32, 64);
  bh3 += __shfl_xor(bh3, 16, 64); bh3 += __shfl_xor(bh3, 32, 64);

  const float mk = mkI ? 1.f : 0.f;
  const float bh = (lg == 0) ? bh0 + bb[0] : (lg == 1) ? bh1 + bb[1]
                 : (lg == 2) ? bh2 + bb[2] : bh3 + bb[3];
  biasOut[(size_t)b * (Hh * NSQ) + (size_t)lg * NSQ + (size_t)i * Nn + j] = bh * mk;
}

// ---------------------------------------------------------------------------
// LayerNorm over last dim (256). One wave per row, 4 rows per block.
// ---------------------------------------------------------------------------
__global__ __launch_bounds__(256) void ln_kernel(
    const float* __restrict__ x, const float* __restrict__ g,
    const float* __restrict__ bta, float* __restrict__ o)
{
  const int row  = blockIdx.x * 4 + (threadIdx.x >> 6);
  const int lane = threadIdx.x & 63;
  const float4 v = *(const float4*)(x + (size_t)row * Dd + lane * 4);
  float s = v.x + v.y + v.z + v.w;
  s = wsum(s);
  const float m = s * (1.f / 256.f);
  const float dx = v.x - m, dy = v.y - m, dz = v.z - m, dw = v.w - m;
  float q = dx*dx + dy*dy + dz*dz + dw*dw;
  q = wsum(q);
  const float inv = rsqrtf(q * (1.f / 256.f) + 1e-5f);
  const int d = lane * 4;
  const float4 gg = *(const float4*)(g + d);
  const float4 bb = *(const float4*)(bta + d);
  float4 out;
  out.x = dx * inv * gg.x + bb.x;
  out.y = dy * inv * gg.y + bb.y;
  out.z = dz * inv * gg.z + bb.z;
  out.w = dw * inv * gg.w + bb.w;
  *(float4*)(o + (size_t)row * Dd + d) = out;
}

// ---------------------------------------------------------------------------
// bf16 MFMA GEMM (no LDS). Wave computes 16(M) x 64(N); block = 4 waves = 64x64.
// MODE 0: C = A @ B^T (+bias)(+res)          grid (Nc/64, M/64)
// MODE 1: QK^T*scale + biasT, safe-mask      grid (6, 6, B*H)
// MODE 2: C = A @ B  (B natural KxN, PV)     grid (1, 6, B*H)
// ---------------------------------------------------------------------------
template<int MODE>
__global__ __launch_bounds__(256) void gemm_mfma(
    const float* __restrict__ A, int lda,
    const float* __restrict__ Bm, int ldb,
    float* __restrict__ Cc, int ldc,
    const float* __restrict__ bias,
    const float* __restrict__ res, int ldr,
    int K,
    const float* __restrict__ biasT, const int* __restrict__ pmask,
    const int* __restrict__ valid)
{
  const int tid = threadIdx.x;
  const int lane = tid & 63;
  const int w   = tid >> 6;
  const int l15 = lane & 15, lg = lane >> 4;
  const int m0 = blockIdx.y * 64 + w * 16;
  const int n0 = blockIdx.x * 64;

  const float* Ab = A; const float* Bb = Bm; float* Cb = Cc;
  const float* biasTb = biasT; const int* pmb = pmask; const int* vlb = valid;
  if (MODE != 0) {
    const int bz = blockIdx.z;
    const int b = bz >> 2, h = bz & 3;
    if (MODE == 1) {
      Ab = A  + (size_t)b * Nn * Dd + h * DHh;
      Bb = Bm + (size_t)b * Nn * Dd + h * DHh;
      Cb = Cc + (size_t)bz * NSQ;
      biasTb = biasT + (size_t)bz * NSQ;
      pmb = pmask + (size_t)b * NSQ;
      vlb = valid + b * Nn;
    } else {
      Ab = A  + (size_t)bz * NSQ;
      Bb = Bm + (size_t)b * Nn * Dd + h * DHh;
      Cb = Cc + (size_t)b * Nn * Dd + h * DHh;
    }
  }

  f32x4 acc[4] = {};
  const float* pa = Ab + (size_t)(m0 + l15) * lda + lg * 8;

  for (int k0 = 0; k0 < K; k0 += 32) {
    short8 af;
    {
      const float4 a0 = ld4(pa + k0);
      const float4 a1 = ld4(pa + k0 + 4);
      af[0] = f2bf(a0.x); af[1] = f2bf(a0.y); af[2] = f2bf(a0.z); af[3] = f2bf(a0.w);
      af[4] = f2bf(a1.x); af[5] = f2bf(a1.y); af[6] = f2bf(a1.z); af[7] = f2bf(a1.w);
    }
    #pragma unroll
    for (int nt = 0; nt < 4; ++nt) {
      short8 bf;
      if (MODE != 2) {
        const float* pb = Bb + (size_t)(n0 + nt * 16 + l15) * ldb + k0 + lg * 8;
        const float4 b0 = ld4(pb);
        const float4 b1 = ld4(pb + 4);
        bf[0] = f2bf(b0.x); bf[1] = f2bf(b0.y); bf[2] = f2bf(b0.z); bf[3] = f2bf(b0.w);
        bf[4] = f2bf(b1.x); bf[5] = f2bf(b1.y); bf[6] = f2bf(b1.z); bf[7] = f2bf(b1.w);
      } else {
        const float* pb = Bb + (size_t)(k0 + lg * 8) * ldb + n0 + nt * 16 + l15;
        #pragma unroll
        for (int jj = 0; jj < 8; ++jj) bf[jj] = f2bf(pb[(size_t)jj * ldb]);
      }
      acc[nt] = __builtin_amdgcn_mfma_f32_16x16x32_bf16(af, bf, acc[nt], 0, 0, 0);
    }
  }

  #pragma unroll
  for (int nt = 0; nt < 4; ++nt) {
    #pragma unroll
    for (int r = 0; r < 4; ++r) {
      const int m = m0 + lg * 4 + r;
      const int n = n0 + nt * 16 + l15;
      float v = acc[nt][r];
      if (MODE == 0) {
        if (bias) v += bias[n];
        if (res)  v += res[(size_t)m * ldr + n];
        Cb[(size_t)m * ldc + n] = v;
      } else if (MODE == 1) {
        v = v * 0.125f + biasTb[(size_t)m * Nn + n];
        const bool safe = (pmb[(size_t)m * Nn + n] != 0) || (vlb[m] == 0 && m == n);
        Cb[(size_t)m * Nn + n] = safe ? v : NEG_MAX;
      } else {
        Cb[(size_t)m * ldc + n] = v;
      }
    }
  }
}

// ---------------------------------------------------------------------------
// Softmax + pair_mask re-mask + renormalize, in place. Wave per row (384).
// ---------------------------------------------------------------------------
__global__ __launch_bounds__(256) void softmax_kernel(
    float* __restrict__ att, const int* __restrict__ pm)
{
  const int row  = blockIdx.x * 4 + (threadIdx.x >> 6);   // [0, B*H*N)
  const int lane = threadIdx.x & 63;
  const int i  = row % Nn;
  const int bh = row / Nn;
  const int b  = bh / Hh;
  float* ar = att + (size_t)row * Nn;
  const int* pmr = pm + (size_t)b * NSQ + (size_t)i * Nn;

  float v[6];
  float mx = NEG_MAX;
  #pragma unroll
  for (int t = 0; t < 6; ++t) { v[t] = ar[lane + t * 64]; mx = fmaxf(mx, v[t]); }
  mx = wmax(mx);
  float s = 0.f;
  #pragma unroll
  for (int t = 0; t < 6; ++t) { v[t] = expf(v[t] - mx); s += v[t]; }
  s = wsum(s);
  const float invs = 1.f / s;
  float s2 = 0.f;
  #pragma unroll
  for (int t = 0; t < 6; ++t) {
    const float pv = (float)pmr[lane + t * 64];
    v[t] = v[t] * invs * pv;
    s2 += v[t];
  }
  s2 = wsum(s2);
  const float r = 1.f / fmaxf(s2, 1e-6f);
  #pragma unroll
  for (int t = 0; t < 6; ++t) ar[lane + t * 64] = v[t] * r;
}

// ---------------------------------------------------------------------------
// ag = a * gelu(g): h (M,1024) -> ag (M,512)
// ---------------------------------------------------------------------------
__global__ __launch_bounds__(256) void gate_kernel(
    const float* __restrict__ hff, float* __restrict__ ag)
{
  const int idx = blockIdx.x * 256 + threadIdx.x;   // over 1536*512/4
  if (idx >= 1536 * 128) return;
  const int m  = idx / 128;
  const int dq = idx - m * 128;
  const float4 a = *(const float4*)(hff + (size_t)m * 1024 + dq * 4);
  const float4 g = *(const float4*)(hff + (size_t)m * 1024 + 512 + dq * 4);
  float4 o;
  o.x = a.x * gelu_f(g.x); o.y = a.y * gelu_f(g.y);
  o.z = a.z * gelu_f(g.z); o.w = a.w * gelu_f(g.w);
  *(float4*)(ag + (size_t)m * 512 + dq * 4) = o;
}

// ---------------------------------------------------------------------------
extern "C" void kernel_launch(void* const* d_in, const int* in_sizes, int n_in,
                              void* d_out, int out_size, void* d_ws, size_t ws_size,
                              hipStream_t stream) {
  const float* x    = (const float*)d_in[0];
  const int*   pm   = (const int*)  d_in[1];
  const int*   vld  = (const int*)  d_in[2];
  const float* cont = (const float*)d_in[3];
  const int* dbk = (const int*)d_in[4];
  const int* drk = (const int*)d_in[5];
  const int* rpk = (const int*)d_in[6];
  const int* hdk = (const int*)d_in[7];
  const int* etk = (const int*)d_in[8];
  const int* spk = (const int*)d_in[9];
  const int* sck = (const int*)d_in[10];
  const int* dgk = (const int*)d_in[11];
  const int* ctk = (const int*)d_in[12];
  const float* Wq  = (const float*)d_in[13];
  const float* Wk  = (const float*)d_in[14];
  const float* Wv  = (const float*)d_in[15];
  const float* Wo  = (const float*)d_in[16];
  const float* bo  = (const float*)d_in[17];
  const float* cmW1 = (const float*)d_in[18];
  const float* cmb1 = (const float*)d_in[19];
  const float* cmW2 = (const float*)d_in[20];
  const float* cmb2 = (const float*)d_in[21];
  const float* Ed  = (const float*)d_in[22];
  const float* Edi = (const float*)d_in[23];
  const float* Er  = (const float*)d_in[24];
  const float* Eh  = (const float*)d_in[25];
  const float* Ee  = (const float*)d_in[26];
  const float* Esp = (const float*)d_in[27];
  const float* Edg = (const float*)d_in[28];
  const float* Ec  = (const float*)d_in[29];
  const float* Es  = (const float*)d_in[30];
  const float* blng = (const float*)d_in[31];
  const float* blnb = (const float*)d_in[32];
  const float* bW   = (const float*)d_in[33];
  const float* bb_  = (const float*)d_in[34];
  const float* ln1g = (const float*)d_in[35];
  const float* ln1b = (const float*)d_in[36];
  const float* ln2g = (const float*)d_in[37];
  const float* ln2b = (const float*)d_in[38];
  const float* ffW1 = (const float*)d_in[39];
  const float* ffb1 = (const float*)d_in[40];
  const float* ffW2 = (const float*)d_in[41];
  const float* ffb2 = (const float*)d_in[42];

  float* out   = (float*)d_out;
  float* xout  = out;                       // 393216
  float* attn  = out + 393216;              // 2359296 (logits in place)
  float* biasO = out + 393216 + 2359296;    // 2359296

  float* ws  = (float*)d_ws;
  float* xn  = ws;                 // 393216  (ln1 out; reused for ln2 out)
  float* qb  = ws + 393216;        // 393216
  float* kb  = ws + 786432;        // 393216
  float* vb  = ws + 1179648;       // 393216
  float* ao  = ws + 1572864;       // 393216
  float* x1  = ws + 1966080;       // 393216
  float* hff = ws + 2359296;       // 1572864
  float* ag  = qb;                 // reuse q+k region (dead after QK)
  // pair-path scratch (in hff region; dead before FF1 writes hff)
  float* dc   = hff;               // 98304
  float* dcb  = hff + 98304;       // 98304
  float* w1p  = hff + 196608;      // 512
  unsigned short* w2bf = (unsigned short*)(hff + 197120);   // 4096 ushort

  // 0) prep: degcell(+b2) merge, W2->bf16, W1 pack
  prep_kernel<<<105, 256, 0, stream>>>(dgk, ctk, Edg, Ec, cmb2, cmW1, cmb1,
      cmW2, dc, dcb, w1p, w2bf);
  // 1) pair bias (MFMA)
  pair_kernel<<<9216, 256, 0, stream>>>(cont, pm, dbk, drk, rpk, hdk, etk, spk,
      sck, w1p, w2bf, Ed, Edi, Er, Eh, Ee, Esp, Es,
      blng, blnb, bW, bb_, dc, dcb, biasO);
  // 2) ln1
  ln_kernel<<<384, 256, 0, stream>>>(x, ln1g, ln1b, xn);
  // 3) q, k, v projections
  gemm_mfma<0><<<dim3(4, 24), 256, 0, stream>>>(xn, 256, Wq, 256, qb, 256,
      nullptr, nullptr, 0, 256, nullptr, nullptr, nullptr);
  gemm_mfma<0><<<dim3(4, 24), 256, 0, stream>>>(xn, 256, Wk, 256, kb, 256,
      nullptr, nullptr, 0, 256, nullptr, nullptr, nullptr);
  gemm_mfma<0><<<dim3(4, 24), 256, 0, stream>>>(xn, 256, Wv, 256, vb, 256,
      nullptr, nullptr, 0, 256, nullptr, nullptr, nullptr);
  // 4) logits = qk^T*scale + bias, safe-masked -> attn region
  gemm_mfma<1><<<dim3(6, 6, 16), 256, 0, stream>>>(qb, 256, kb, 256, attn, 384,
      nullptr, nullptr, 0, 64, biasO, pm, vld);
  // 5) softmax + mask + renorm (in place)
  softmax_kernel<<<1536, 256, 0, stream>>>(attn, pm);
  // 6) PV
  gemm_mfma<2><<<dim3(1, 6, 16), 256, 0, stream>>>(attn, 384, vb, 256, ao, 256,
      nullptr, nullptr, 0, 384, nullptr, nullptr, nullptr);
  // 7) Wo + bo + residual(x) -> x1
  gemm_mfma<0><<<dim3(4, 24), 256, 0, stream>>>(ao, 256, Wo, 256, x1, 256,
      bo, x, 256, 256, nullptr, nullptr, nullptr);
  // 8) ln2 -> xn (reuse)
  ln_kernel<<<384, 256, 0, stream>>>(x1, ln2g, ln2b, xn);
  // 9) FF1
  gemm_mfma<0><<<dim3(16, 24), 256, 0, stream>>>(xn, 256, ffW1, 256, hff, 1024,
      ffb1, nullptr, 0, 256, nullptr, nullptr, nullptr);
  // 10) gate: ag = a * gelu(g)
  gate_kernel<<<768, 256, 0, stream>>>(hff, ag);
  // 11) FF2 + ffb2 + residual(x1) -> x_out
  gemm_mfma<0><<<dim3(4, 24), 256, 0, stream>>>(ag, 512, ffW2, 512, xout, 256,
      ffb2, x1, 256, 512, nullptr, nullptr, nullptr);
}

// Round 6
// 397.136 us; speedup vs baseline: 1.2809x; 1.2809x over previous
//
#include <hip/hip_runtime.h>
#include <hip/hip_bf16.h>
#include <float.h>

// Problem constants
#define Bz   4
#define Nn   384
#define Dd   256
#define Hh   4
#define DHh  64
#define HIDn 64
#define NSQ  (384*384)
#define NEG_MAX (-3.40282346638528859812e+38f)

typedef __attribute__((ext_vector_type(8))) short short8;
typedef __attribute__((ext_vector_type(4))) float f32x4;

__device__ __forceinline__ float gelu_f(float x){
  return 0.5f * x * (1.0f + erff(x * 0.70710678118654752f));
}
__device__ __forceinline__ float wsum(float v){
  #pragma unroll
  for (int o = 32; o > 0; o >>= 1) v += __shfl_xor(v, o, 64);
  return v;
}
__device__ __forceinline__ float wmax(float v){
  #pragma unroll
  for (int o = 32; o > 0; o >>= 1) v = fmaxf(v, __shfl_xor(v, o, 64));
  return v;
}
__device__ __forceinline__ float4 ld4(const float* p){ return *(const float4*)p; }

// fp32 -> bf16 (RNE, finite inputs)
__device__ __forceinline__ unsigned short f2bfu(float f){
  union { float f; unsigned u; } v; v.f = f;
  unsigned r = v.u + 0x7FFFu + ((v.u >> 16) & 1u);
  return (unsigned short)(r >> 16);
}
__device__ __forceinline__ short f2bf(float f){ return (short)f2bfu(f); }

// ---------------------------------------------------------------------------
// prep:
//  dc  [row][c] = E_deg[deg[row]][c] + E_cell[cell[row]][c]        (j-side)
//  dcb [row][c] = dc[row][c] + b2[c]                               (i-side)
//  w2bf[c][k]   = bf16(W2[c][k])                                   (A-frags)
//  w1p [k][8]   = {W1[k][0..5], b1[k], 0}
// ---------------------------------------------------------------------------
__global__ __launch_bounds__(256) void prep_kernel(
    const int* __restrict__ dgk, const int* __restrict__ ctk,
    const float* __restrict__ Edg, const float* __restrict__ Ec,
    const float* __restrict__ b2,
    const float* __restrict__ W1, const float* __restrict__ b1,
    const float* __restrict__ W2,
    float* __restrict__ dc, float* __restrict__ dcb,
    float* __restrict__ w1p, unsigned short* __restrict__ w2bf)
{
  const int idx = blockIdx.x * 256 + threadIdx.x;
  if (idx < Bz * Nn * 16) {
    const int row = idx >> 4;
    const int q   = (idx & 15) << 2;
    const float4 a = ld4(Edg + (dgk[row] << 6) + q);
    const float4 b = ld4(Ec  + (ctk[row] << 6) + q);
    float4 o; o.x = a.x + b.x; o.y = a.y + b.y; o.z = a.z + b.z; o.w = a.w + b.w;
    *(float4*)(dc + ((size_t)row << 6) + q) = o;
    const float4 bb4 = ld4(b2 + q);
    float4 o2; o2.x = o.x + bb4.x; o2.y = o.y + bb4.y;
    o2.z = o.z + bb4.z; o2.w = o.w + bb4.w;
    *(float4*)(dcb + ((size_t)row << 6) + q) = o2;
  } else if (idx < Bz * Nn * 16 + 2048) {
    const int t = idx - Bz * Nn * 16;
    const int c = t >> 5, k2 = (t & 31) << 1;
    w2bf[c * 64 + k2]     = f2bfu(W2[c * 64 + k2]);
    w2bf[c * 64 + k2 + 1] = f2bfu(W2[c * 64 + k2 + 1]);
  } else if (idx < Bz * Nn * 16 + 2048 + 64) {
    const int k = idx - (Bz * Nn * 16 + 2048);
    #pragma unroll
    for (int d = 0; d < 6; ++d) w1p[k * 8 + d] = W1[k * 6 + d];
    w1p[k * 8 + 6] = b1[k];
    w1p[k * 8 + 7] = 0.f;
  }
}

// ---------------------------------------------------------------------------
// Fused pair kernel v6 (MFMA, spill-safe ordering): wave = 16 pairs.
//   Phase a: lane computes its 16 h1 values -> bfr0/bfr1 (B-frags).
//   Phase b: acc = W2 @ H1^T via 8 x mfma_f32_16x16x32_bf16 (acc starts 0).
//   Phase c: gather 9 embedding tables, ADD into acc per m-tile (so gather
//            temps never coexist with MFMA A-frag loads).
//   Phase d: LN over channels = 2 shuffles (xor16/32); gelu; 4-head dot;
//            lane stores head lg of pair l15 (coalesced).
//   launch_bounds(256,2): 256-reg unified cap -> no spill.
// ---------------------------------------------------------------------------
__global__ __launch_bounds__(256, 2) void pair_kernel(
    const float* __restrict__ cont, const int* __restrict__ pm,
    const int* __restrict__ dbk, const int* __restrict__ drk,
    const int* __restrict__ rpk, const int* __restrict__ hdk,
    const int* __restrict__ etk, const int* __restrict__ spk,
    const int* __restrict__ sck,
    const float* __restrict__ w1p, const unsigned short* __restrict__ w2bf,
    const float* __restrict__ Ed, const float* __restrict__ Edi,
    const float* __restrict__ Er, const float* __restrict__ Eh,
    const float* __restrict__ Ee, const float* __restrict__ Esp,
    const float* __restrict__ Es,
    const float* __restrict__ lng, const float* __restrict__ lnb,
    const float* __restrict__ bW, const float* __restrict__ bb,
    const float* __restrict__ dc, const float* __restrict__ dcb,
    float* __restrict__ biasOut)
{
  const int tid  = threadIdx.x;
  const int lane = tid & 63;
  const int l15  = lane & 15, lg = lane >> 4;
  const int wid  = blockIdx.x * 4 + (tid >> 6);              // [0, 36864)
  const int rowU = __builtin_amdgcn_readfirstlane(wid / 24); // b*N+i
  const int jb   = wid - rowU * 24;
  const int b    = rowU / Nn;
  const int i    = rowU - b * Nn;
  const int j    = jb * 16 + l15;                            // lane's pair
  const size_t p = (size_t)rowU * Nn + j;
  const int colOff = lg << 2;                                // channel sub-base

  // ---- phase a: B-fragments h1[pair l15][k], k = ks*32 + lg*8 + jj ----
  const float* cp = cont + p * 6;
  const float2 fA = *(const float2*)cp;
  const float2 fB = *(const float2*)(cp + 2);
  const float2 fC = *(const float2*)(cp + 4);

  short8 bfr0, bfr1;
  #pragma unroll
  for (int jj = 0; jj < 8; ++jj) {
    {
      const int k = (lg << 3) + jj;
      const float4 wa = ld4(w1p + k * 8);
      const float4 wb = ld4(w1p + k * 8 + 4);
      float s = wb.z;
      s = fmaf(wa.x, fA.x, s); s = fmaf(wa.y, fA.y, s);
      s = fmaf(wa.z, fB.x, s); s = fmaf(wa.w, fB.y, s);
      s = fmaf(wb.x, fC.x, s); s = fmaf(wb.y, fC.y, s);
      bfr0[jj] = f2bf(gelu_f(s));
    }
    {
      const int k = 32 + (lg << 3) + jj;
      const float4 wa = ld4(w1p + k * 8);
      const float4 wb = ld4(w1p + k * 8 + 4);
      float s = wb.z;
      s = fmaf(wa.x, fA.x, s); s = fmaf(wa.y, fA.y, s);
      s = fmaf(wa.z, fB.x, s); s = fmaf(wa.w, fB.y, s);
      s = fmaf(wb.x, fC.x, s); s = fmaf(wb.y, fC.y, s);
      bfr1[jj] = f2bf(gelu_f(s));
    }
  }

  // ---- phase b: acc = W2 @ H1^T (A row = channel mt*16+l15) ----
  f32x4 acc[4] = {};
  #pragma unroll
  for (int mt = 0; mt < 4; ++mt) {
    const unsigned short* wrow = w2bf + (size_t)((mt << 4) + l15) * 64;
    const short8 a0 = *(const short8*)(wrow + (lg << 3));
    const short8 a1 = *(const short8*)(wrow + 32 + (lg << 3));
    acc[mt] = __builtin_amdgcn_mfma_f32_16x16x32_bf16(a0, bfr0, acc[mt], 0, 0, 0);
    acc[mt] = __builtin_amdgcn_mfma_f32_16x16x32_bf16(a1, bfr1, acc[mt], 0, 0, 0);
  }

  // ---- phase c: embedding gathers added into acc ----
  const int xdb = dbk[p] << 6, xdr = drk[p] << 6, xrp = rpk[p] << 6;
  const int xhd = hdk[p] << 6, xet = etk[p] << 6, xsp = spk[p] << 6;
  const int xsc = sck[p] << 6;
  const float* dcjp = dc  + ((size_t)(b * Nn + j) << 6);
  const float* dcbp = dcb + ((size_t)rowU << 6);

  #pragma unroll
  for (int mt = 0; mt < 4; ++mt) {
    const int c0 = (mt << 4) + colOff;
    float4 a = ld4(dcbp + c0);          // i-side degcell + b2
    float4 t;
    t = ld4(dcjp + c0);      a.x += t.x; a.y += t.y; a.z += t.z; a.w += t.w;
    t = ld4(Ed  + xdb + c0); a.x += t.x; a.y += t.y; a.z += t.z; a.w += t.w;
    t = ld4(Edi + xdr + c0); a.x += t.x; a.y += t.y; a.z += t.z; a.w += t.w;
    t = ld4(Er  + xrp + c0); a.x += t.x; a.y += t.y; a.z += t.z; a.w += t.w;
    t = ld4(Eh  + xhd + c0); a.x += t.x; a.y += t.y; a.z += t.z; a.w += t.w;
    t = ld4(Ee  + xet + c0); a.x += t.x; a.y += t.y; a.z += t.z; a.w += t.w;
    t = ld4(Esp + xsp + c0); a.x += t.x; a.y += t.y; a.z += t.z; a.w += t.w;
    t = ld4(Es  + xsc + c0); a.x += t.x; a.y += t.y; a.z += t.z; a.w += t.w;
    acc[mt][0] += a.x; acc[mt][1] += a.y; acc[mt][2] += a.z; acc[mt][3] += a.w;
  }

  // ---- phase d: LN stats (pair's 64 ch live on 4 lanes: xor16/32) ----
  float sum = 0.f, sq = 0.f;
  #pragma unroll
  for (int mt = 0; mt < 4; ++mt)
    #pragma unroll
    for (int r = 0; r < 4; ++r) {
      const float v = acc[mt][r];
      sum += v; sq = fmaf(v, v, sq);
    }
  sum += __shfl_xor(sum, 16, 64); sum += __shfl_xor(sum, 32, 64);
  sq  += __shfl_xor(sq,  16, 64); sq  += __shfl_xor(sq,  32, 64);
  const float mean = sum * (1.f / 64.f);
  const float var  = sq * (1.f / 64.f) - mean * mean;
  const float inv  = rsqrtf(var + 1e-5f);

  // gelu(LN) -> 4-head partial dots over own 16 channels
  float bh0 = 0.f, bh1 = 0.f, bh2 = 0.f, bh3 = 0.f;
  #pragma unroll
  for (int mt = 0; mt < 4; ++mt) {
    const int c0 = (mt << 4) + colOff;
    const float4 g4 = ld4(lng + c0);
    const float4 b4 = ld4(lnb + c0);
    const float4 w0 = ld4(bW + c0);
    const float4 w1_ = ld4(bW + 64 + c0);
    const float4 w2_ = ld4(bW + 128 + c0);
    const float4 w3_ = ld4(bW + 192 + c0);
    float g;
    g = gelu_f((acc[mt][0] - mean) * inv * g4.x + b4.x);
    bh0 = fmaf(w0.x, g, bh0); bh1 = fmaf(w1_.x, g, bh1);
    bh2 = fmaf(w2_.x, g, bh2); bh3 = fmaf(w3_.x, g, bh3);
    g = gelu_f((acc[mt][1] - mean) * inv * g4.y + b4.y);
    bh0 = fmaf(w0.y, g, bh0); bh1 = fmaf(w1_.y, g, bh1);
    bh2 = fmaf(w2_.y, g, bh2); bh3 = fmaf(w3_.y, g, bh3);
    g = gelu_f((acc[mt][2] - mean) * inv * g4.z + b4.z);
    bh0 = fmaf(w0.z, g, bh0); bh1 = fmaf(w1_.z, g, bh1);
    bh2 = fmaf(w2_.z, g, bh2); bh3 = fmaf(w3_.z, g, bh3);
    g = gelu_f((acc[mt][3] - mean) * inv * g4.w + b4.w);
    bh0 = fmaf(w0.w, g, bh0); bh1 = fmaf(w1_.w, g, bh1);
    bh2 = fmaf(w2_.w, g, bh2); bh3 = fmaf(w3_.w, g, bh3);
  }
  bh0 += __shfl_xor(bh0, 16, 64); bh0 += __shfl_xor(bh0, 32, 64);
  bh1 += __shfl_xor(bh1, 16, 64); bh1 += __shfl_xor(bh1, 32, 64);
  bh2 += __shfl_xor(bh2, 16, 64); bh2 += __shfl_xor(bh2, 32, 64);
  bh3 += __shfl_xor(bh3, 16, 64); bh3 += __shfl_xor(bh3, 32, 64);

  const float mk = pm[p] ? 1.f : 0.f;
  const float bh = (lg == 0) ? bh0 + bb[0] : (lg == 1) ? bh1 + bb[1]
                 : (lg == 2) ? bh2 + bb[2] : bh3 + bb[3];
  biasOut[(size_t)b * (Hh * NSQ) + (size_t)lg * NSQ + (size_t)i * Nn + j] = bh * mk;
}

// ---------------------------------------------------------------------------
// LayerNorm over last dim (256). One wave per row, 4 rows per block.
// ---------------------------------------------------------------------------
__global__ __launch_bounds__(256) void ln_kernel(
    const float* __restrict__ x, const float* __restrict__ g,
    const float* __restrict__ bta, float* __restrict__ o)
{
  const int row  = blockIdx.x * 4 + (threadIdx.x >> 6);
  const int lane = threadIdx.x & 63;
  const float4 v = *(const float4*)(x + (size_t)row * Dd + lane * 4);
  float s = v.x + v.y + v.z + v.w;
  s = wsum(s);
  const float m = s * (1.f / 256.f);
  const float dx = v.x - m, dy = v.y - m, dz = v.z - m, dw = v.w - m;
  float q = dx*dx + dy*dy + dz*dz + dw*dw;
  q = wsum(q);
  const float inv = rsqrtf(q * (1.f / 256.f) + 1e-5f);
  const int d = lane * 4;
  const float4 gg = *(const float4*)(g + d);
  const float4 bb = *(const float4*)(bta + d);
  float4 out;
  out.x = dx * inv * gg.x + bb.x;
  out.y = dy * inv * gg.y + bb.y;
  out.z = dz * inv * gg.z + bb.z;
  out.w = dw * inv * gg.w + bb.w;
  *(float4*)(o + (size_t)row * Dd + d) = out;
}

// ---------------------------------------------------------------------------
// bf16 MFMA GEMM (no LDS). Wave computes 16(M) x 64(N); block = 4 waves = 64x64.
// MODE 0: C = A @ B^T (+bias)(+res)          grid (Nc/64, M/64)
// MODE 1: QK^T*scale + biasT, safe-mask      grid (6, 6, B*H)
// MODE 2: C = A @ B  (B natural KxN, PV)     grid (1, 6, B*H)
// ---------------------------------------------------------------------------
template<int MODE>
__global__ __launch_bounds__(256) void gemm_mfma(
    const float* __restrict__ A, int lda,
    const float* __restrict__ Bm, int ldb,
    float* __restrict__ Cc, int ldc,
    const float* __restrict__ bias,
    const float* __restrict__ res, int ldr,
    int K,
    const float* __restrict__ biasT, const int* __restrict__ pmask,
    const int* __restrict__ valid)
{
  const int tid = threadIdx.x;
  const int lane = tid & 63;
  const int w   = tid >> 6;
  const int l15 = lane & 15, lg = lane >> 4;
  const int m0 = blockIdx.y * 64 + w * 16;
  const int n0 = blockIdx.x * 64;

  const float* Ab = A; const float* Bb = Bm; float* Cb = Cc;
  const float* biasTb = biasT; const int* pmb = pmask; const int* vlb = valid;
  if (MODE != 0) {
    const int bz = blockIdx.z;
    const int b = bz >> 2, h = bz & 3;
    if (MODE == 1) {
      Ab = A  + (size_t)b * Nn * Dd + h * DHh;
      Bb = Bm + (size_t)b * Nn * Dd + h * DHh;
      Cb = Cc + (size_t)bz * NSQ;
      biasTb = biasT + (size_t)bz * NSQ;
      pmb = pmask + (size_t)b * NSQ;
      vlb = valid + b * Nn;
    } else {
      Ab = A  + (size_t)bz * NSQ;
      Bb = Bm + (size_t)b * Nn * Dd + h * DHh;
      Cb = Cc + (size_t)b * Nn * Dd + h * DHh;
    }
  }

  f32x4 acc[4] = {};
  const float* pa = Ab + (size_t)(m0 + l15) * lda + lg * 8;

  for (int k0 = 0; k0 < K; k0 += 32) {
    short8 af;
    {
      const float4 a0 = ld4(pa + k0);
      const float4 a1 = ld4(pa + k0 + 4);
      af[0] = f2bf(a0.x); af[1] = f2bf(a0.y); af[2] = f2bf(a0.z); af[3] = f2bf(a0.w);
      af[4] = f2bf(a1.x); af[5] = f2bf(a1.y); af[6] = f2bf(a1.z); af[7] = f2bf(a1.w);
    }
    #pragma unroll
    for (int nt = 0; nt < 4; ++nt) {
      short8 bf;
      if (MODE != 2) {
        const float* pb = Bb + (size_t)(n0 + nt * 16 + l15) * ldb + k0 + lg * 8;
        const float4 b0 = ld4(pb);
        const float4 b1 = ld4(pb + 4);
        bf[0] = f2bf(b0.x); bf[1] = f2bf(b0.y); bf[2] = f2bf(b0.z); bf[3] = f2bf(b0.w);
        bf[4] = f2bf(b1.x); bf[5] = f2bf(b1.y); bf[6] = f2bf(b1.z); bf[7] = f2bf(b1.w);
      } else {
        const float* pb = Bb + (size_t)(k0 + lg * 8) * ldb + n0 + nt * 16 + l15;
        #pragma unroll
        for (int jj = 0; jj < 8; ++jj) bf[jj] = f2bf(pb[(size_t)jj * ldb]);
      }
      acc[nt] = __builtin_amdgcn_mfma_f32_16x16x32_bf16(af, bf, acc[nt], 0, 0, 0);
    }
  }

  #pragma unroll
  for (int nt = 0; nt < 4; ++nt) {
    #pragma unroll
    for (int r = 0; r < 4; ++r) {
      const int m = m0 + lg * 4 + r;
      const int n = n0 + nt * 16 + l15;
      float v = acc[nt][r];
      if (MODE == 0) {
        if (bias) v += bias[n];
        if (res)  v += res[(size_t)m * ldr + n];
        Cb[(size_t)m * ldc + n] = v;
      } else if (MODE == 1) {
        v = v * 0.125f + biasTb[(size_t)m * Nn + n];
        const bool safe = (pmb[(size_t)m * Nn + n] != 0) || (vlb[m] == 0 && m == n);
        Cb[(size_t)m * Nn + n] = safe ? v : NEG_MAX;
      } else {
        Cb[(size_t)m * ldc + n] = v;
      }
    }
  }
}

// ---------------------------------------------------------------------------
// Softmax + pair_mask re-mask + renormalize, in place. Wave per row (384).
// ---------------------------------------------------------------------------
__global__ __launch_bounds__(256) void softmax_kernel(
    float* __restrict__ att, const int* __restrict__ pm)
{
  const int row  = blockIdx.x * 4 + (threadIdx.x >> 6);   // [0, B*H*N)
  const int lane = threadIdx.x & 63;
  const int i  = row % Nn;
  const int bh = row / Nn;
  const int b  = bh / Hh;
  float* ar = att + (size_t)row * Nn;
  const int* pmr = pm + (size_t)b * NSQ + (size_t)i * Nn;

  float v[6];
  float mx = NEG_MAX;
  #pragma unroll
  for (int t = 0; t < 6; ++t) { v[t] = ar[lane + t * 64]; mx = fmaxf(mx, v[t]); }
  mx = wmax(mx);
  float s = 0.f;
  #pragma unroll
  for (int t = 0; t < 6; ++t) { v[t] = expf(v[t] - mx); s += v[t]; }
  s = wsum(s);
  const float invs = 1.f / s;
  float s2 = 0.f;
  #pragma unroll
  for (int t = 0; t < 6; ++t) {
    const float pv = (float)pmr[lane + t * 64];
    v[t] = v[t] * invs * pv;
    s2 += v[t];
  }
  s2 = wsum(s2);
  const float r = 1.f / fmaxf(s2, 1e-6f);
  #pragma unroll
  for (int t = 0; t < 6; ++t) ar[lane + t * 64] = v[t] * r;
}

// ---------------------------------------------------------------------------
// ag = a * gelu(g): h (M,1024) -> ag (M,512)
// ---------------------------------------------------------------------------
__global__ __launch_bounds__(256) void gate_kernel(
    const float* __restrict__ hff, float* __restrict__ ag)
{
  const int idx = blockIdx.x * 256 + threadIdx.x;   // over 1536*512/4
  if (idx >= 1536 * 128) return;
  const int m  = idx / 128;
  const int dq = idx - m * 128;
  const float4 a = *(const float4*)(hff + (size_t)m * 1024 + dq * 4);
  const float4 g = *(const float4*)(hff + (size_t)m * 1024 + 512 + dq * 4);
  float4 o;
  o.x = a.x * gelu_f(g.x); o.y = a.y * gelu_f(g.y);
  o.z = a.z * gelu_f(g.z); o.w = a.w * gelu_f(g.w);
  *(float4*)(ag + (size_t)m * 512 + dq * 4) = o;
}

// ---------------------------------------------------------------------------
extern "C" void kernel_launch(void* const* d_in, const int* in_sizes, int n_in,
                              void* d_out, int out_size, void* d_ws, size_t ws_size,
                              hipStream_t stream) {
  const float* x    = (const float*)d_in[0];
  const int*   pm   = (const int*)  d_in[1];
  const int*   vld  = (const int*)  d_in[2];
  const float* cont = (const float*)d_in[3];
  const int* dbk = (const int*)d_in[4];
  const int* drk = (const int*)d_in[5];
  const int* rpk = (const int*)d_in[6];
  const int* hdk = (const int*)d_in[7];
  const int* etk = (const int*)d_in[8];
  const int* spk = (const int*)d_in[9];
  const int* sck = (const int*)d_in[10];
  const int* dgk = (const int*)d_in[11];
  const int* ctk = (const int*)d_in[12];
  const float* Wq  = (const float*)d_in[13];
  const float* Wk  = (const float*)d_in[14];
  const float* Wv  = (const float*)d_in[15];
  const float* Wo  = (const float*)d_in[16];
  const float* bo  = (const float*)d_in[17];
  const float* cmW1 = (const float*)d_in[18];
  const float* cmb1 = (const float*)d_in[19];
  const float* cmW2 = (const float*)d_in[20];
  const float* cmb2 = (const float*)d_in[21];
  const float* Ed  = (const float*)d_in[22];
  const float* Edi = (const float*)d_in[23];
  const float* Er  = (const float*)d_in[24];
  const float* Eh  = (const float*)d_in[25];
  const float* Ee  = (const float*)d_in[26];
  const float* Esp = (const float*)d_in[27];
  const float* Edg = (const float*)d_in[28];
  const float* Ec  = (const float*)d_in[29];
  const float* Es  = (const float*)d_in[30];
  const float* blng = (const float*)d_in[31];
  const float* blnb = (const float*)d_in[32];
  const float* bW   = (const float*)d_in[33];
  const float* bb_  = (const float*)d_in[34];
  const float* ln1g = (const float*)d_in[35];
  const float* ln1b = (const float*)d_in[36];
  const float* ln2g = (const float*)d_in[37];
  const float* ln2b = (const float*)d_in[38];
  const float* ffW1 = (const float*)d_in[39];
  const float* ffb1 = (const float*)d_in[40];
  const float* ffW2 = (const float*)d_in[41];
  const float* ffb2 = (const float*)d_in[42];

  float* out   = (float*)d_out;
  float* xout  = out;                       // 393216
  float* attn  = out + 393216;              // 2359296 (logits in place)
  float* biasO = out + 393216 + 2359296;    // 2359296

  float* ws  = (float*)d_ws;
  float* xn  = ws;                 // 393216  (ln1 out; reused for ln2 out)
  float* qb  = ws + 393216;        // 393216
  float* kb  = ws + 786432;        // 393216
  float* vb  = ws + 1179648;       // 393216
  float* ao  = ws + 1572864;       // 393216
  float* x1  = ws + 1966080;       // 393216
  float* hff = ws + 2359296;       // 1572864
  float* ag  = qb;                 // reuse q+k region (dead after QK)
  // pair-path scratch (in hff region; dead before FF1 writes hff)
  float* dc   = hff;               // 98304
  float* dcb  = hff + 98304;       // 98304
  float* w1p  = hff + 196608;      // 512
  unsigned short* w2bf = (unsigned short*)(hff + 197120);   // 4096 ushort

  // 0) prep: degcell(+b2) merge, W2->bf16, W1 pack
  prep_kernel<<<105, 256, 0, stream>>>(dgk, ctk, Edg, Ec, cmb2, cmW1, cmb1,
      cmW2, dc, dcb, w1p, w2bf);
  // 1) pair bias (MFMA)
  pair_kernel<<<9216, 256, 0, stream>>>(cont, pm, dbk, drk, rpk, hdk, etk, spk,
      sck, w1p, w2bf, Ed, Edi, Er, Eh, Ee, Esp, Es,
      blng, blnb, bW, bb_, dc, dcb, biasO);
  // 2) ln1
  ln_kernel<<<384, 256, 0, stream>>>(x, ln1g, ln1b, xn);
  // 3) q, k, v projections
  gemm_mfma<0><<<dim3(4, 24), 256, 0, stream>>>(xn, 256, Wq, 256, qb, 256,
      nullptr, nullptr, 0, 256, nullptr, nullptr, nullptr);
  gemm_mfma<0><<<dim3(4, 24), 256, 0, stream>>>(xn, 256, Wk, 256, kb, 256,
      nullptr, nullptr, 0, 256, nullptr, nullptr, nullptr);
  gemm_mfma<0><<<dim3(4, 24), 256, 0, stream>>>(xn, 256, Wv, 256, vb, 256,
      nullptr, nullptr, 0, 256, nullptr, nullptr, nullptr);
  // 4) logits = qk^T*scale + bias, safe-masked -> attn region
  gemm_mfma<1><<<dim3(6, 6, 16), 256, 0, stream>>>(qb, 256, kb, 256, attn, 384,
      nullptr, nullptr, 0, 64, biasO, pm, vld);
  // 5) softmax + mask + renorm (in place)
  softmax_kernel<<<1536, 256, 0, stream>>>(attn, pm);
  // 6) PV
  gemm_mfma<2><<<dim3(1, 6, 16), 256, 0, stream>>>(attn, 384, vb, 256, ao, 256,
      nullptr, nullptr, 0, 384, nullptr, nullptr, nullptr);
  // 7) Wo + bo + residual(x) -> x1
  gemm_mfma<0><<<dim3(4, 24), 256, 0, stream>>>(ao, 256, Wo, 256, x1, 256,
      bo, x, 256, 256, nullptr, nullptr, nullptr);
  // 8) ln2 -> xn (reuse)
  ln_kernel<<<384, 256, 0, stream>>>(x1, ln2g, ln2b, xn);
  // 9) FF1
  gemm_mfma<0><<<dim3(16, 24), 256, 0, stream>>>(xn, 256, ffW1, 256, hff, 1024,
      ffb1, nullptr, 0, 256, nullptr, nullptr, nullptr);
  // 10) gate: ag = a * gelu(g)
  gate_kernel<<<768, 256, 0, stream>>>(hff, ag);
  // 11) FF2 + ffb2 + residual(x1) -> x_out
  gemm_mfma<0><<<dim3(4, 24), 256, 0, stream>>>(ag, 512, ffW2, 512, xout, 256,
      ffb2, x1, 256, 512, nullptr, nullptr, nullptr);
}

// Round 7
// 345.251 us; speedup vs baseline: 1.4733x; 1.1503x over previous
//
#include <hip/hip_runtime.h>
#include <hip/hip_bf16.h>
#include <float.h>

// Problem constants
#define Bz   4
#define Nn   384
#define Dd   256
#define Hh   4
#define DHh  64
#define HIDn 64
#define NSQ  (384*384)
#define NEG_MAX (-3.40282346638528859812e+38f)

typedef __attribute__((ext_vector_type(8))) short short8;
typedef __attribute__((ext_vector_type(4))) float f32x4;

// fast exact-gelu: erf via Abramowitz-Stegun 7.1.26 (|err| <= 1.5e-7)
__device__ __forceinline__ float gelu_f(float x){
  const float y = __builtin_fabsf(x) * 0.70710678118654752f;
  const float t = __builtin_amdgcn_rcpf(fmaf(0.3275911f, y, 1.0f));
  float poly = fmaf(1.061405429f, t, -1.453152027f);
  poly = fmaf(poly, t, 1.421413741f);
  poly = fmaf(poly, t, -0.284496736f);
  poly = fmaf(poly, t, 0.254829592f);
  poly *= t;
  const float e = __expf(-y * y);
  const float erfa = fmaf(-poly, e, 1.0f);          // erf(|y|)
  const float er = __builtin_copysignf(erfa, x);
  return 0.5f * x * (1.0f + er);
}
__device__ __forceinline__ float wsum(float v){
  #pragma unroll
  for (int o = 32; o > 0; o >>= 1) v += __shfl_xor(v, o, 64);
  return v;
}
__device__ __forceinline__ float wmax(float v){
  #pragma unroll
  for (int o = 32; o > 0; o >>= 1) v = fmaxf(v, __shfl_xor(v, o, 64));
  return v;
}
__device__ __forceinline__ float4 ld4(const float* p){ return *(const float4*)p; }

// fp32 -> bf16 (RNE, finite inputs)
__device__ __forceinline__ unsigned short f2bfu(float f){
  union { float f; unsigned u; } v; v.f = f;
  unsigned r = v.u + 0x7FFFu + ((v.u >> 16) & 1u);
  return (unsigned short)(r >> 16);
}
__device__ __forceinline__ short f2bf(float f){ return (short)f2bfu(f); }

// ---------------------------------------------------------------------------
// prep:
//  dc  [row][c] = E_deg[deg[row]][c] + E_cell[cell[row]][c]        (j-side)
//  dcb [row][c] = dc[row][c] + b2[c]                               (i-side)
//  w2bf[c][k]   = bf16(W2[c][k])                                   (A-frags)
//  w1p [k][8]   = {W1[k][0..5], b1[k], 0}
// ---------------------------------------------------------------------------
__global__ __launch_bounds__(256) void prep_kernel(
    const int* __restrict__ dgk, const int* __restrict__ ctk,
    const float* __restrict__ Edg, const float* __restrict__ Ec,
    const float* __restrict__ b2,
    const float* __restrict__ W1, const float* __restrict__ b1,
    const float* __restrict__ W2,
    float* __restrict__ dc, float* __restrict__ dcb,
    float* __restrict__ w1p, unsigned short* __restrict__ w2bf)
{
  const int idx = blockIdx.x * 256 + threadIdx.x;
  if (idx < Bz * Nn * 16) {
    const int row = idx >> 4;
    const int q   = (idx & 15) << 2;
    const float4 a = ld4(Edg + (dgk[row] << 6) + q);
    const float4 b = ld4(Ec  + (ctk[row] << 6) + q);
    float4 o; o.x = a.x + b.x; o.y = a.y + b.y; o.z = a.z + b.z; o.w = a.w + b.w;
    *(float4*)(dc + ((size_t)row << 6) + q) = o;
    const float4 bb4 = ld4(b2 + q);
    float4 o2; o2.x = o.x + bb4.x; o2.y = o.y + bb4.y;
    o2.z = o.z + bb4.z; o2.w = o.w + bb4.w;
    *(float4*)(dcb + ((size_t)row << 6) + q) = o2;
  } else if (idx < Bz * Nn * 16 + 2048) {
    const int t = idx - Bz * Nn * 16;
    const int c = t >> 5, k2 = (t & 31) << 1;
    w2bf[c * 64 + k2]     = f2bfu(W2[c * 64 + k2]);
    w2bf[c * 64 + k2 + 1] = f2bfu(W2[c * 64 + k2 + 1]);
  } else if (idx < Bz * Nn * 16 + 2048 + 64) {
    const int k = idx - (Bz * Nn * 16 + 2048);
    #pragma unroll
    for (int d = 0; d < 6; ++d) w1p[k * 8 + d] = W1[k * 6 + d];
    w1p[k * 8 + 6] = b1[k];
    w1p[k * 8 + 7] = 0.f;
  }
}

// ---------------------------------------------------------------------------
// Fused pair kernel v7 (MFMA, spill-safe ordering, fast gelu, 4 blk/CU):
//   Phase a: lane computes its 16 h1 values -> bfr0/bfr1 (B-frags).
//   Phase b: acc = W2 @ H1^T via 8 x mfma_f32_16x16x32_bf16 (acc starts 0).
//   Phase c: gather 9 embedding tables, ADD into acc per m-tile.
//   Phase d: LN via 2 shuffles; gelu; 4-head dot; coalesced store.
// ---------------------------------------------------------------------------
__global__ __launch_bounds__(256, 4) void pair_kernel(
    const float* __restrict__ cont, const int* __restrict__ pm,
    const int* __restrict__ dbk, const int* __restrict__ drk,
    const int* __restrict__ rpk, const int* __restrict__ hdk,
    const int* __restrict__ etk, const int* __restrict__ spk,
    const int* __restrict__ sck,
    const float* __restrict__ w1p, const unsigned short* __restrict__ w2bf,
    const float* __restrict__ Ed, const float* __restrict__ Edi,
    const float* __restrict__ Er, const float* __restrict__ Eh,
    const float* __restrict__ Ee, const float* __restrict__ Esp,
    const float* __restrict__ Es,
    const float* __restrict__ lng, const float* __restrict__ lnb,
    const float* __restrict__ bW, const float* __restrict__ bb,
    const float* __restrict__ dc, const float* __restrict__ dcb,
    float* __restrict__ biasOut)
{
  const int tid  = threadIdx.x;
  const int lane = tid & 63;
  const int l15  = lane & 15, lg = lane >> 4;
  const int wid  = blockIdx.x * 4 + (tid >> 6);              // [0, 36864)
  const int rowU = __builtin_amdgcn_readfirstlane(wid / 24); // b*N+i
  const int jb   = wid - rowU * 24;
  const int b    = rowU / Nn;
  const int i    = rowU - b * Nn;
  const int j    = jb * 16 + l15;                            // lane's pair
  const size_t p = (size_t)rowU * Nn + j;
  const int colOff = lg << 2;                                // channel sub-base

  // ---- phase a: B-fragments h1[pair l15][k], k = ks*32 + lg*8 + jj ----
  const float* cp = cont + p * 6;
  const float2 fA = *(const float2*)cp;
  const float2 fB = *(const float2*)(cp + 2);
  const float2 fC = *(const float2*)(cp + 4);

  short8 bfr0, bfr1;
  #pragma unroll
  for (int jj = 0; jj < 8; ++jj) {
    {
      const int k = (lg << 3) + jj;
      const float4 wa = ld4(w1p + k * 8);
      const float4 wb = ld4(w1p + k * 8 + 4);
      float s = wb.z;
      s = fmaf(wa.x, fA.x, s); s = fmaf(wa.y, fA.y, s);
      s = fmaf(wa.z, fB.x, s); s = fmaf(wa.w, fB.y, s);
      s = fmaf(wb.x, fC.x, s); s = fmaf(wb.y, fC.y, s);
      bfr0[jj] = f2bf(gelu_f(s));
    }
    {
      const int k = 32 + (lg << 3) + jj;
      const float4 wa = ld4(w1p + k * 8);
      const float4 wb = ld4(w1p + k * 8 + 4);
      float s = wb.z;
      s = fmaf(wa.x, fA.x, s); s = fmaf(wa.y, fA.y, s);
      s = fmaf(wa.z, fB.x, s); s = fmaf(wa.w, fB.y, s);
      s = fmaf(wb.x, fC.x, s); s = fmaf(wb.y, fC.y, s);
      bfr1[jj] = f2bf(gelu_f(s));
    }
  }

  // ---- phase b: acc = W2 @ H1^T (A row = channel mt*16+l15) ----
  f32x4 acc[4] = {};
  #pragma unroll
  for (int mt = 0; mt < 4; ++mt) {
    const unsigned short* wrow = w2bf + (size_t)((mt << 4) + l15) * 64;
    const short8 a0 = *(const short8*)(wrow + (lg << 3));
    const short8 a1 = *(const short8*)(wrow + 32 + (lg << 3));
    acc[mt] = __builtin_amdgcn_mfma_f32_16x16x32_bf16(a0, bfr0, acc[mt], 0, 0, 0);
    acc[mt] = __builtin_amdgcn_mfma_f32_16x16x32_bf16(a1, bfr1, acc[mt], 0, 0, 0);
  }

  // ---- phase c: embedding gathers added into acc ----
  const int xdb = dbk[p] << 6, xdr = drk[p] << 6, xrp = rpk[p] << 6;
  const int xhd = hdk[p] << 6, xet = etk[p] << 6, xsp = spk[p] << 6;
  const int xsc = sck[p] << 6;
  const float* dcjp = dc  + ((size_t)(b * Nn + j) << 6);
  const float* dcbp = dcb + ((size_t)rowU << 6);

  #pragma unroll
  for (int mt = 0; mt < 4; ++mt) {
    const int c0 = (mt << 4) + colOff;
    float4 a = ld4(dcbp + c0);          // i-side degcell + b2
    float4 t;
    t = ld4(dcjp + c0);      a.x += t.x; a.y += t.y; a.z += t.z; a.w += t.w;
    t = ld4(Ed  + xdb + c0); a.x += t.x; a.y += t.y; a.z += t.z; a.w += t.w;
    t = ld4(Edi + xdr + c0); a.x += t.x; a.y += t.y; a.z += t.z; a.w += t.w;
    t = ld4(Er  + xrp + c0); a.x += t.x; a.y += t.y; a.z += t.z; a.w += t.w;
    t = ld4(Eh  + xhd + c0); a.x += t.x; a.y += t.y; a.z += t.z; a.w += t.w;
    t = ld4(Ee  + xet + c0); a.x += t.x; a.y += t.y; a.z += t.z; a.w += t.w;
    t = ld4(Esp + xsp + c0); a.x += t.x; a.y += t.y; a.z += t.z; a.w += t.w;
    t = ld4(Es  + xsc + c0); a.x += t.x; a.y += t.y; a.z += t.z; a.w += t.w;
    acc[mt][0] += a.x; acc[mt][1] += a.y; acc[mt][2] += a.z; acc[mt][3] += a.w;
  }

  // ---- phase d: LN stats (pair's 64 ch live on 4 lanes: xor16/32) ----
  float sum = 0.f, sq = 0.f;
  #pragma unroll
  for (int mt = 0; mt < 4; ++mt)
    #pragma unroll
    for (int r = 0; r < 4; ++r) {
      const float v = acc[mt][r];
      sum += v; sq = fmaf(v, v, sq);
    }
  sum += __shfl_xor(sum, 16, 64); sum += __shfl_xor(sum, 32, 64);
  sq  += __shfl_xor(sq,  16, 64); sq  += __shfl_xor(sq,  32, 64);
  const float mean = sum * (1.f / 64.f);
  const float var  = sq * (1.f / 64.f) - mean * mean;
  const float inv  = rsqrtf(var + 1e-5f);

  // gelu(LN) -> 4-head partial dots over own 16 channels
  float bh0 = 0.f, bh1 = 0.f, bh2 = 0.f, bh3 = 0.f;
  #pragma unroll
  for (int mt = 0; mt < 4; ++mt) {
    const int c0 = (mt << 4) + colOff;
    const float4 g4 = ld4(lng + c0);
    const float4 b4 = ld4(lnb + c0);
    const float4 w0 = ld4(bW + c0);
    const float4 w1_ = ld4(bW + 64 + c0);
    const float4 w2_ = ld4(bW + 128 + c0);
    const float4 w3_ = ld4(bW + 192 + c0);
    float g;
    g = gelu_f((acc[mt][0] - mean) * inv * g4.x + b4.x);
    bh0 = fmaf(w0.x, g, bh0); bh1 = fmaf(w1_.x, g, bh1);
    bh2 = fmaf(w2_.x, g, bh2); bh3 = fmaf(w3_.x, g, bh3);
    g = gelu_f((acc[mt][1] - mean) * inv * g4.y + b4.y);
    bh0 = fmaf(w0.y, g, bh0); bh1 = fmaf(w1_.y, g, bh1);
    bh2 = fmaf(w2_.y, g, bh2); bh3 = fmaf(w3_.y, g, bh3);
    g = gelu_f((acc[mt][2] - mean) * inv * g4.z + b4.z);
    bh0 = fmaf(w0.z, g, bh0); bh1 = fmaf(w1_.z, g, bh1);
    bh2 = fmaf(w2_.z, g, bh2); bh3 = fmaf(w3_.z, g, bh3);
    g = gelu_f((acc[mt][3] - mean) * inv * g4.w + b4.w);
    bh0 = fmaf(w0.w, g, bh0); bh1 = fmaf(w1_.w, g, bh1);
    bh2 = fmaf(w2_.w, g, bh2); bh3 = fmaf(w3_.w, g, bh3);
  }
  bh0 += __shfl_xor(bh0, 16, 64); bh0 += __shfl_xor(bh0, 32, 64);
  bh1 += __shfl_xor(bh1, 16, 64); bh1 += __shfl_xor(bh1, 32, 64);
  bh2 += __shfl_xor(bh2, 16, 64); bh2 += __shfl_xor(bh2, 32, 64);
  bh3 += __shfl_xor(bh3, 16, 64); bh3 += __shfl_xor(bh3, 32, 64);

  const float mk = pm[p] ? 1.f : 0.f;
  const float bh = (lg == 0) ? bh0 + bb[0] : (lg == 1) ? bh1 + bb[1]
                 : (lg == 2) ? bh2 + bb[2] : bh3 + bb[3];
  biasOut[(size_t)b * (Hh * NSQ) + (size_t)lg * NSQ + (size_t)i * Nn + j] = bh * mk;
}

// ---------------------------------------------------------------------------
// LayerNorm over last dim (256). One wave per row, 4 rows per block.
// ---------------------------------------------------------------------------
__global__ __launch_bounds__(256) void ln_kernel(
    const float* __restrict__ x, const float* __restrict__ g,
    const float* __restrict__ bta, float* __restrict__ o)
{
  const int row  = blockIdx.x * 4 + (threadIdx.x >> 6);
  const int lane = threadIdx.x & 63;
  const float4 v = *(const float4*)(x + (size_t)row * Dd + lane * 4);
  float s = v.x + v.y + v.z + v.w;
  s = wsum(s);
  const float m = s * (1.f / 256.f);
  const float dx = v.x - m, dy = v.y - m, dz = v.z - m, dw = v.w - m;
  float q = dx*dx + dy*dy + dz*dz + dw*dw;
  q = wsum(q);
  const float inv = rsqrtf(q * (1.f / 256.f) + 1e-5f);
  const int d = lane * 4;
  const float4 gg = *(const float4*)(g + d);
  const float4 bb = *(const float4*)(bta + d);
  float4 out;
  out.x = dx * inv * gg.x + bb.x;
  out.y = dy * inv * gg.y + bb.y;
  out.z = dz * inv * gg.z + bb.z;
  out.w = dw * inv * gg.w + bb.w;
  *(float4*)(o + (size_t)row * Dd + d) = out;
}

// ---------------------------------------------------------------------------
// Fused QKV projection: one launch, blockIdx.z selects {Wq->q, Wk->k, Wv->v}.
// Same 64x64 MFMA tile as gemm_mfma MODE 0, K=256, no bias/res.
// ---------------------------------------------------------------------------
__global__ __launch_bounds__(256) void qkv_kernel(
    const float* __restrict__ xn,
    const float* __restrict__ Wq, const float* __restrict__ Wk,
    const float* __restrict__ Wv,
    float* __restrict__ qb, float* __restrict__ kb, float* __restrict__ vb)
{
  const int tid = threadIdx.x;
  const int lane = tid & 63;
  const int w   = tid >> 6;
  const int l15 = lane & 15, lg = lane >> 4;
  const int m0 = blockIdx.y * 64 + w * 16;
  const int n0 = blockIdx.x * 64;
  const int z  = blockIdx.z;
  const float* Bb = (z == 0) ? Wq : (z == 1) ? Wk : Wv;
  float* Cb = (z == 0) ? qb : (z == 1) ? kb : vb;

  f32x4 acc[4] = {};
  const float* pa = xn + (size_t)(m0 + l15) * Dd + lg * 8;
  for (int k0 = 0; k0 < Dd; k0 += 32) {
    short8 af;
    {
      const float4 a0 = ld4(pa + k0);
      const float4 a1 = ld4(pa + k0 + 4);
      af[0] = f2bf(a0.x); af[1] = f2bf(a0.y); af[2] = f2bf(a0.z); af[3] = f2bf(a0.w);
      af[4] = f2bf(a1.x); af[5] = f2bf(a1.y); af[6] = f2bf(a1.z); af[7] = f2bf(a1.w);
    }
    #pragma unroll
    for (int nt = 0; nt < 4; ++nt) {
      const float* pb = Bb + (size_t)(n0 + nt * 16 + l15) * Dd + k0 + lg * 8;
      const float4 b0 = ld4(pb);
      const float4 b1 = ld4(pb + 4);
      short8 bf;
      bf[0] = f2bf(b0.x); bf[1] = f2bf(b0.y); bf[2] = f2bf(b0.z); bf[3] = f2bf(b0.w);
      bf[4] = f2bf(b1.x); bf[5] = f2bf(b1.y); bf[6] = f2bf(b1.z); bf[7] = f2bf(b1.w);
      acc[nt] = __builtin_amdgcn_mfma_f32_16x16x32_bf16(af, bf, acc[nt], 0, 0, 0);
    }
  }
  #pragma unroll
  for (int nt = 0; nt < 4; ++nt)
    #pragma unroll
    for (int r = 0; r < 4; ++r)
      Cb[(size_t)(m0 + lg * 4 + r) * Dd + n0 + nt * 16 + l15] = acc[nt][r];
}

// ---------------------------------------------------------------------------
// bf16 MFMA GEMM (no LDS). Wave computes 16(M) x 64(N); block = 4 waves = 64x64.
// MODE 0: C = A @ B^T (+bias)(+res)          grid (Nc/64, M/64)
// MODE 1: QK^T*scale + biasT, safe-mask      grid (6, 6, B*H)
// MODE 2: C = A @ B  (B natural KxN, PV)     grid (1, 6, B*H)
// MODE 3: C = (a*gelu(g)) @ B^T (+bias)(+res), A rows = hff[m][0..512|512..1024]
// ---------------------------------------------------------------------------
template<int MODE>
__global__ __launch_bounds__(256) void gemm_mfma(
    const float* __restrict__ A, int lda,
    const float* __restrict__ Bm, int ldb,
    float* __restrict__ Cc, int ldc,
    const float* __restrict__ bias,
    const float* __restrict__ res, int ldr,
    int K,
    const float* __restrict__ biasT, const int* __restrict__ pmask,
    const int* __restrict__ valid)
{
  const int tid = threadIdx.x;
  const int lane = tid & 63;
  const int w   = tid >> 6;
  const int l15 = lane & 15, lg = lane >> 4;
  const int m0 = blockIdx.y * 64 + w * 16;
  const int n0 = blockIdx.x * 64;

  const float* Ab = A; const float* Bb = Bm; float* Cb = Cc;
  const float* biasTb = biasT; const int* pmb = pmask; const int* vlb = valid;
  if (MODE == 1 || MODE == 2) {
    const int bz = blockIdx.z;
    const int b = bz >> 2, h = bz & 3;
    if (MODE == 1) {
      Ab = A  + (size_t)b * Nn * Dd + h * DHh;
      Bb = Bm + (size_t)b * Nn * Dd + h * DHh;
      Cb = Cc + (size_t)bz * NSQ;
      biasTb = biasT + (size_t)bz * NSQ;
      pmb = pmask + (size_t)b * NSQ;
      vlb = valid + b * Nn;
    } else {
      Ab = A  + (size_t)bz * NSQ;
      Bb = Bm + (size_t)b * Nn * Dd + h * DHh;
      Cb = Cc + (size_t)b * Nn * Dd + h * DHh;
    }
  }

  f32x4 acc[4] = {};
  const float* pa = Ab + (size_t)(m0 + l15) * lda + lg * 8;

  for (int k0 = 0; k0 < K; k0 += 32) {
    short8 af;
    if (MODE == 3) {
      const float4 a0 = ld4(pa + k0);
      const float4 a1 = ld4(pa + k0 + 4);
      const float4 g0 = ld4(pa + 512 + k0);
      const float4 g1 = ld4(pa + 512 + k0 + 4);
      af[0] = f2bf(a0.x * gelu_f(g0.x)); af[1] = f2bf(a0.y * gelu_f(g0.y));
      af[2] = f2bf(a0.z * gelu_f(g0.z)); af[3] = f2bf(a0.w * gelu_f(g0.w));
      af[4] = f2bf(a1.x * gelu_f(g1.x)); af[5] = f2bf(a1.y * gelu_f(g1.y));
      af[6] = f2bf(a1.z * gelu_f(g1.z)); af[7] = f2bf(a1.w * gelu_f(g1.w));
    } else {
      const float4 a0 = ld4(pa + k0);
      const float4 a1 = ld4(pa + k0 + 4);
      af[0] = f2bf(a0.x); af[1] = f2bf(a0.y); af[2] = f2bf(a0.z); af[3] = f2bf(a0.w);
      af[4] = f2bf(a1.x); af[5] = f2bf(a1.y); af[6] = f2bf(a1.z); af[7] = f2bf(a1.w);
    }
    #pragma unroll
    for (int nt = 0; nt < 4; ++nt) {
      short8 bf;
      if (MODE != 2) {
        const float* pb = Bb + (size_t)(n0 + nt * 16 + l15) * ldb + k0 + lg * 8;
        const float4 b0 = ld4(pb);
        const float4 b1 = ld4(pb + 4);
        bf[0] = f2bf(b0.x); bf[1] = f2bf(b0.y); bf[2] = f2bf(b0.z); bf[3] = f2bf(b0.w);
        bf[4] = f2bf(b1.x); bf[5] = f2bf(b1.y); bf[6] = f2bf(b1.z); bf[7] = f2bf(b1.w);
      } else {
        const float* pb = Bb + (size_t)(k0 + lg * 8) * ldb + n0 + nt * 16 + l15;
        #pragma unroll
        for (int jj = 0; jj < 8; ++jj) bf[jj] = f2bf(pb[(size_t)jj * ldb]);
      }
      acc[nt] = __builtin_amdgcn_mfma_f32_16x16x32_bf16(af, bf, acc[nt], 0, 0, 0);
    }
  }

  #pragma unroll
  for (int nt = 0; nt < 4; ++nt) {
    #pragma unroll
    for (int r = 0; r < 4; ++r) {
      const int m = m0 + lg * 4 + r;
      const int n = n0 + nt * 16 + l15;
      float v = acc[nt][r];
      if (MODE == 0 || MODE == 3) {
        if (bias) v += bias[n];
        if (res)  v += res[(size_t)m * ldr + n];
        Cb[(size_t)m * ldc + n] = v;
      } else if (MODE == 1) {
        v = v * 0.125f + biasTb[(size_t)m * Nn + n];
        const bool safe = (pmb[(size_t)m * Nn + n] != 0) || (vlb[m] == 0 && m == n);
        Cb[(size_t)m * Nn + n] = safe ? v : NEG_MAX;
      } else {
        Cb[(size_t)m * ldc + n] = v;
      }
    }
  }
}

// ---------------------------------------------------------------------------
// Softmax + pair_mask re-mask + renormalize, in place. Wave per row (384).
// ---------------------------------------------------------------------------
__global__ __launch_bounds__(256) void softmax_kernel(
    float* __restrict__ att, const int* __restrict__ pm)
{
  const int row  = blockIdx.x * 4 + (threadIdx.x >> 6);   // [0, B*H*N)
  const int lane = threadIdx.x & 63;
  const int i  = row % Nn;
  const int bh = row / Nn;
  const int b  = bh / Hh;
  float* ar = att + (size_t)row * Nn;
  const int* pmr = pm + (size_t)b * NSQ + (size_t)i * Nn;

  float v[6];
  float mx = NEG_MAX;
  #pragma unroll
  for (int t = 0; t < 6; ++t) { v[t] = ar[lane + t * 64]; mx = fmaxf(mx, v[t]); }
  mx = wmax(mx);
  float s = 0.f;
  #pragma unroll
  for (int t = 0; t < 6; ++t) { v[t] = __expf(v[t] - mx); s += v[t]; }
  s = wsum(s);
  const float invs = 1.f / s;
  float s2 = 0.f;
  #pragma unroll
  for (int t = 0; t < 6; ++t) {
    const float pv = (float)pmr[lane + t * 64];
    v[t] = v[t] * invs * pv;
    s2 += v[t];
  }
  s2 = wsum(s2);
  const float r = 1.f / fmaxf(s2, 1e-6f);
  #pragma unroll
  for (int t = 0; t < 6; ++t) ar[lane + t * 64] = v[t] * r;
}

// ---------------------------------------------------------------------------
extern "C" void kernel_launch(void* const* d_in, const int* in_sizes, int n_in,
                              void* d_out, int out_size, void* d_ws, size_t ws_size,
                              hipStream_t stream) {
  const float* x    = (const float*)d_in[0];
  const int*   pm   = (const int*)  d_in[1];
  const int*   vld  = (const int*)  d_in[2];
  const float* cont = (const float*)d_in[3];
  const int* dbk = (const int*)d_in[4];
  const int* drk = (const int*)d_in[5];
  const int* rpk = (const int*)d_in[6];
  const int* hdk = (const int*)d_in[7];
  const int* etk = (const int*)d_in[8];
  const int* spk = (const int*)d_in[9];
  const int* sck = (const int*)d_in[10];
  const int* dgk = (const int*)d_in[11];
  const int* ctk = (const int*)d_in[12];
  const float* Wq  = (const float*)d_in[13];
  const float* Wk  = (const float*)d_in[14];
  const float* Wv  = (const float*)d_in[15];
  const float* Wo  = (const float*)d_in[16];
  const float* bo  = (const float*)d_in[17];
  const float* cmW1 = (const float*)d_in[18];
  const float* cmb1 = (const float*)d_in[19];
  const float* cmW2 = (const float*)d_in[20];
  const float* cmb2 = (const float*)d_in[21];
  const float* Ed  = (const float*)d_in[22];
  const float* Edi = (const float*)d_in[23];
  const float* Er  = (const float*)d_in[24];
  const float* Eh  = (const float*)d_in[25];
  const float* Ee  = (const float*)d_in[26];
  const float* Esp = (const float*)d_in[27];
  const float* Edg = (const float*)d_in[28];
  const float* Ec  = (const float*)d_in[29];
  const float* Es  = (const float*)d_in[30];
  const float* blng = (const float*)d_in[31];
  const float* blnb = (const float*)d_in[32];
  const float* bW   = (const float*)d_in[33];
  const float* bb_  = (const float*)d_in[34];
  const float* ln1g = (const float*)d_in[35];
  const float* ln1b = (const float*)d_in[36];
  const float* ln2g = (const float*)d_in[37];
  const float* ln2b = (const float*)d_in[38];
  const float* ffW1 = (const float*)d_in[39];
  const float* ffb1 = (const float*)d_in[40];
  const float* ffW2 = (const float*)d_in[41];
  const float* ffb2 = (const float*)d_in[42];

  float* out   = (float*)d_out;
  float* xout  = out;                       // 393216
  float* attn  = out + 393216;              // 2359296 (logits in place)
  float* biasO = out + 393216 + 2359296;    // 2359296

  float* ws  = (float*)d_ws;
  float* xn  = ws;                 // 393216  (ln1 out; reused for ln2 out)
  float* qb  = ws + 393216;        // 393216
  float* kb  = ws + 786432;        // 393216
  float* vb  = ws + 1179648;       // 393216
  float* ao  = ws + 1572864;       // 393216
  float* x1  = ws + 1966080;       // 393216
  float* hff = ws + 2359296;       // 1572864
  // pair-path scratch (in hff region; dead before FF1 writes hff)
  float* dc   = hff;               // 98304
  float* dcb  = hff + 98304;       // 98304
  float* w1p  = hff + 196608;      // 512
  unsigned short* w2bf = (unsigned short*)(hff + 197120);   // 4096 ushort

  // 0) prep: degcell(+b2) merge, W2->bf16, W1 pack
  prep_kernel<<<105, 256, 0, stream>>>(dgk, ctk, Edg, Ec, cmb2, cmW1, cmb1,
      cmW2, dc, dcb, w1p, w2bf);
  // 1) pair bias (MFMA)
  pair_kernel<<<9216, 256, 0, stream>>>(cont, pm, dbk, drk, rpk, hdk, etk, spk,
      sck, w1p, w2bf, Ed, Edi, Er, Eh, Ee, Esp, Es,
      blng, blnb, bW, bb_, dc, dcb, biasO);
  // 2) ln1
  ln_kernel<<<384, 256, 0, stream>>>(x, ln1g, ln1b, xn);
  // 3) q, k, v projections (single launch)
  qkv_kernel<<<dim3(4, 24, 3), 256, 0, stream>>>(xn, Wq, Wk, Wv, qb, kb, vb);
  // 4) logits = qk^T*scale + bias, safe-masked -> attn region
  gemm_mfma<1><<<dim3(6, 6, 16), 256, 0, stream>>>(qb, 256, kb, 256, attn, 384,
      nullptr, nullptr, 0, 64, biasO, pm, vld);
  // 5) softmax + mask + renorm (in place)
  softmax_kernel<<<1536, 256, 0, stream>>>(attn, pm);
  // 6) PV
  gemm_mfma<2><<<dim3(1, 6, 16), 256, 0, stream>>>(attn, 384, vb, 256, ao, 256,
      nullptr, nullptr, 0, 384, nullptr, nullptr, nullptr);
  // 7) Wo + bo + residual(x) -> x1
  gemm_mfma<0><<<dim3(4, 24), 256, 0, stream>>>(ao, 256, Wo, 256, x1, 256,
      bo, x, 256, 256, nullptr, nullptr, nullptr);
  // 8) ln2 -> xn (reuse)
  ln_kernel<<<384, 256, 0, stream>>>(x1, ln2g, ln2b, xn);
  // 9) FF1
  gemm_mfma<0><<<dim3(16, 24), 256, 0, stream>>>(xn, 256, ffW1, 256, hff, 1024,
      ffb1, nullptr, 0, 256, nullptr, nullptr, nullptr);
  // 10) FF2 with fused gate (a*gelu(g)) + ffb2 + residual(x1) -> x_out
  gemm_mfma<3><<<dim3(4, 24), 256, 0, stream>>>(hff, 1024, ffW2, 512, xout, 256,
      ffb2, x1, 256, 512, nullptr, nullptr, nullptr);
}

// Round 8
// 307.815 us; speedup vs baseline: 1.6525x; 1.1216x over previous
//
#include <hip/hip_runtime.h>
#include <hip/hip_bf16.h>
#include <float.h>

// Problem constants
#define Bz   4
#define Nn   384
#define Dd   256
#define Hh   4
#define DHh  64
#define HIDn 64
#define NSQ  (384*384)
#define NEG_MAX (-3.40282346638528859812e+38f)

typedef __attribute__((ext_vector_type(8))) short short8;
typedef __attribute__((ext_vector_type(4))) float f32x4;

// fast exact-gelu: erf via Abramowitz-Stegun 7.1.26 (|err| <= 1.5e-7)
__device__ __forceinline__ float gelu_f(float x){
  const float y = __builtin_fabsf(x) * 0.70710678118654752f;
  const float t = __builtin_amdgcn_rcpf(fmaf(0.3275911f, y, 1.0f));
  float poly = fmaf(1.061405429f, t, -1.453152027f);
  poly = fmaf(poly, t, 1.421413741f);
  poly = fmaf(poly, t, -0.284496736f);
  poly = fmaf(poly, t, 0.254829592f);
  poly *= t;
  const float e = __expf(-y * y);
  const float erfa = fmaf(-poly, e, 1.0f);          // erf(|y|)
  const float er = __builtin_copysignf(erfa, x);
  return 0.5f * x * (1.0f + er);
}
__device__ __forceinline__ float wsum(float v){
  #pragma unroll
  for (int o = 32; o > 0; o >>= 1) v += __shfl_xor(v, o, 64);
  return v;
}
__device__ __forceinline__ float wmax(float v){
  #pragma unroll
  for (int o = 32; o > 0; o >>= 1) v = fmaxf(v, __shfl_xor(v, o, 64));
  return v;
}
__device__ __forceinline__ float4 ld4(const float* p){ return *(const float4*)p; }

// fp32 -> bf16 (RNE, finite inputs)
__device__ __forceinline__ unsigned short f2bfu(float f){
  union { float f; unsigned u; } v; v.f = f;
  unsigned r = v.u + 0x7FFFu + ((v.u >> 16) & 1u);
  return (unsigned short)(r >> 16);
}
__device__ __forceinline__ short f2bf(float f){ return (short)f2bfu(f); }

// ---------------------------------------------------------------------------
// prep:
//  dc  [row][c] = E_deg[deg[row]][c] + E_cell[cell[row]][c]        (j-side)
//  dcb [row][c] = dc[row][c] + b2[c]                               (i-side)
//  w2bf[c][k]   = bf16(W2[c][k])                                   (A-frags)
//  w1p [k][8]   = {W1[k][0..5], b1[k], 0}
//  Edd [d*10+r]   = Ed[d] + Edi[r]          (90 rows)
//  Ers [ro*6+s]   = Er[ro] + Esp[s]         (60 rows)
//  Ehes[(h*5+e)*3+sm] = Eh[h]+Ee[e]+Es[sm]  (60 rows)
// ---------------------------------------------------------------------------
__global__ __launch_bounds__(256) void prep_kernel(
    const int* __restrict__ dgk, const int* __restrict__ ctk,
    const float* __restrict__ Edg, const float* __restrict__ Ec,
    const float* __restrict__ b2,
    const float* __restrict__ W1, const float* __restrict__ b1,
    const float* __restrict__ W2,
    const float* __restrict__ Ed, const float* __restrict__ Edi,
    const float* __restrict__ Er, const float* __restrict__ Eh,
    const float* __restrict__ Ee, const float* __restrict__ Esp,
    const float* __restrict__ Es,
    float* __restrict__ dc, float* __restrict__ dcb,
    float* __restrict__ w1p, unsigned short* __restrict__ w2bf,
    float* __restrict__ Edd, float* __restrict__ Ers,
    float* __restrict__ Ehes)
{
  const int idx = blockIdx.x * 256 + threadIdx.x;
  if (idx < 24576) {                       // dc / dcb
    const int row = idx >> 4;
    const int q   = (idx & 15) << 2;
    const float4 a = ld4(Edg + (dgk[row] << 6) + q);
    const float4 b = ld4(Ec  + (ctk[row] << 6) + q);
    float4 o; o.x = a.x + b.x; o.y = a.y + b.y; o.z = a.z + b.z; o.w = a.w + b.w;
    *(float4*)(dc + ((size_t)row << 6) + q) = o;
    const float4 bb4 = ld4(b2 + q);
    float4 o2; o2.x = o.x + bb4.x; o2.y = o.y + bb4.y;
    o2.z = o.z + bb4.z; o2.w = o.w + bb4.w;
    *(float4*)(dcb + ((size_t)row << 6) + q) = o2;
  } else if (idx < 26624) {                // w2bf
    const int t = idx - 24576;
    const int c = t >> 5, k2 = (t & 31) << 1;
    w2bf[c * 64 + k2]     = f2bfu(W2[c * 64 + k2]);
    w2bf[c * 64 + k2 + 1] = f2bfu(W2[c * 64 + k2 + 1]);
  } else if (idx < 26688) {                // w1p
    const int k = idx - 26624;
    #pragma unroll
    for (int d = 0; d < 6; ++d) w1p[k * 8 + d] = W1[k * 6 + d];
    w1p[k * 8 + 6] = b1[k];
    w1p[k * 8 + 7] = 0.f;
  } else if (idx < 28128) {                // Edd: 90 rows x 16 chunks
    const int t = idx - 26688;
    const int row = t >> 4, q = (t & 15) << 2;
    const int d = row / 10, r = row - d * 10;
    const float4 a = ld4(Ed + (d << 6) + q);
    const float4 b = ld4(Edi + (r << 6) + q);
    float4 o; o.x = a.x + b.x; o.y = a.y + b.y; o.z = a.z + b.z; o.w = a.w + b.w;
    *(float4*)(Edd + (row << 6) + q) = o;
  } else if (idx < 29088) {                // Ers: 60 rows x 16 chunks
    const int t = idx - 28128;
    const int row = t >> 4, q = (t & 15) << 2;
    const int ro = row / 6, s = row - ro * 6;
    const float4 a = ld4(Er + (ro << 6) + q);
    const float4 b = ld4(Esp + (s << 6) + q);
    float4 o; o.x = a.x + b.x; o.y = a.y + b.y; o.z = a.z + b.z; o.w = a.w + b.w;
    *(float4*)(Ers + (row << 6) + q) = o;
  } else if (idx < 30048) {                // Ehes: 60 rows x 16 chunks
    const int t = idx - 29088;
    const int row = t >> 4, q = (t & 15) << 2;
    const int h = row / 15, rem = row - h * 15;
    const int e = rem / 3, sm = rem - e * 3;
    const float4 a = ld4(Eh + (h << 6) + q);
    const float4 b = ld4(Ee + (e << 6) + q);
    const float4 c = ld4(Es + (sm << 6) + q);
    float4 o; o.x = a.x + b.x + c.x; o.y = a.y + b.y + c.y;
    o.z = a.z + b.z + c.z; o.w = a.w + b.w + c.w;
    *(float4*)(Ehes + (row << 6) + q) = o;
  }
}

// ---------------------------------------------------------------------------
// Fused pair kernel v8 (MFMA + combined tables + batched gathers):
//   Phase a: lane computes its 16 h1 values -> bfr0/bfr1 (B-frags).
//   Phase b: acc = W2 @ H1^T via 8 x mfma_f32_16x16x32_bf16 (acc starts 0).
//   Phase c: 20 float4 gathers (3 combined tables + dcj + dcb) issued as a
//            single batch into named regs (max MLP), then added into acc.
//   Phase d: LN via 2 shuffles; gelu; 4-head dot; coalesced store.
//   launch_bounds(256,2): 128-reg cap, room for ~16 loads in flight.
// ---------------------------------------------------------------------------
__global__ __launch_bounds__(256, 2) void pair_kernel(
    const float* __restrict__ cont, const int* __restrict__ pm,
    const int* __restrict__ dbk, const int* __restrict__ drk,
    const int* __restrict__ rpk, const int* __restrict__ hdk,
    const int* __restrict__ etk, const int* __restrict__ spk,
    const int* __restrict__ sck,
    const float* __restrict__ w1p, const unsigned short* __restrict__ w2bf,
    const float* __restrict__ Edd, const float* __restrict__ Ers,
    const float* __restrict__ Ehes,
    const float* __restrict__ lng, const float* __restrict__ lnb,
    const float* __restrict__ bW, const float* __restrict__ bb,
    const float* __restrict__ dc, const float* __restrict__ dcb,
    float* __restrict__ biasOut)
{
  const int tid  = threadIdx.x;
  const int lane = tid & 63;
  const int l15  = lane & 15, lg = lane >> 4;
  const int wid  = blockIdx.x * 4 + (tid >> 6);              // [0, 36864)
  const int rowU = __builtin_amdgcn_readfirstlane(wid / 24); // b*N+i
  const int jb   = wid - rowU * 24;
  const int b    = rowU / Nn;
  const int i    = rowU - b * Nn;
  const int j    = jb * 16 + l15;                            // lane's pair
  const size_t p = (size_t)rowU * Nn + j;
  const int colOff = lg << 2;                                // channel sub-base

  // combined embedding indices (issued early; consumed in phase c)
  const int xdd  = (dbk[p] * 10 + drk[p]) << 6;
  const int xrs  = (rpk[p] * 6 + spk[p]) << 6;
  const int xhes = ((hdk[p] * 5 + etk[p]) * 3 + sck[p]) << 6;
  const int mkI  = pm[p];
  const float* dcjp = dc  + ((size_t)(b * Nn + j) << 6);
  const float* dcbp = dcb + ((size_t)rowU << 6);             // uniform

  // ---- phase a: B-fragments h1[pair l15][k], k = ks*32 + lg*8 + jj ----
  const float* cp = cont + p * 6;
  const float2 fA = *(const float2*)cp;
  const float2 fB = *(const float2*)(cp + 2);
  const float2 fC = *(const float2*)(cp + 4);

  short8 bfr0, bfr1;
  #pragma unroll
  for (int jj = 0; jj < 8; ++jj) {
    {
      const int k = (lg << 3) + jj;
      const float4 wa = ld4(w1p + k * 8);
      const float4 wb = ld4(w1p + k * 8 + 4);
      float s = wb.z;
      s = fmaf(wa.x, fA.x, s); s = fmaf(wa.y, fA.y, s);
      s = fmaf(wa.z, fB.x, s); s = fmaf(wa.w, fB.y, s);
      s = fmaf(wb.x, fC.x, s); s = fmaf(wb.y, fC.y, s);
      bfr0[jj] = f2bf(gelu_f(s));
    }
    {
      const int k = 32 + (lg << 3) + jj;
      const float4 wa = ld4(w1p + k * 8);
      const float4 wb = ld4(w1p + k * 8 + 4);
      float s = wb.z;
      s = fmaf(wa.x, fA.x, s); s = fmaf(wa.y, fA.y, s);
      s = fmaf(wa.z, fB.x, s); s = fmaf(wa.w, fB.y, s);
      s = fmaf(wb.x, fC.x, s); s = fmaf(wb.y, fC.y, s);
      bfr1[jj] = f2bf(gelu_f(s));
    }
  }

  // ---- phase b: acc = W2 @ H1^T (A row = channel mt*16+l15) ----
  f32x4 acc[4] = {};
  #pragma unroll
  for (int mt = 0; mt < 4; ++mt) {
    const unsigned short* wrow = w2bf + (size_t)((mt << 4) + l15) * 64;
    const short8 a0 = *(const short8*)(wrow + (lg << 3));
    const short8 a1 = *(const short8*)(wrow + 32 + (lg << 3));
    acc[mt] = __builtin_amdgcn_mfma_f32_16x16x32_bf16(a0, bfr0, acc[mt], 0, 0, 0);
    acc[mt] = __builtin_amdgcn_mfma_f32_16x16x32_bf16(a1, bfr1, acc[mt], 0, 0, 0);
  }

  // ---- phase c: batched gathers (all loads issued, then adds) ----
  float4 t0[4], t1[4], t2[4], t3[4], t4[4];
  #pragma unroll
  for (int mt = 0; mt < 4; ++mt) {
    const int c0 = (mt << 4) + colOff;
    t0[mt] = ld4(Edd  + xdd  + c0);
    t1[mt] = ld4(Ers  + xrs  + c0);
    t2[mt] = ld4(Ehes + xhes + c0);
    t3[mt] = ld4(dcjp + c0);
    t4[mt] = ld4(dcbp + c0);
  }
  #pragma unroll
  for (int mt = 0; mt < 4; ++mt) {
    acc[mt][0] += t0[mt].x + t1[mt].x + t2[mt].x + t3[mt].x + t4[mt].x;
    acc[mt][1] += t0[mt].y + t1[mt].y + t2[mt].y + t3[mt].y + t4[mt].y;
    acc[mt][2] += t0[mt].z + t1[mt].z + t2[mt].z + t3[mt].z + t4[mt].z;
    acc[mt][3] += t0[mt].w + t1[mt].w + t2[mt].w + t3[mt].w + t4[mt].w;
  }

  // ---- phase d: LN stats (pair's 64 ch live on 4 lanes: xor16/32) ----
  float sum = 0.f, sq = 0.f;
  #pragma unroll
  for (int mt = 0; mt < 4; ++mt)
    #pragma unroll
    for (int r = 0; r < 4; ++r) {
      const float v = acc[mt][r];
      sum += v; sq = fmaf(v, v, sq);
    }
  sum += __shfl_xor(sum, 16, 64); sum += __shfl_xor(sum, 32, 64);
  sq  += __shfl_xor(sq,  16, 64); sq  += __shfl_xor(sq,  32, 64);
  const float mean = sum * (1.f / 64.f);
  const float var  = sq * (1.f / 64.f) - mean * mean;
  const float inv  = rsqrtf(var + 1e-5f);

  // gelu(LN) -> 4-head partial dots over own 16 channels
  float bh0 = 0.f, bh1 = 0.f, bh2 = 0.f, bh3 = 0.f;
  #pragma unroll
  for (int mt = 0; mt < 4; ++mt) {
    const int c0 = (mt << 4) + colOff;
    const float4 g4 = ld4(lng + c0);
    const float4 b4 = ld4(lnb + c0);
    const float4 w0 = ld4(bW + c0);
    const float4 w1_ = ld4(bW + 64 + c0);
    const float4 w2_ = ld4(bW + 128 + c0);
    const float4 w3_ = ld4(bW + 192 + c0);
    float g;
    g = gelu_f((acc[mt][0] - mean) * inv * g4.x + b4.x);
    bh0 = fmaf(w0.x, g, bh0); bh1 = fmaf(w1_.x, g, bh1);
    bh2 = fmaf(w2_.x, g, bh2); bh3 = fmaf(w3_.x, g, bh3);
    g = gelu_f((acc[mt][1] - mean) * inv * g4.y + b4.y);
    bh0 = fmaf(w0.y, g, bh0); bh1 = fmaf(w1_.y, g, bh1);
    bh2 = fmaf(w2_.y, g, bh2); bh3 = fmaf(w3_.y, g, bh3);
    g = gelu_f((acc[mt][2] - mean) * inv * g4.z + b4.z);
    bh0 = fmaf(w0.z, g, bh0); bh1 = fmaf(w1_.z, g, bh1);
    bh2 = fmaf(w2_.z, g, bh2); bh3 = fmaf(w3_.z, g, bh3);
    g = gelu_f((acc[mt][3] - mean) * inv * g4.w + b4.w);
    bh0 = fmaf(w0.w, g, bh0); bh1 = fmaf(w1_.w, g, bh1);
    bh2 = fmaf(w2_.w, g, bh2); bh3 = fmaf(w3_.w, g, bh3);
  }
  bh0 += __shfl_xor(bh0, 16, 64); bh0 += __shfl_xor(bh0, 32, 64);
  bh1 += __shfl_xor(bh1, 16, 64); bh1 += __shfl_xor(bh1, 32, 64);
  bh2 += __shfl_xor(bh2, 16, 64); bh2 += __shfl_xor(bh2, 32, 64);
  bh3 += __shfl_xor(bh3, 16, 64); bh3 += __shfl_xor(bh3, 32, 64);

  const float mk = mkI ? 1.f : 0.f;
  const float bh = (lg == 0) ? bh0 + bb[0] : (lg == 1) ? bh1 + bb[1]
                 : (lg == 2) ? bh2 + bb[2] : bh3 + bb[3];
  biasOut[(size_t)b * (Hh * NSQ) + (size_t)lg * NSQ + (size_t)i * Nn + j] = bh * mk;
}

// ---------------------------------------------------------------------------
// LayerNorm over last dim (256). One wave per row, 4 rows per block.
// ---------------------------------------------------------------------------
__global__ __launch_bounds__(256) void ln_kernel(
    const float* __restrict__ x, const float* __restrict__ g,
    const float* __restrict__ bta, float* __restrict__ o)
{
  const int row  = blockIdx.x * 4 + (threadIdx.x >> 6);
  const int lane = threadIdx.x & 63;
  const float4 v = *(const float4*)(x + (size_t)row * Dd + lane * 4);
  float s = v.x + v.y + v.z + v.w;
  s = wsum(s);
  const float m = s * (1.f / 256.f);
  const float dx = v.x - m, dy = v.y - m, dz = v.z - m, dw = v.w - m;
  float q = dx*dx + dy*dy + dz*dz + dw*dw;
  q = wsum(q);
  const float inv = rsqrtf(q * (1.f / 256.f) + 1e-5f);
  const int d = lane * 4;
  const float4 gg = *(const float4*)(g + d);
  const float4 bb = *(const float4*)(bta + d);
  float4 out;
  out.x = dx * inv * gg.x + bb.x;
  out.y = dy * inv * gg.y + bb.y;
  out.z = dz * inv * gg.z + bb.z;
  out.w = dw * inv * gg.w + bb.w;
  *(float4*)(o + (size_t)row * Dd + d) = out;
}

// ---------------------------------------------------------------------------
// Fused QKV projection: one launch, blockIdx.z selects {Wq->q, Wk->k, Wv->v}.
// ---------------------------------------------------------------------------
__global__ __launch_bounds__(256) void qkv_kernel(
    const float* __restrict__ xn,
    const float* __restrict__ Wq, const float* __restrict__ Wk,
    const float* __restrict__ Wv,
    float* __restrict__ qb, float* __restrict__ kb, float* __restrict__ vb)
{
  const int tid = threadIdx.x;
  const int lane = tid & 63;
  const int w   = tid >> 6;
  const int l15 = lane & 15, lg = lane >> 4;
  const int m0 = blockIdx.y * 64 + w * 16;
  const int n0 = blockIdx.x * 64;
  const int z  = blockIdx.z;
  const float* Bb = (z == 0) ? Wq : (z == 1) ? Wk : Wv;
  float* Cb = (z == 0) ? qb : (z == 1) ? kb : vb;

  f32x4 acc[4] = {};
  const float* pa = xn + (size_t)(m0 + l15) * Dd + lg * 8;
  for (int k0 = 0; k0 < Dd; k0 += 32) {
    short8 af;
    {
      const float4 a0 = ld4(pa + k0);
      const float4 a1 = ld4(pa + k0 + 4);
      af[0] = f2bf(a0.x); af[1] = f2bf(a0.y); af[2] = f2bf(a0.z); af[3] = f2bf(a0.w);
      af[4] = f2bf(a1.x); af[5] = f2bf(a1.y); af[6] = f2bf(a1.z); af[7] = f2bf(a1.w);
    }
    #pragma unroll
    for (int nt = 0; nt < 4; ++nt) {
      const float* pb = Bb + (size_t)(n0 + nt * 16 + l15) * Dd + k0 + lg * 8;
      const float4 b0 = ld4(pb);
      const float4 b1 = ld4(pb + 4);
      short8 bf;
      bf[0] = f2bf(b0.x); bf[1] = f2bf(b0.y); bf[2] = f2bf(b0.z); bf[3] = f2bf(b0.w);
      bf[4] = f2bf(b1.x); bf[5] = f2bf(b1.y); bf[6] = f2bf(b1.z); bf[7] = f2bf(b1.w);
      acc[nt] = __builtin_amdgcn_mfma_f32_16x16x32_bf16(af, bf, acc[nt], 0, 0, 0);
    }
  }
  #pragma unroll
  for (int nt = 0; nt < 4; ++nt)
    #pragma unroll
    for (int r = 0; r < 4; ++r)
      Cb[(size_t)(m0 + lg * 4 + r) * Dd + n0 + nt * 16 + l15] = acc[nt][r];
}

// ---------------------------------------------------------------------------
// bf16 MFMA GEMM (no LDS). Wave computes 16(M) x 64(N); block = 4 waves = 64x64.
// MODE 0: C = A @ B^T (+bias)(+res)          grid (Nc/64, M/64)
// MODE 1: QK^T*scale + biasT, safe-mask      grid (6, 6, B*H)
// MODE 2: C = A @ B  (B natural KxN, PV)     grid (1, 6, B*H)
// MODE 3: C = (a*gelu(g)) @ B^T (+bias)(+res), A rows = hff[m][0..512|512..1024]
// ---------------------------------------------------------------------------
template<int MODE>
__global__ __launch_bounds__(256) void gemm_mfma(
    const float* __restrict__ A, int lda,
    const float* __restrict__ Bm, int ldb,
    float* __restrict__ Cc, int ldc,
    const float* __restrict__ bias,
    const float* __restrict__ res, int ldr,
    int K,
    const float* __restrict__ biasT, const int* __restrict__ pmask,
    const int* __restrict__ valid)
{
  const int tid = threadIdx.x;
  const int lane = tid & 63;
  const int w   = tid >> 6;
  const int l15 = lane & 15, lg = lane >> 4;
  const int m0 = blockIdx.y * 64 + w * 16;
  const int n0 = blockIdx.x * 64;

  const float* Ab = A; const float* Bb = Bm; float* Cb = Cc;
  const float* biasTb = biasT; const int* pmb = pmask; const int* vlb = valid;
  if (MODE == 1 || MODE == 2) {
    const int bz = blockIdx.z;
    const int b = bz >> 2, h = bz & 3;
    if (MODE == 1) {
      Ab = A  + (size_t)b * Nn * Dd + h * DHh;
      Bb = Bm + (size_t)b * Nn * Dd + h * DHh;
      Cb = Cc + (size_t)bz * NSQ;
      biasTb = biasT + (size_t)bz * NSQ;
      pmb = pmask + (size_t)b * NSQ;
      vlb = valid + b * Nn;
    } else {
      Ab = A  + (size_t)bz * NSQ;
      Bb = Bm + (size_t)b * Nn * Dd + h * DHh;
      Cb = Cc + (size_t)b * Nn * Dd + h * DHh;
    }
  }

  f32x4 acc[4] = {};
  const float* pa = Ab + (size_t)(m0 + l15) * lda + lg * 8;

  for (int k0 = 0; k0 < K; k0 += 32) {
    short8 af;
    if (MODE == 3) {
      const float4 a0 = ld4(pa + k0);
      const float4 a1 = ld4(pa + k0 + 4);
      const float4 g0 = ld4(pa + 512 + k0);
      const float4 g1 = ld4(pa + 512 + k0 + 4);
      af[0] = f2bf(a0.x * gelu_f(g0.x)); af[1] = f2bf(a0.y * gelu_f(g0.y));
      af[2] = f2bf(a0.z * gelu_f(g0.z)); af[3] = f2bf(a0.w * gelu_f(g0.w));
      af[4] = f2bf(a1.x * gelu_f(g1.x)); af[5] = f2bf(a1.y * gelu_f(g1.y));
      af[6] = f2bf(a1.z * gelu_f(g1.z)); af[7] = f2bf(a1.w * gelu_f(g1.w));
    } else {
      const float4 a0 = ld4(pa + k0);
      const float4 a1 = ld4(pa + k0 + 4);
      af[0] = f2bf(a0.x); af[1] = f2bf(a0.y); af[2] = f2bf(a0.z); af[3] = f2bf(a0.w);
      af[4] = f2bf(a1.x); af[5] = f2bf(a1.y); af[6] = f2bf(a1.z); af[7] = f2bf(a1.w);
    }
    #pragma unroll
    for (int nt = 0; nt < 4; ++nt) {
      short8 bf;
      if (MODE != 2) {
        const float* pb = Bb + (size_t)(n0 + nt * 16 + l15) * ldb + k0 + lg * 8;
        const float4 b0 = ld4(pb);
        const float4 b1 = ld4(pb + 4);
        bf[0] = f2bf(b0.x); bf[1] = f2bf(b0.y); bf[2] = f2bf(b0.z); bf[3] = f2bf(b0.w);
        bf[4] = f2bf(b1.x); bf[5] = f2bf(b1.y); bf[6] = f2bf(b1.z); bf[7] = f2bf(b1.w);
      } else {
        const float* pb = Bb + (size_t)(k0 + lg * 8) * ldb + n0 + nt * 16 + l15;
        #pragma unroll
        for (int jj = 0; jj < 8; ++jj) bf[jj] = f2bf(pb[(size_t)jj * ldb]);
      }
      acc[nt] = __builtin_amdgcn_mfma_f32_16x16x32_bf16(af, bf, acc[nt], 0, 0, 0);
    }
  }

  #pragma unroll
  for (int nt = 0; nt < 4; ++nt) {
    #pragma unroll
    for (int r = 0; r < 4; ++r) {
      const int m = m0 + lg * 4 + r;
      const int n = n0 + nt * 16 + l15;
      float v = acc[nt][r];
      if (MODE == 0 || MODE == 3) {
        if (bias) v += bias[n];
        if (res)  v += res[(size_t)m * ldr + n];
        Cb[(size_t)m * ldc + n] = v;
      } else if (MODE == 1) {
        v = v * 0.125f + biasTb[(size_t)m * Nn + n];
        const bool safe = (pmb[(size_t)m * Nn + n] != 0) || (vlb[m] == 0 && m == n);
        Cb[(size_t)m * Nn + n] = safe ? v : NEG_MAX;
      } else {
        Cb[(size_t)m * ldc + n] = v;
      }
    }
  }
}

// ---------------------------------------------------------------------------
// Softmax + pair_mask re-mask + renormalize, in place. Wave per row (384).
// ---------------------------------------------------------------------------
__global__ __launch_bounds__(256) void softmax_kernel(
    float* __restrict__ att, const int* __restrict__ pm)
{
  const int row  = blockIdx.x * 4 + (threadIdx.x >> 6);   // [0, B*H*N)
  const int lane = threadIdx.x & 63;
  const int i  = row % Nn;
  const int bh = row / Nn;
  const int b  = bh / Hh;
  float* ar = att + (size_t)row * Nn;
  const int* pmr = pm + (size_t)b * NSQ + (size_t)i * Nn;

  float v[6];
  float mx = NEG_MAX;
  #pragma unroll
  for (int t = 0; t < 6; ++t) { v[t] = ar[lane + t * 64]; mx = fmaxf(mx, v[t]); }
  mx = wmax(mx);
  float s = 0.f;
  #pragma unroll
  for (int t = 0; t < 6; ++t) { v[t] = __expf(v[t] - mx); s += v[t]; }
  s = wsum(s);
  const float invs = 1.f / s;
  float s2 = 0.f;
  #pragma unroll
  for (int t = 0; t < 6; ++t) {
    const float pv = (float)pmr[lane + t * 64];
    v[t] = v[t] * invs * pv;
    s2 += v[t];
  }
  s2 = wsum(s2);
  const float r = 1.f / fmaxf(s2, 1e-6f);
  #pragma unroll
  for (int t = 0; t < 6; ++t) ar[lane + t * 64] = v[t] * r;
}

// ---------------------------------------------------------------------------
extern "C" void kernel_launch(void* const* d_in, const int* in_sizes, int n_in,
                              void* d_out, int out_size, void* d_ws, size_t ws_size,
                              hipStream_t stream) {
  const float* x    = (const float*)d_in[0];
  const int*   pm   = (const int*)  d_in[1];
  const int*   vld  = (const int*)  d_in[2];
  const float* cont = (const float*)d_in[3];
  const int* dbk = (const int*)d_in[4];
  const int* drk = (const int*)d_in[5];
  const int* rpk = (const int*)d_in[6];
  const int* hdk = (const int*)d_in[7];
  const int* etk = (const int*)d_in[8];
  const int* spk = (const int*)d_in[9];
  const int* sck = (const int*)d_in[10];
  const int* dgk = (const int*)d_in[11];
  const int* ctk = (const int*)d_in[12];
  const float* Wq  = (const float*)d_in[13];
  const float* Wk  = (const float*)d_in[14];
  const float* Wv  = (const float*)d_in[15];
  const float* Wo  = (const float*)d_in[16];
  const float* bo  = (const float*)d_in[17];
  const float* cmW1 = (const float*)d_in[18];
  const float* cmb1 = (const float*)d_in[19];
  const float* cmW2 = (const float*)d_in[20];
  const float* cmb2 = (const float*)d_in[21];
  const float* Ed  = (const float*)d_in[22];
  const float* Edi = (const float*)d_in[23];
  const float* Er  = (const float*)d_in[24];
  const float* Eh  = (const float*)d_in[25];
  const float* Ee  = (const float*)d_in[26];
  const float* Esp = (const float*)d_in[27];
  const float* Edg = (const float*)d_in[28];
  const float* Ec  = (const float*)d_in[29];
  const float* Es  = (const float*)d_in[30];
  const float* blng = (const float*)d_in[31];
  const float* blnb = (const float*)d_in[32];
  const float* bW   = (const float*)d_in[33];
  const float* bb_  = (const float*)d_in[34];
  const float* ln1g = (const float*)d_in[35];
  const float* ln1b = (const float*)d_in[36];
  const float* ln2g = (const float*)d_in[37];
  const float* ln2b = (const float*)d_in[38];
  const float* ffW1 = (const float*)d_in[39];
  const float* ffb1 = (const float*)d_in[40];
  const float* ffW2 = (const float*)d_in[41];
  const float* ffb2 = (const float*)d_in[42];

  float* out   = (float*)d_out;
  float* xout  = out;                       // 393216
  float* attn  = out + 393216;              // 2359296 (logits in place)
  float* biasO = out + 393216 + 2359296;    // 2359296

  float* ws  = (float*)d_ws;
  float* xn  = ws;                 // 393216  (ln1 out; reused for ln2 out)
  float* qb  = ws + 393216;        // 393216
  float* kb  = ws + 786432;        // 393216
  float* vb  = ws + 1179648;       // 393216
  float* ao  = ws + 1572864;       // 393216
  float* x1  = ws + 1966080;       // 393216
  float* hff = ws + 2359296;       // 1572864
  // pair-path scratch (in hff region; dead before FF1 writes hff)
  float* dc   = hff;               // 98304
  float* dcb  = hff + 98304;       // 98304
  float* w1p  = hff + 196608;      // 512
  unsigned short* w2bf = (unsigned short*)(hff + 197120);   // 2048 floats
  float* Edd  = hff + 199168;      // 5760
  float* Ers  = hff + 204928;      // 3840
  float* Ehes = hff + 208768;      // 3840 (ends 212608)

  // 0) prep: degcell(+b2), W2->bf16, W1 pack, combined tables
  prep_kernel<<<118, 256, 0, stream>>>(dgk, ctk, Edg, Ec, cmb2, cmW1, cmb1,
      cmW2, Ed, Edi, Er, Eh, Ee, Esp, Es, dc, dcb, w1p, w2bf, Edd, Ers, Ehes);
  // 1) pair bias (MFMA + batched gathers)
  pair_kernel<<<9216, 256, 0, stream>>>(cont, pm, dbk, drk, rpk, hdk, etk, spk,
      sck, w1p, w2bf, Edd, Ers, Ehes, blng, blnb, bW, bb_, dc, dcb, biasO);
  // 2) ln1
  ln_kernel<<<384, 256, 0, stream>>>(x, ln1g, ln1b, xn);
  // 3) q, k, v projections (single launch)
  qkv_kernel<<<dim3(4, 24, 3), 256, 0, stream>>>(xn, Wq, Wk, Wv, qb, kb, vb);
  // 4) logits = qk^T*scale + bias, safe-masked -> attn region
  gemm_mfma<1><<<dim3(6, 6, 16), 256, 0, stream>>>(qb, 256, kb, 256, attn, 384,
      nullptr, nullptr, 0, 64, biasO, pm, vld);
  // 5) softmax + mask + renorm (in place)
  softmax_kernel<<<1536, 256, 0, stream>>>(attn, pm);
  // 6) PV
  gemm_mfma<2><<<dim3(1, 6, 16), 256, 0, stream>>>(attn, 384, vb, 256, ao, 256,
      nullptr, nullptr, 0, 384, nullptr, nullptr, nullptr);
  // 7) Wo + bo + residual(x) -> x1
  gemm_mfma<0><<<dim3(4, 24), 256, 0, stream>>>(ao, 256, Wo, 256, x1, 256,
      bo, x, 256, 256, nullptr, nullptr, nullptr);
  // 8) ln2 -> xn (reuse)
  ln_kernel<<<384, 256, 0, stream>>>(x1, ln2g, ln2b, xn);
  // 9) FF1
  gemm_mfma<0><<<dim3(16, 24), 256, 0, stream>>>(xn, 256, ffW1, 256, hff, 1024,
      ffb1, nullptr, 0, 256, nullptr, nullptr, nullptr);
  // 10) FF2 with fused gate (a*gelu(g)) + ffb2 + residual(x1) -> x_out
  gemm_mfma<3><<<dim3(4, 24), 256, 0, stream>>>(hff, 1024, ffW2, 512, xout, 256,
      ffb2, x1, 256, 512, nullptr, nullptr, nullptr);
}

// Round 9
// 307.006 us; speedup vs baseline: 1.6569x; 1.0026x over previous
//
#include <hip/hip_runtime.h>
#include <hip/hip_bf16.h>
#include <float.h>

// Problem constants
#define Bz   4
#define Nn   384
#define Dd   256
#define Hh   4
#define DHh  64
#define HIDn 64
#define NSQ  (384*384)
#define NEG_MAX (-3.40282346638528859812e+38f)

typedef __attribute__((ext_vector_type(8))) short short8;
typedef __attribute__((ext_vector_type(4))) float f32x4;
typedef __attribute__((ext_vector_type(2))) float f32x2;

// fast exact-gelu: erf via Abramowitz-Stegun 7.1.26 (|err| <= 1.5e-7)
__device__ __forceinline__ float gelu_f(float x){
  const float y = __builtin_fabsf(x) * 0.70710678118654752f;
  const float t = __builtin_amdgcn_rcpf(fmaf(0.3275911f, y, 1.0f));
  float poly = fmaf(1.061405429f, t, -1.453152027f);
  poly = fmaf(poly, t, 1.421413741f);
  poly = fmaf(poly, t, -0.284496736f);
  poly = fmaf(poly, t, 0.254829592f);
  poly *= t;
  const float e = __expf(-y * y);
  const float erfa = fmaf(-poly, e, 1.0f);          // erf(|y|)
  const float er = __builtin_copysignf(erfa, x);
  return 0.5f * x * (1.0f + er);
}
__device__ __forceinline__ float wsum(float v){
  #pragma unroll
  for (int o = 32; o > 0; o >>= 1) v += __shfl_xor(v, o, 64);
  return v;
}
__device__ __forceinline__ float wmax(float v){
  #pragma unroll
  for (int o = 32; o > 0; o >>= 1) v = fmaxf(v, __shfl_xor(v, o, 64));
  return v;
}
__device__ __forceinline__ float4 ld4(const float* p){ return *(const float4*)p; }
__device__ __forceinline__ f32x4 ldv4(const float* p){ return *(const f32x4*)p; }

// fp32 -> bf16 (RNE, finite inputs)
__device__ __forceinline__ unsigned short f2bfu(float f){
  union { float f; unsigned u; } v; v.f = f;
  unsigned r = v.u + 0x7FFFu + ((v.u >> 16) & 1u);
  return (unsigned short)(r >> 16);
}
__device__ __forceinline__ short f2bf(float f){ return (short)f2bfu(f); }

// ---------------------------------------------------------------------------
// prep (unchanged from R8)
// ---------------------------------------------------------------------------
__global__ __launch_bounds__(256) void prep_kernel(
    const int* __restrict__ dgk, const int* __restrict__ ctk,
    const float* __restrict__ Edg, const float* __restrict__ Ec,
    const float* __restrict__ b2,
    const float* __restrict__ W1, const float* __restrict__ b1,
    const float* __restrict__ W2,
    const float* __restrict__ Ed, const float* __restrict__ Edi,
    const float* __restrict__ Er, const float* __restrict__ Eh,
    const float* __restrict__ Ee, const float* __restrict__ Esp,
    const float* __restrict__ Es,
    float* __restrict__ dc, float* __restrict__ dcb,
    float* __restrict__ w1p, unsigned short* __restrict__ w2bf,
    float* __restrict__ Edd, float* __restrict__ Ers,
    float* __restrict__ Ehes)
{
  const int idx = blockIdx.x * 256 + threadIdx.x;
  if (idx < 24576) {                       // dc / dcb
    const int row = idx >> 4;
    const int q   = (idx & 15) << 2;
    const float4 a = ld4(Edg + (dgk[row] << 6) + q);
    const float4 b = ld4(Ec  + (ctk[row] << 6) + q);
    float4 o; o.x = a.x + b.x; o.y = a.y + b.y; o.z = a.z + b.z; o.w = a.w + b.w;
    *(float4*)(dc + ((size_t)row << 6) + q) = o;
    const float4 bb4 = ld4(b2 + q);
    float4 o2; o2.x = o.x + bb4.x; o2.y = o.y + bb4.y;
    o2.z = o.z + bb4.z; o2.w = o.w + bb4.w;
    *(float4*)(dcb + ((size_t)row << 6) + q) = o2;
  } else if (idx < 26624) {                // w2bf
    const int t = idx - 24576;
    const int c = t >> 5, k2 = (t & 31) << 1;
    w2bf[c * 64 + k2]     = f2bfu(W2[c * 64 + k2]);
    w2bf[c * 64 + k2 + 1] = f2bfu(W2[c * 64 + k2 + 1]);
  } else if (idx < 26688) {                // w1p
    const int k = idx - 26624;
    #pragma unroll
    for (int d = 0; d < 6; ++d) w1p[k * 8 + d] = W1[k * 6 + d];
    w1p[k * 8 + 6] = b1[k];
    w1p[k * 8 + 7] = 0.f;
  } else if (idx < 28128) {                // Edd: 90 rows x 16 chunks
    const int t = idx - 26688;
    const int row = t >> 4, q = (t & 15) << 2;
    const int d = row / 10, r = row - d * 10;
    const float4 a = ld4(Ed + (d << 6) + q);
    const float4 b = ld4(Edi + (r << 6) + q);
    float4 o; o.x = a.x + b.x; o.y = a.y + b.y; o.z = a.z + b.z; o.w = a.w + b.w;
    *(float4*)(Edd + (row << 6) + q) = o;
  } else if (idx < 29088) {                // Ers: 60 rows x 16 chunks
    const int t = idx - 28128;
    const int row = t >> 4, q = (t & 15) << 2;
    const int ro = row / 6, s = row - ro * 6;
    const float4 a = ld4(Er + (ro << 6) + q);
    const float4 b = ld4(Esp + (s << 6) + q);
    float4 o; o.x = a.x + b.x; o.y = a.y + b.y; o.z = a.z + b.z; o.w = a.w + b.w;
    *(float4*)(Ers + (row << 6) + q) = o;
  } else if (idx < 30048) {                // Ehes: 60 rows x 16 chunks
    const int t = idx - 29088;
    const int row = t >> 4, q = (t & 15) << 2;
    const int h = row / 15, rem = row - h * 15;
    const int e = rem / 3, sm = rem - e * 3;
    const float4 a = ld4(Eh + (h << 6) + q);
    const float4 b = ld4(Ee + (e << 6) + q);
    const float4 c = ld4(Es + (sm << 6) + q);
    float4 o; o.x = a.x + b.x + c.x; o.y = a.y + b.y + c.y;
    o.z = a.z + b.z + c.z; o.w = a.w + b.w + c.w;
    *(float4*)(Ehes + (row << 6) + q) = o;
  }
}

// ---------------------------------------------------------------------------
// Fused pair kernel v9: R8 structure + asm-fenced load batches to force MLP.
// Each fence consumes a batch of loaded values -> compiler must co-issue the
// batch (one waitcnt) instead of serializing at 1 load in flight (R8: VGPR=36).
// ---------------------------------------------------------------------------
__global__ __launch_bounds__(256, 2) void pair_kernel(
    const float* __restrict__ cont, const int* __restrict__ pm,
    const int* __restrict__ dbk, const int* __restrict__ drk,
    const int* __restrict__ rpk, const int* __restrict__ hdk,
    const int* __restrict__ etk, const int* __restrict__ spk,
    const int* __restrict__ sck,
    const float* __restrict__ w1p, const unsigned short* __restrict__ w2bf,
    const float* __restrict__ Edd, const float* __restrict__ Ers,
    const float* __restrict__ Ehes,
    const float* __restrict__ lng, const float* __restrict__ lnb,
    const float* __restrict__ bW, const float* __restrict__ bb,
    const float* __restrict__ dc, const float* __restrict__ dcb,
    float* __restrict__ biasOut)
{
  const int tid  = threadIdx.x;
  const int lane = tid & 63;
  const int l15  = lane & 15, lg = lane >> 4;
  const int wid  = blockIdx.x * 4 + (tid >> 6);              // [0, 36864)
  const int rowU = __builtin_amdgcn_readfirstlane(wid / 24); // b*N+i
  const int jb   = wid - rowU * 24;
  const int b    = rowU / Nn;
  const int i    = rowU - b * Nn;
  const int j    = jb * 16 + l15;                            // lane's pair
  const size_t p = (size_t)rowU * Nn + j;
  const int colOff = lg << 2;                                // channel sub-base

  // ---- init: batch the per-pair index / cont / mask loads ----
  const int vdb = dbk[p], vdr = drk[p], vrp = rpk[p], vhd = hdk[p];
  const int vet = etk[p], vsp = spk[p], vsc = sck[p];
  const int mkI = pm[p];
  const float* cp = cont + p * 6;
  const f32x2 fA = *(const f32x2*)cp;
  const f32x2 fB = *(const f32x2*)(cp + 2);
  const f32x2 fC = *(const f32x2*)(cp + 4);
  asm volatile("" :: "v"(vdb), "v"(vdr), "v"(vrp), "v"(vhd), "v"(vet),
                     "v"(vsp), "v"(vsc), "v"(mkI), "v"(fA), "v"(fB), "v"(fC));
  const int xdd  = (vdb * 10 + vdr) << 6;
  const int xrs  = (vrp * 6 + vsp) << 6;
  const int xhes = ((vhd * 5 + vet) * 3 + vsc) << 6;
  const float* dcjp = dc  + ((size_t)(b * Nn + j) << 6);
  const float* dcbp = dcb + ((size_t)rowU << 6);             // uniform -> s_load

  // ---- phase a: h1 fragments; 4 batches of 8 f32x4 w1p loads ----
  short8 bfr0, bfr1;
  #pragma unroll
  for (int jg = 0; jg < 4; ++jg) {
    const int ka = (lg << 3) + jg * 2;     // rows ka, ka+1, ka+32, ka+33
    const f32x4 a0 = ldv4(w1p + (ka + 0) * 8),  a1 = ldv4(w1p + (ka + 0) * 8 + 4);
    const f32x4 b0 = ldv4(w1p + (ka + 1) * 8),  b1 = ldv4(w1p + (ka + 1) * 8 + 4);
    const f32x4 c0 = ldv4(w1p + (ka + 32) * 8), c1 = ldv4(w1p + (ka + 32) * 8 + 4);
    const f32x4 d0 = ldv4(w1p + (ka + 33) * 8), d1 = ldv4(w1p + (ka + 33) * 8 + 4);
    asm volatile("" :: "v"(a0), "v"(a1), "v"(b0), "v"(b1),
                       "v"(c0), "v"(c1), "v"(d0), "v"(d1));
    float s;
    s = a1[2];
    s = fmaf(a0[0], fA[0], s); s = fmaf(a0[1], fA[1], s);
    s = fmaf(a0[2], fB[0], s); s = fmaf(a0[3], fB[1], s);
    s = fmaf(a1[0], fC[0], s); s = fmaf(a1[1], fC[1], s);
    bfr0[jg * 2 + 0] = f2bf(gelu_f(s));
    s = b1[2];
    s = fmaf(b0[0], fA[0], s); s = fmaf(b0[1], fA[1], s);
    s = fmaf(b0[2], fB[0], s); s = fmaf(b0[3], fB[1], s);
    s = fmaf(b1[0], fC[0], s); s = fmaf(b1[1], fC[1], s);
    bfr0[jg * 2 + 1] = f2bf(gelu_f(s));
    s = c1[2];
    s = fmaf(c0[0], fA[0], s); s = fmaf(c0[1], fA[1], s);
    s = fmaf(c0[2], fB[0], s); s = fmaf(c0[3], fB[1], s);
    s = fmaf(c1[0], fC[0], s); s = fmaf(c1[1], fC[1], s);
    bfr1[jg * 2 + 0] = f2bf(gelu_f(s));
    s = d1[2];
    s = fmaf(d0[0], fA[0], s); s = fmaf(d0[1], fA[1], s);
    s = fmaf(d0[2], fB[0], s); s = fmaf(d0[3], fB[1], s);
    s = fmaf(d1[0], fC[0], s); s = fmaf(d1[1], fC[1], s);
    bfr1[jg * 2 + 1] = f2bf(gelu_f(s));
  }

  // ---- phase b: batch all 8 A-frag loads, then 8 MFMAs ----
  const unsigned short* wbase = w2bf + (size_t)l15 * 64 + (lg << 3);
  const short8 wa0 = *(const short8*)(wbase);
  const short8 wb0 = *(const short8*)(wbase + 32);
  const short8 wa1 = *(const short8*)(wbase + 16 * 64);
  const short8 wb1 = *(const short8*)(wbase + 16 * 64 + 32);
  const short8 wa2 = *(const short8*)(wbase + 32 * 64);
  const short8 wb2 = *(const short8*)(wbase + 32 * 64 + 32);
  const short8 wa3 = *(const short8*)(wbase + 48 * 64);
  const short8 wb3 = *(const short8*)(wbase + 48 * 64 + 32);
  asm volatile("" :: "v"(wa0), "v"(wb0), "v"(wa1), "v"(wb1),
                     "v"(wa2), "v"(wb2), "v"(wa3), "v"(wb3));
  f32x4 acc[4] = {};
  acc[0] = __builtin_amdgcn_mfma_f32_16x16x32_bf16(wa0, bfr0, acc[0], 0, 0, 0);
  acc[0] = __builtin_amdgcn_mfma_f32_16x16x32_bf16(wb0, bfr1, acc[0], 0, 0, 0);
  acc[1] = __builtin_amdgcn_mfma_f32_16x16x32_bf16(wa1, bfr0, acc[1], 0, 0, 0);
  acc[1] = __builtin_amdgcn_mfma_f32_16x16x32_bf16(wb1, bfr1, acc[1], 0, 0, 0);
  acc[2] = __builtin_amdgcn_mfma_f32_16x16x32_bf16(wa2, bfr0, acc[2], 0, 0, 0);
  acc[2] = __builtin_amdgcn_mfma_f32_16x16x32_bf16(wb2, bfr1, acc[2], 0, 0, 0);
  acc[3] = __builtin_amdgcn_mfma_f32_16x16x32_bf16(wa3, bfr0, acc[3], 0, 0, 0);
  acc[3] = __builtin_amdgcn_mfma_f32_16x16x32_bf16(wb3, bfr1, acc[3], 0, 0, 0);

  // ---- phase c: gathers in 2 fenced batches of 8 ----
  {
    const f32x4 e0 = ldv4(Edd + xdd + colOff);
    const f32x4 e1 = ldv4(Edd + xdd + 16 + colOff);
    const f32x4 e2 = ldv4(Edd + xdd + 32 + colOff);
    const f32x4 e3 = ldv4(Edd + xdd + 48 + colOff);
    const f32x4 r0 = ldv4(Ers + xrs + colOff);
    const f32x4 r1 = ldv4(Ers + xrs + 16 + colOff);
    const f32x4 r2 = ldv4(Ers + xrs + 32 + colOff);
    const f32x4 r3 = ldv4(Ers + xrs + 48 + colOff);
    asm volatile("" :: "v"(e0), "v"(e1), "v"(e2), "v"(e3),
                       "v"(r0), "v"(r1), "v"(r2), "v"(r3));
    acc[0] += e0 + r0; acc[1] += e1 + r1; acc[2] += e2 + r2; acc[3] += e3 + r3;
  }
  {
    const f32x4 h0 = ldv4(Ehes + xhes + colOff);
    const f32x4 h1v = ldv4(Ehes + xhes + 16 + colOff);
    const f32x4 h2 = ldv4(Ehes + xhes + 32 + colOff);
    const f32x4 h3 = ldv4(Ehes + xhes + 48 + colOff);
    const f32x4 j0 = ldv4(dcjp + colOff);
    const f32x4 j1 = ldv4(dcjp + 16 + colOff);
    const f32x4 j2 = ldv4(dcjp + 32 + colOff);
    const f32x4 j3 = ldv4(dcjp + 48 + colOff);
    asm volatile("" :: "v"(h0), "v"(h1v), "v"(h2), "v"(h3),
                       "v"(j0), "v"(j1), "v"(j2), "v"(j3));
    const f32x4 u0 = ldv4(dcbp + colOff);          // uniform (scalar path ok)
    const f32x4 u1 = ldv4(dcbp + 16 + colOff);
    const f32x4 u2 = ldv4(dcbp + 32 + colOff);
    const f32x4 u3 = ldv4(dcbp + 48 + colOff);
    acc[0] += h0 + j0 + u0; acc[1] += h1v + j1 + u1;
    acc[2] += h2 + j2 + u2; acc[3] += h3 + j3 + u3;
  }

  // ---- phase d: LN stats (xor16/32 over lg) ----
  float sum = 0.f, sq = 0.f;
  #pragma unroll
  for (int mt = 0; mt < 4; ++mt)
    #pragma unroll
    for (int r = 0; r < 4; ++r) {
      const float v = acc[mt][r];
      sum += v; sq = fmaf(v, v, sq);
    }
  sum += __shfl_xor(sum, 16, 64); sum += __shfl_xor(sum, 32, 64);
  sq  += __shfl_xor(sq,  16, 64); sq  += __shfl_xor(sq,  32, 64);
  const float mean = sum * (1.f / 64.f);
  const float var  = sq * (1.f / 64.f) - mean * mean;
  const float inv  = rsqrtf(var + 1e-5f);

  // gelu(LN) -> 4-head partial dots; per-mt fenced batch of 6 loads
  float bh0 = 0.f, bh1 = 0.f, bh2 = 0.f, bh3 = 0.f;
  #pragma unroll
  for (int mt = 0; mt < 4; ++mt) {
    const int c0 = (mt << 4) + colOff;
    const f32x4 g4 = ldv4(lng + c0);
    const f32x4 b4 = ldv4(lnb + c0);
    const f32x4 w0 = ldv4(bW + c0);
    const f32x4 w1_ = ldv4(bW + 64 + c0);
    const f32x4 w2_ = ldv4(bW + 128 + c0);
    const f32x4 w3_ = ldv4(bW + 192 + c0);
    asm volatile("" :: "v"(g4), "v"(b4), "v"(w0), "v"(w1_), "v"(w2_), "v"(w3_));
    #pragma unroll
    for (int r = 0; r < 4; ++r) {
      const float g = gelu_f((acc[mt][r] - mean) * inv * g4[r] + b4[r]);
      bh0 = fmaf(w0[r], g, bh0); bh1 = fmaf(w1_[r], g, bh1);
      bh2 = fmaf(w2_[r], g, bh2); bh3 = fmaf(w3_[r], g, bh3);
    }
  }
  bh0 += __shfl_xor(bh0, 16, 64); bh0 += __shfl_xor(bh0, 32, 64);
  bh1 += __shfl_xor(bh1, 16, 64); bh1 += __shfl_xor(bh1, 32, 64);
  bh2 += __shfl_xor(bh2, 16, 64); bh2 += __shfl_xor(bh2, 32, 64);
  bh3 += __shfl_xor(bh3, 16, 64); bh3 += __shfl_xor(bh3, 32, 64);

  const float mk = mkI ? 1.f : 0.f;
  const float bh = (lg == 0) ? bh0 + bb[0] : (lg == 1) ? bh1 + bb[1]
                 : (lg == 2) ? bh2 + bb[2] : bh3 + bb[3];
  biasOut[(size_t)b * (Hh * NSQ) + (size_t)lg * NSQ + (size_t)i * Nn + j] = bh * mk;
}

// ---------------------------------------------------------------------------
// LayerNorm over last dim (256). One wave per row, 4 rows per block.
// ---------------------------------------------------------------------------
__global__ __launch_bounds__(256) void ln_kernel(
    const float* __restrict__ x, const float* __restrict__ g,
    const float* __restrict__ bta, float* __restrict__ o)
{
  const int row  = blockIdx.x * 4 + (threadIdx.x >> 6);
  const int lane = threadIdx.x & 63;
  const float4 v = *(const float4*)(x + (size_t)row * Dd + lane * 4);
  float s = v.x + v.y + v.z + v.w;
  s = wsum(s);
  const float m = s * (1.f / 256.f);
  const float dx = v.x - m, dy = v.y - m, dz = v.z - m, dw = v.w - m;
  float q = dx*dx + dy*dy + dz*dz + dw*dw;
  q = wsum(q);
  const float inv = rsqrtf(q * (1.f / 256.f) + 1e-5f);
  const int d = lane * 4;
  const float4 gg = *(const float4*)(g + d);
  const float4 bb = *(const float4*)(bta + d);
  float4 out;
  out.x = dx * inv * gg.x + bb.x;
  out.y = dy * inv * gg.y + bb.y;
  out.z = dz * inv * gg.z + bb.z;
  out.w = dw * inv * gg.w + bb.w;
  *(float4*)(o + (size_t)row * Dd + d) = out;
}

// ---------------------------------------------------------------------------
// Fused QKV projection: one launch, blockIdx.z selects {Wq->q, Wk->k, Wv->v}.
// ---------------------------------------------------------------------------
__global__ __launch_bounds__(256) void qkv_kernel(
    const float* __restrict__ xn,
    const float* __restrict__ Wq, const float* __restrict__ Wk,
    const float* __restrict__ Wv,
    float* __restrict__ qb, float* __restrict__ kb, float* __restrict__ vb)
{
  const int tid = threadIdx.x;
  const int lane = tid & 63;
  const int w   = tid >> 6;
  const int l15 = lane & 15, lg = lane >> 4;
  const int m0 = blockIdx.y * 64 + w * 16;
  const int n0 = blockIdx.x * 64;
  const int z  = blockIdx.z;
  const float* Bb = (z == 0) ? Wq : (z == 1) ? Wk : Wv;
  float* Cb = (z == 0) ? qb : (z == 1) ? kb : vb;

  f32x4 acc[4] = {};
  const float* pa = xn + (size_t)(m0 + l15) * Dd + lg * 8;
  for (int k0 = 0; k0 < Dd; k0 += 32) {
    short8 af;
    {
      const float4 a0 = ld4(pa + k0);
      const float4 a1 = ld4(pa + k0 + 4);
      af[0] = f2bf(a0.x); af[1] = f2bf(a0.y); af[2] = f2bf(a0.z); af[3] = f2bf(a0.w);
      af[4] = f2bf(a1.x); af[5] = f2bf(a1.y); af[6] = f2bf(a1.z); af[7] = f2bf(a1.w);
    }
    #pragma unroll
    for (int nt = 0; nt < 4; ++nt) {
      const float* pb = Bb + (size_t)(n0 + nt * 16 + l15) * Dd + k0 + lg * 8;
      const float4 b0 = ld4(pb);
      const float4 b1 = ld4(pb + 4);
      short8 bf;
      bf[0] = f2bf(b0.x); bf[1] = f2bf(b0.y); bf[2] = f2bf(b0.z); bf[3] = f2bf(b0.w);
      bf[4] = f2bf(b1.x); bf[5] = f2bf(b1.y); bf[6] = f2bf(b1.z); bf[7] = f2bf(b1.w);
      acc[nt] = __builtin_amdgcn_mfma_f32_16x16x32_bf16(af, bf, acc[nt], 0, 0, 0);
    }
  }
  #pragma unroll
  for (int nt = 0; nt < 4; ++nt)
    #pragma unroll
    for (int r = 0; r < 4; ++r)
      Cb[(size_t)(m0 + lg * 4 + r) * Dd + n0 + nt * 16 + l15] = acc[nt][r];
}

// ---------------------------------------------------------------------------
// bf16 MFMA GEMM (no LDS). Wave computes 16(M) x 64(N); block = 4 waves = 64x64.
// MODE 0: C = A @ B^T (+bias)(+res)          grid (Nc/64, M/64)
// MODE 1: QK^T*scale + biasT, safe-mask      grid (6, 6, B*H)
// MODE 2: C = A @ B  (B natural KxN, PV)     grid (1, 6, B*H)
// MODE 3: C = (a*gelu(g)) @ B^T (+bias)(+res), A rows = hff[m][0..512|512..1024]
// ---------------------------------------------------------------------------
template<int MODE>
__global__ __launch_bounds__(256) void gemm_mfma(
    const float* __restrict__ A, int lda,
    const float* __restrict__ Bm, int ldb,
    float* __restrict__ Cc, int ldc,
    const float* __restrict__ bias,
    const float* __restrict__ res, int ldr,
    int K,
    const float* __restrict__ biasT, const int* __restrict__ pmask,
    const int* __restrict__ valid)
{
  const int tid = threadIdx.x;
  const int lane = tid & 63;
  const int w   = tid >> 6;
  const int l15 = lane & 15, lg = lane >> 4;
  const int m0 = blockIdx.y * 64 + w * 16;
  const int n0 = blockIdx.x * 64;

  const float* Ab = A; const float* Bb = Bm; float* Cb = Cc;
  const float* biasTb = biasT; const int* pmb = pmask; const int* vlb = valid;
  if (MODE == 1 || MODE == 2) {
    const int bz = blockIdx.z;
    const int b = bz >> 2, h = bz & 3;
    if (MODE == 1) {
      Ab = A  + (size_t)b * Nn * Dd + h * DHh;
      Bb = Bm + (size_t)b * Nn * Dd + h * DHh;
      Cb = Cc + (size_t)bz * NSQ;
      biasTb = biasT + (size_t)bz * NSQ;
      pmb = pmask + (size_t)b * NSQ;
      vlb = valid + b * Nn;
    } else {
      Ab = A  + (size_t)bz * NSQ;
      Bb = Bm + (size_t)b * Nn * Dd + h * DHh;
      Cb = Cc + (size_t)b * Nn * Dd + h * DHh;
    }
  }

  f32x4 acc[4] = {};
  const float* pa = Ab + (size_t)(m0 + l15) * lda + lg * 8;

  for (int k0 = 0; k0 < K; k0 += 32) {
    short8 af;
    if (MODE == 3) {
      const float4 a0 = ld4(pa + k0);
      const float4 a1 = ld4(pa + k0 + 4);
      const float4 g0 = ld4(pa + 512 + k0);
      const float4 g1 = ld4(pa + 512 + k0 + 4);
      af[0] = f2bf(a0.x * gelu_f(g0.x)); af[1] = f2bf(a0.y * gelu_f(g0.y));
      af[2] = f2bf(a0.z * gelu_f(g0.z)); af[3] = f2bf(a0.w * gelu_f(g0.w));
      af[4] = f2bf(a1.x * gelu_f(g1.x)); af[5] = f2bf(a1.y * gelu_f(g1.y));
      af[6] = f2bf(a1.z * gelu_f(g1.z)); af[7] = f2bf(a1.w * gelu_f(g1.w));
    } else {
      const float4 a0 = ld4(pa + k0);
      const float4 a1 = ld4(pa + k0 + 4);
      af[0] = f2bf(a0.x); af[1] = f2bf(a0.y); af[2] = f2bf(a0.z); af[3] = f2bf(a0.w);
      af[4] = f2bf(a1.x); af[5] = f2bf(a1.y); af[6] = f2bf(a1.z); af[7] = f2bf(a1.w);
    }
    #pragma unroll
    for (int nt = 0; nt < 4; ++nt) {
      short8 bf;
      if (MODE != 2) {
        const float* pb = Bb + (size_t)(n0 + nt * 16 + l15) * ldb + k0 + lg * 8;
        const float4 b0 = ld4(pb);
        const float4 b1 = ld4(pb + 4);
        bf[0] = f2bf(b0.x); bf[1] = f2bf(b0.y); bf[2] = f2bf(b0.z); bf[3] = f2bf(b0.w);
        bf[4] = f2bf(b1.x); bf[5] = f2bf(b1.y); bf[6] = f2bf(b1.z); bf[7] = f2bf(b1.w);
      } else {
        const float* pb = Bb + (size_t)(k0 + lg * 8) * ldb + n0 + nt * 16 + l15;
        #pragma unroll
        for (int jj = 0; jj < 8; ++jj) bf[jj] = f2bf(pb[(size_t)jj * ldb]);
      }
      acc[nt] = __builtin_amdgcn_mfma_f32_16x16x32_bf16(af, bf, acc[nt], 0, 0, 0);
    }
  }

  #pragma unroll
  for (int nt = 0; nt < 4; ++nt) {
    #pragma unroll
    for (int r = 0; r < 4; ++r) {
      const int m = m0 + lg * 4 + r;
      const int n = n0 + nt * 16 + l15;
      float v = acc[nt][r];
      if (MODE == 0 || MODE == 3) {
        if (bias) v += bias[n];
        if (res)  v += res[(size_t)m * ldr + n];
        Cb[(size_t)m * ldc + n] = v;
      } else if (MODE == 1) {
        v = v * 0.125f + biasTb[(size_t)m * Nn + n];
        const bool safe = (pmb[(size_t)m * Nn + n] != 0) || (vlb[m] == 0 && m == n);
        Cb[(size_t)m * Nn + n] = safe ? v : NEG_MAX;
      } else {
        Cb[(size_t)m * ldc + n] = v;
      }
    }
  }
}

// ---------------------------------------------------------------------------
// Softmax + pair_mask re-mask + renormalize, in place. Wave per row (384).
// ---------------------------------------------------------------------------
__global__ __launch_bounds__(256) void softmax_kernel(
    float* __restrict__ att, const int* __restrict__ pm)
{
  const int row  = blockIdx.x * 4 + (threadIdx.x >> 6);   // [0, B*H*N)
  const int lane = threadIdx.x & 63;
  const int i  = row % Nn;
  const int bh = row / Nn;
  const int b  = bh / Hh;
  float* ar = att + (size_t)row * Nn;
  const int* pmr = pm + (size_t)b * NSQ + (size_t)i * Nn;

  float v[6];
  float mx = NEG_MAX;
  #pragma unroll
  for (int t = 0; t < 6; ++t) { v[t] = ar[lane + t * 64]; mx = fmaxf(mx, v[t]); }
  mx = wmax(mx);
  float s = 0.f;
  #pragma unroll
  for (int t = 0; t < 6; ++t) { v[t] = __expf(v[t] - mx); s += v[t]; }
  s = wsum(s);
  const float invs = 1.f / s;
  float s2 = 0.f;
  #pragma unroll
  for (int t = 0; t < 6; ++t) {
    const float pv = (float)pmr[lane + t * 64];
    v[t] = v[t] * invs * pv;
    s2 += v[t];
  }
  s2 = wsum(s2);
  const float r = 1.f / fmaxf(s2, 1e-6f);
  #pragma unroll
  for (int t = 0; t < 6; ++t) ar[lane + t * 64] = v[t] * r;
}

// ---------------------------------------------------------------------------
extern "C" void kernel_launch(void* const* d_in, const int* in_sizes, int n_in,
                              void* d_out, int out_size, void* d_ws, size_t ws_size,
                              hipStream_t stream) {
  const float* x    = (const float*)d_in[0];
  const int*   pm   = (const int*)  d_in[1];
  const int*   vld  = (const int*)  d_in[2];
  const float* cont = (const float*)d_in[3];
  const int* dbk = (const int*)d_in[4];
  const int* drk = (const int*)d_in[5];
  const int* rpk = (const int*)d_in[6];
  const int* hdk = (const int*)d_in[7];
  const int* etk = (const int*)d_in[8];
  const int* spk = (const int*)d_in[9];
  const int* sck = (const int*)d_in[10];
  const int* dgk = (const int*)d_in[11];
  const int* ctk = (const int*)d_in[12];
  const float* Wq  = (const float*)d_in[13];
  const float* Wk  = (const float*)d_in[14];
  const float* Wv  = (const float*)d_in[15];
  const float* Wo  = (const float*)d_in[16];
  const float* bo  = (const float*)d_in[17];
  const float* cmW1 = (const float*)d_in[18];
  const float* cmb1 = (const float*)d_in[19];
  const float* cmW2 = (const float*)d_in[20];
  const float* cmb2 = (const float*)d_in[21];
  const float* Ed  = (const float*)d_in[22];
  const float* Edi = (const float*)d_in[23];
  const float* Er  = (const float*)d_in[24];
  const float* Eh  = (const float*)d_in[25];
  const float* Ee  = (const float*)d_in[26];
  const float* Esp = (const float*)d_in[27];
  const float* Edg = (const float*)d_in[28];
  const float* Ec  = (const float*)d_in[29];
  const float* Es  = (const float*)d_in[30];
  const float* blng = (const float*)d_in[31];
  const float* blnb = (const float*)d_in[32];
  const float* bW   = (const float*)d_in[33];
  const float* bb_  = (const float*)d_in[34];
  const float* ln1g = (const float*)d_in[35];
  const float* ln1b = (const float*)d_in[36];
  const float* ln2g = (const float*)d_in[37];
  const float* ln2b = (const float*)d_in[38];
  const float* ffW1 = (const float*)d_in[39];
  const float* ffb1 = (const float*)d_in[40];
  const float* ffW2 = (const float*)d_in[41];
  const float* ffb2 = (const float*)d_in[42];

  float* out   = (float*)d_out;
  float* xout  = out;                       // 393216
  float* attn  = out + 393216;              // 2359296 (logits in place)
  float* biasO = out + 393216 + 2359296;    // 2359296

  float* ws  = (float*)d_ws;
  float* xn  = ws;                 // 393216  (ln1 out; reused for ln2 out)
  float* qb  = ws + 393216;        // 393216
  float* kb  = ws + 786432;        // 393216
  float* vb  = ws + 1179648;       // 393216
  float* ao  = ws + 1572864;       // 393216
  float* x1  = ws + 1966080;       // 393216
  float* hff = ws + 2359296;       // 1572864
  // pair-path scratch (in hff region; dead before FF1 writes hff)
  float* dc   = hff;               // 98304
  float* dcb  = hff + 98304;       // 98304
  float* w1p  = hff + 196608;      // 512
  unsigned short* w2bf = (unsigned short*)(hff + 197120);   // 2048 floats
  float* Edd  = hff + 199168;      // 5760
  float* Ers  = hff + 204928;      // 3840
  float* Ehes = hff + 208768;      // 3840 (ends 212608)

  // 0) prep: degcell(+b2), W2->bf16, W1 pack, combined tables
  prep_kernel<<<118, 256, 0, stream>>>(dgk, ctk, Edg, Ec, cmb2, cmW1, cmb1,
      cmW2, Ed, Edi, Er, Eh, Ee, Esp, Es, dc, dcb, w1p, w2bf, Edd, Ers, Ehes);
  // 1) pair bias (MFMA + fenced load batches)
  pair_kernel<<<9216, 256, 0, stream>>>(cont, pm, dbk, drk, rpk, hdk, etk, spk,
      sck, w1p, w2bf, Edd, Ers, Ehes, blng, blnb, bW, bb_, dc, dcb, biasO);
  // 2) ln1
  ln_kernel<<<384, 256, 0, stream>>>(x, ln1g, ln1b, xn);
  // 3) q, k, v projections (single launch)
  qkv_kernel<<<dim3(4, 24, 3), 256, 0, stream>>>(xn, Wq, Wk, Wv, qb, kb, vb);
  // 4) logits = qk^T*scale + bias, safe-masked -> attn region
  gemm_mfma<1><<<dim3(6, 6, 16), 256, 0, stream>>>(qb, 256, kb, 256, attn, 384,
      nullptr, nullptr, 0, 64, biasO, pm, vld);
  // 5) softmax + mask + renorm (in place)
  softmax_kernel<<<1536, 256, 0, stream>>>(attn, pm);
  // 6) PV
  gemm_mfma<2><<<dim3(1, 6, 16), 256, 0, stream>>>(attn, 384, vb, 256, ao, 256,
      nullptr, nullptr, 0, 384, nullptr, nullptr, nullptr);
  // 7) Wo + bo + residual(x) -> x1
  gemm_mfma<0><<<dim3(4, 24), 256, 0, stream>>>(ao, 256, Wo, 256, x1, 256,
      bo, x, 256, 256, nullptr, nullptr, nullptr);
  // 8) ln2 -> xn (reuse)
  ln_kernel<<<384, 256, 0, stream>>>(x1, ln2g, ln2b, xn);
  // 9) FF1
  gemm_mfma<0><<<dim3(16, 24), 256, 0, stream>>>(xn, 256, ffW1, 256, hff, 1024,
      ffb1, nullptr, 0, 256, nullptr, nullptr, nullptr);
  // 10) FF2 with fused gate (a*gelu(g)) + ffb2 + residual(x1) -> x_out
  gemm_mfma<3><<<dim3(4, 24), 256, 0, stream>>>(hff, 1024, ffW2, 512, xout, 256,
      ffb2, x1, 256, 512, nullptr, nullptr, nullptr);
}

// Round 10
// 266.120 us; speedup vs baseline: 1.9114x; 1.1536x over previous
//
#include <hip/hip_runtime.h>
#include <hip/hip_bf16.h>
#include <float.h>

// Problem constants
#define Bz   4
#define Nn   384
#define Dd   256
#define Hh   4
#define DHh  64
#define HIDn 64
#define NSQ  (384*384)
#define NEG_MAX (-3.40282346638528859812e+38f)

typedef __attribute__((ext_vector_type(8))) short short8;
typedef __attribute__((ext_vector_type(4))) float f32x4;
typedef __attribute__((ext_vector_type(2))) float f32x2;

// fast exact-gelu: erf via Abramowitz-Stegun 7.1.26 (|err| <= 1.5e-7)
__device__ __forceinline__ float gelu_f(float x){
  const float y = __builtin_fabsf(x) * 0.70710678118654752f;
  const float t = __builtin_amdgcn_rcpf(fmaf(0.3275911f, y, 1.0f));
  float poly = fmaf(1.061405429f, t, -1.453152027f);
  poly = fmaf(poly, t, 1.421413741f);
  poly = fmaf(poly, t, -0.284496736f);
  poly = fmaf(poly, t, 0.254829592f);
  poly *= t;
  const float e = __expf(-y * y);
  const float erfa = fmaf(-poly, e, 1.0f);          // erf(|y|)
  const float er = __builtin_copysignf(erfa, x);
  return 0.5f * x * (1.0f + er);
}
__device__ __forceinline__ float wsum(float v){
  #pragma unroll
  for (int o = 32; o > 0; o >>= 1) v += __shfl_xor(v, o, 64);
  return v;
}
__device__ __forceinline__ float wmax(float v){
  #pragma unroll
  for (int o = 32; o > 0; o >>= 1) v = fmaxf(v, __shfl_xor(v, o, 64));
  return v;
}
__device__ __forceinline__ float4 ld4(const float* p){ return *(const float4*)p; }
__device__ __forceinline__ f32x4 ldv4(const float* p){ return *(const f32x4*)p; }

// fp32 <-> bf16
__device__ __forceinline__ unsigned short f2bfu(float f){
  union { float f; unsigned u; } v; v.f = f;
  unsigned r = v.u + 0x7FFFu + ((v.u >> 16) & 1u);
  return (unsigned short)(r >> 16);
}
__device__ __forceinline__ short f2bf(float f){ return (short)f2bfu(f); }
__device__ __forceinline__ float bfe2f(unsigned short u){
  union { unsigned u; float f; } v; v.u = ((unsigned)u) << 16; return v.f;
}

// ---------------------------------------------------------------------------
// pack: ip[p] = {xdd, xrs, xhes, pm} (indices pre-combined and <<6)
// ---------------------------------------------------------------------------
__global__ __launch_bounds__(256) void pack_kernel(
    const int* __restrict__ dbk, const int* __restrict__ drk,
    const int* __restrict__ rpk, const int* __restrict__ hdk,
    const int* __restrict__ etk, const int* __restrict__ spk,
    const int* __restrict__ sck, const int* __restrict__ pm,
    int4* __restrict__ ip)
{
  const int p = blockIdx.x * 256 + threadIdx.x;   // 589824 = 2304*256
  int4 v;
  v.x = (dbk[p] * 10 + drk[p]) << 6;
  v.y = (rpk[p] * 6 + spk[p]) << 6;
  v.z = ((hdk[p] * 5 + etk[p]) * 3 + sck[p]) << 6;
  v.w = pm[p];
  ip[p] = v;
}

// ---------------------------------------------------------------------------
// prep: dc/dcb, w2bf, w1bf (bf16 {W1 row, b1, 0}), combined tables
// ---------------------------------------------------------------------------
__global__ __launch_bounds__(256) void prep_kernel(
    const int* __restrict__ dgk, const int* __restrict__ ctk,
    const float* __restrict__ Edg, const float* __restrict__ Ec,
    const float* __restrict__ b2,
    const float* __restrict__ W1, const float* __restrict__ b1,
    const float* __restrict__ W2,
    const float* __restrict__ Ed, const float* __restrict__ Edi,
    const float* __restrict__ Er, const float* __restrict__ Eh,
    const float* __restrict__ Ee, const float* __restrict__ Esp,
    const float* __restrict__ Es,
    float* __restrict__ dc, float* __restrict__ dcb,
    unsigned short* __restrict__ w1bf, unsigned short* __restrict__ w2bf,
    float* __restrict__ Edd, float* __restrict__ Ers,
    float* __restrict__ Ehes)
{
  const int idx = blockIdx.x * 256 + threadIdx.x;
  if (idx < 24576) {                       // dc / dcb
    const int row = idx >> 4;
    const int q   = (idx & 15) << 2;
    const float4 a = ld4(Edg + (dgk[row] << 6) + q);
    const float4 b = ld4(Ec  + (ctk[row] << 6) + q);
    float4 o; o.x = a.x + b.x; o.y = a.y + b.y; o.z = a.z + b.z; o.w = a.w + b.w;
    *(float4*)(dc + ((size_t)row << 6) + q) = o;
    const float4 bb4 = ld4(b2 + q);
    float4 o2; o2.x = o.x + bb4.x; o2.y = o.y + bb4.y;
    o2.z = o.z + bb4.z; o2.w = o.w + bb4.w;
    *(float4*)(dcb + ((size_t)row << 6) + q) = o2;
  } else if (idx < 26624) {                // w2bf
    const int t = idx - 24576;
    const int c = t >> 5, k2 = (t & 31) << 1;
    w2bf[c * 64 + k2]     = f2bfu(W2[c * 64 + k2]);
    w2bf[c * 64 + k2 + 1] = f2bfu(W2[c * 64 + k2 + 1]);
  } else if (idx < 26688) {                // w1bf
    const int k = idx - 26624;
    #pragma unroll
    for (int d = 0; d < 6; ++d) w1bf[k * 8 + d] = f2bfu(W1[k * 6 + d]);
    w1bf[k * 8 + 6] = f2bfu(b1[k]);
    w1bf[k * 8 + 7] = 0;
  } else if (idx < 28128) {                // Edd: 90 rows x 16 chunks
    const int t = idx - 26688;
    const int row = t >> 4, q = (t & 15) << 2;
    const int d = row / 10, r = row - d * 10;
    const float4 a = ld4(Ed + (d << 6) + q);
    const float4 b = ld4(Edi + (r << 6) + q);
    float4 o; o.x = a.x + b.x; o.y = a.y + b.y; o.z = a.z + b.z; o.w = a.w + b.w;
    *(float4*)(Edd + (row << 6) + q) = o;
  } else if (idx < 29088) {                // Ers: 60 rows x 16 chunks
    const int t = idx - 28128;
    const int row = t >> 4, q = (t & 15) << 2;
    const int ro = row / 6, s = row - ro * 6;
    const float4 a = ld4(Er + (ro << 6) + q);
    const float4 b = ld4(Esp + (s << 6) + q);
    float4 o; o.x = a.x + b.x; o.y = a.y + b.y; o.z = a.z + b.z; o.w = a.w + b.w;
    *(float4*)(Ers + (row << 6) + q) = o;
  } else if (idx < 30048) {                // Ehes: 60 rows x 16 chunks
    const int t = idx - 29088;
    const int row = t >> 4, q = (t & 15) << 2;
    const int h = row / 15, rem = row - h * 15;
    const int e = rem / 3, sm = rem - e * 3;
    const float4 a = ld4(Eh + (h << 6) + q);
    const float4 b = ld4(Ee + (e << 6) + q);
    const float4 c = ld4(Es + (sm << 6) + q);
    float4 o; o.x = a.x + b.x + c.x; o.y = a.y + b.y + c.y;
    o.z = a.z + b.z + c.z; o.w = a.w + b.w + c.w;
    *(float4*)(Ehes + (row << 6) + q) = o;
  }
}

// ---------------------------------------------------------------------------
// Fused pair kernel v10: wave = 32 pairs (2 tiles of 16).  Wave-invariant
// streams (w1bf rows, W2 A-frags, LN/bW consts, i-side dcb) issue ONCE per
// wave -> ~45% fewer VMEM ops per pair (TA-pipe-bound per R8/R9 evidence).
// ---------------------------------------------------------------------------
__global__ __launch_bounds__(256, 2) void pair_kernel(
    const float* __restrict__ cont, const int4* __restrict__ ip,
    const unsigned short* __restrict__ w1bf,
    const unsigned short* __restrict__ w2bf,
    const float* __restrict__ Edd, const float* __restrict__ Ers,
    const float* __restrict__ Ehes,
    const float* __restrict__ lng, const float* __restrict__ lnb,
    const float* __restrict__ bW, const float* __restrict__ bb,
    const float* __restrict__ dc, const float* __restrict__ dcb,
    float* __restrict__ biasOut)
{
  const int tid  = threadIdx.x;
  const int lane = tid & 63;
  const int l15  = lane & 15, lg = lane >> 4;
  const int wid  = blockIdx.x * 4 + (tid >> 6);              // [0, 18432)
  const int rowU = __builtin_amdgcn_readfirstlane(wid / 12); // b*N+i
  const int jb2  = wid - rowU * 12;
  const int b    = rowU / Nn;
  const int i    = rowU - b * Nn;
  const int j0   = jb2 * 32 + l15;
  const size_t p0 = (size_t)rowU * Nn + j0;
  const size_t p1 = p0 + 16;
  const int colOff = lg << 2;

  // ---- init: packed indices + cont for both tiles ----
  const int4 ix0 = ip[p0];
  const int4 ix1 = ip[p1];
  const float* cp0 = cont + p0 * 6;
  const float* cp1 = cont + p1 * 6;
  const f32x2 fA0 = *(const f32x2*)cp0, fB0 = *(const f32x2*)(cp0 + 2),
              fC0 = *(const f32x2*)(cp0 + 4);
  const f32x2 fA1 = *(const f32x2*)cp1, fB1 = *(const f32x2*)(cp1 + 2),
              fC1 = *(const f32x2*)(cp1 + 4);
  asm volatile("" :: "v"(ix0.x), "v"(ix0.y), "v"(ix0.z), "v"(ix0.w),
                     "v"(ix1.x), "v"(ix1.y), "v"(ix1.z), "v"(ix1.w),
                     "v"(fA0), "v"(fB0), "v"(fC0),
                     "v"(fA1), "v"(fB1), "v"(fC1));

  // ---- phase a: h1 for both tiles; w1bf rows loaded once ----
  short8 b00, b01, b10, b11;    // [tile][rowblock]
  #pragma unroll
  for (int rb = 0; rb < 2; ++rb) {
    const unsigned short* wb_ = w1bf + ((rb * 32 + (lg << 3)) << 3);
    const short8 r0 = *(const short8*)(wb_ +  0);
    const short8 r1 = *(const short8*)(wb_ +  8);
    const short8 r2 = *(const short8*)(wb_ + 16);
    const short8 r3 = *(const short8*)(wb_ + 24);
    const short8 r4 = *(const short8*)(wb_ + 32);
    const short8 r5 = *(const short8*)(wb_ + 40);
    const short8 r6 = *(const short8*)(wb_ + 48);
    const short8 r7 = *(const short8*)(wb_ + 56);
    asm volatile("" :: "v"(r0), "v"(r1), "v"(r2), "v"(r3),
                       "v"(r4), "v"(r5), "v"(r6), "v"(r7));
    short8& d0 = rb ? b01 : b00;
    short8& d1 = rb ? b11 : b10;
#define H1ROW(R, JJ) { \
    const float w0 = bfe2f((unsigned short)R[0]); \
    const float w1 = bfe2f((unsigned short)R[1]); \
    const float w2 = bfe2f((unsigned short)R[2]); \
    const float w3 = bfe2f((unsigned short)R[3]); \
    const float w4 = bfe2f((unsigned short)R[4]); \
    const float w5 = bfe2f((unsigned short)R[5]); \
    const float w6 = bfe2f((unsigned short)R[6]); \
    float s0 = w6, s1 = w6; \
    s0 = fmaf(w0, fA0[0], s0); s0 = fmaf(w1, fA0[1], s0); \
    s0 = fmaf(w2, fB0[0], s0); s0 = fmaf(w3, fB0[1], s0); \
    s0 = fmaf(w4, fC0[0], s0); s0 = fmaf(w5, fC0[1], s0); \
    s1 = fmaf(w0, fA1[0], s1); s1 = fmaf(w1, fA1[1], s1); \
    s1 = fmaf(w2, fB1[0], s1); s1 = fmaf(w3, fB1[1], s1); \
    s1 = fmaf(w4, fC1[0], s1); s1 = fmaf(w5, fC1[1], s1); \
    d0[JJ] = f2bf(gelu_f(s0)); d1[JJ] = f2bf(gelu_f(s1)); }
    H1ROW(r0, 0) H1ROW(r1, 1) H1ROW(r2, 2) H1ROW(r3, 3)
    H1ROW(r4, 4) H1ROW(r5, 5) H1ROW(r6, 6) H1ROW(r7, 7)
#undef H1ROW
  }

  // ---- phase b: A-frags once; 16 MFMAs (8 per tile) ----
  const unsigned short* wbase = w2bf + (size_t)l15 * 64 + (lg << 3);
  const short8 wa0 = *(const short8*)(wbase);
  const short8 wc0 = *(const short8*)(wbase + 32);
  const short8 wa1 = *(const short8*)(wbase + 16 * 64);
  const short8 wc1 = *(const short8*)(wbase + 16 * 64 + 32);
  const short8 wa2 = *(const short8*)(wbase + 32 * 64);
  const short8 wc2 = *(const short8*)(wbase + 32 * 64 + 32);
  const short8 wa3 = *(const short8*)(wbase + 48 * 64);
  const short8 wc3 = *(const short8*)(wbase + 48 * 64 + 32);
  asm volatile("" :: "v"(wa0), "v"(wc0), "v"(wa1), "v"(wc1),
                     "v"(wa2), "v"(wc2), "v"(wa3), "v"(wc3));
  f32x4 acc0[4] = {}, acc1[4] = {};
  acc0[0] = __builtin_amdgcn_mfma_f32_16x16x32_bf16(wa0, b00, acc0[0], 0, 0, 0);
  acc0[0] = __builtin_amdgcn_mfma_f32_16x16x32_bf16(wc0, b01, acc0[0], 0, 0, 0);
  acc0[1] = __builtin_amdgcn_mfma_f32_16x16x32_bf16(wa1, b00, acc0[1], 0, 0, 0);
  acc0[1] = __builtin_amdgcn_mfma_f32_16x16x32_bf16(wc1, b01, acc0[1], 0, 0, 0);
  acc0[2] = __builtin_amdgcn_mfma_f32_16x16x32_bf16(wa2, b00, acc0[2], 0, 0, 0);
  acc0[2] = __builtin_amdgcn_mfma_f32_16x16x32_bf16(wc2, b01, acc0[2], 0, 0, 0);
  acc0[3] = __builtin_amdgcn_mfma_f32_16x16x32_bf16(wa3, b00, acc0[3], 0, 0, 0);
  acc0[3] = __builtin_amdgcn_mfma_f32_16x16x32_bf16(wc3, b01, acc0[3], 0, 0, 0);
  acc1[0] = __builtin_amdgcn_mfma_f32_16x16x32_bf16(wa0, b10, acc1[0], 0, 0, 0);
  acc1[0] = __builtin_amdgcn_mfma_f32_16x16x32_bf16(wc0, b11, acc1[0], 0, 0, 0);
  acc1[1] = __builtin_amdgcn_mfma_f32_16x16x32_bf16(wa1, b10, acc1[1], 0, 0, 0);
  acc1[1] = __builtin_amdgcn_mfma_f32_16x16x32_bf16(wc1, b11, acc1[1], 0, 0, 0);
  acc1[2] = __builtin_amdgcn_mfma_f32_16x16x32_bf16(wa2, b10, acc1[2], 0, 0, 0);
  acc1[2] = __builtin_amdgcn_mfma_f32_16x16x32_bf16(wc2, b11, acc1[2], 0, 0, 0);
  acc1[3] = __builtin_amdgcn_mfma_f32_16x16x32_bf16(wa3, b10, acc1[3], 0, 0, 0);
  acc1[3] = __builtin_amdgcn_mfma_f32_16x16x32_bf16(wc3, b11, acc1[3], 0, 0, 0);

  // ---- phase c: i-side dcb once (shared); per-tile gathers ----
  const float* dcbp = dcb + ((size_t)rowU << 6);
  const f32x4 u0 = ldv4(dcbp + colOff);
  const f32x4 u1 = ldv4(dcbp + 16 + colOff);
  const f32x4 u2 = ldv4(dcbp + 32 + colOff);
  const f32x4 u3 = ldv4(dcbp + 48 + colOff);
  {
    const float* dcjp = dc + ((size_t)(b * Nn + j0) << 6);
    const f32x4 e0 = ldv4(Edd + ix0.x + colOff);
    const f32x4 e1 = ldv4(Edd + ix0.x + 16 + colOff);
    const f32x4 e2 = ldv4(Edd + ix0.x + 32 + colOff);
    const f32x4 e3 = ldv4(Edd + ix0.x + 48 + colOff);
    const f32x4 r0 = ldv4(Ers + ix0.y + colOff);
    const f32x4 r1 = ldv4(Ers + ix0.y + 16 + colOff);
    const f32x4 r2 = ldv4(Ers + ix0.y + 32 + colOff);
    const f32x4 r3 = ldv4(Ers + ix0.y + 48 + colOff);
    asm volatile("" :: "v"(e0), "v"(e1), "v"(e2), "v"(e3),
                       "v"(r0), "v"(r1), "v"(r2), "v"(r3));
    const f32x4 h0 = ldv4(Ehes + ix0.z + colOff);
    const f32x4 h1 = ldv4(Ehes + ix0.z + 16 + colOff);
    const f32x4 h2 = ldv4(Ehes + ix0.z + 32 + colOff);
    const f32x4 h3 = ldv4(Ehes + ix0.z + 48 + colOff);
    const f32x4 q0 = ldv4(dcjp + colOff);
    const f32x4 q1 = ldv4(dcjp + 16 + colOff);
    const f32x4 q2 = ldv4(dcjp + 32 + colOff);
    const f32x4 q3 = ldv4(dcjp + 48 + colOff);
    asm volatile("" :: "v"(h0), "v"(h1), "v"(h2), "v"(h3),
                       "v"(q0), "v"(q1), "v"(q2), "v"(q3));
    acc0[0] += e0 + r0 + h0 + q0 + u0;
    acc0[1] += e1 + r1 + h1 + q1 + u1;
    acc0[2] += e2 + r2 + h2 + q2 + u2;
    acc0[3] += e3 + r3 + h3 + q3 + u3;
  }
  {
    const float* dcjp = dc + ((size_t)(b * Nn + j0 + 16) << 6);
    const f32x4 e0 = ldv4(Edd + ix1.x + colOff);
    const f32x4 e1 = ldv4(Edd + ix1.x + 16 + colOff);
    const f32x4 e2 = ldv4(Edd + ix1.x + 32 + colOff);
    const f32x4 e3 = ldv4(Edd + ix1.x + 48 + colOff);
    const f32x4 r0 = ldv4(Ers + ix1.y + colOff);
    const f32x4 r1 = ldv4(Ers + ix1.y + 16 + colOff);
    const f32x4 r2 = ldv4(Ers + ix1.y + 32 + colOff);
    const f32x4 r3 = ldv4(Ers + ix1.y + 48 + colOff);
    asm volatile("" :: "v"(e0), "v"(e1), "v"(e2), "v"(e3),
                       "v"(r0), "v"(r1), "v"(r2), "v"(r3));
    const f32x4 h0 = ldv4(Ehes + ix1.z + colOff);
    const f32x4 h1 = ldv4(Ehes + ix1.z + 16 + colOff);
    const f32x4 h2 = ldv4(Ehes + ix1.z + 32 + colOff);
    const f32x4 h3 = ldv4(Ehes + ix1.z + 48 + colOff);
    const f32x4 q0 = ldv4(dcjp + colOff);
    const f32x4 q1 = ldv4(dcjp + 16 + colOff);
    const f32x4 q2 = ldv4(dcjp + 32 + colOff);
    const f32x4 q3 = ldv4(dcjp + 48 + colOff);
    asm volatile("" :: "v"(h0), "v"(h1), "v"(h2), "v"(h3),
                       "v"(q0), "v"(q1), "v"(q2), "v"(q3));
    acc1[0] += e0 + r0 + h0 + q0 + u0;
    acc1[1] += e1 + r1 + h1 + q1 + u1;
    acc1[2] += e2 + r2 + h2 + q2 + u2;
    acc1[3] += e3 + r3 + h3 + q3 + u3;
  }

  // ---- phase d: LN stats both tiles; consts loaded once per mt ----
  float sum0 = 0.f, sq0 = 0.f, sum1 = 0.f, sq1 = 0.f;
  #pragma unroll
  for (int mt = 0; mt < 4; ++mt)
    #pragma unroll
    for (int r = 0; r < 4; ++r) {
      const float v0 = acc0[mt][r], v1 = acc1[mt][r];
      sum0 += v0; sq0 = fmaf(v0, v0, sq0);
      sum1 += v1; sq1 = fmaf(v1, v1, sq1);
    }
  sum0 += __shfl_xor(sum0, 16, 64); sum0 += __shfl_xor(sum0, 32, 64);
  sq0  += __shfl_xor(sq0,  16, 64); sq0  += __shfl_xor(sq0,  32, 64);
  sum1 += __shfl_xor(sum1, 16, 64); sum1 += __shfl_xor(sum1, 32, 64);
  sq1  += __shfl_xor(sq1,  16, 64); sq1  += __shfl_xor(sq1,  32, 64);
  const float mean0 = sum0 * (1.f / 64.f);
  const float inv0  = rsqrtf(sq0 * (1.f / 64.f) - mean0 * mean0 + 1e-5f);
  const float mean1 = sum1 * (1.f / 64.f);
  const float inv1  = rsqrtf(sq1 * (1.f / 64.f) - mean1 * mean1 + 1e-5f);

  float a00 = 0.f, a01 = 0.f, a02 = 0.f, a03 = 0.f;
  float a10 = 0.f, a11 = 0.f, a12 = 0.f, a13 = 0.f;
  #pragma unroll
  for (int mt = 0; mt < 4; ++mt) {
    const int c0 = (mt << 4) + colOff;
    const f32x4 g4 = ldv4(lng + c0);
    const f32x4 b4 = ldv4(lnb + c0);
    const f32x4 w0 = ldv4(bW + c0);
    const f32x4 w1_ = ldv4(bW + 64 + c0);
    const f32x4 w2_ = ldv4(bW + 128 + c0);
    const f32x4 w3_ = ldv4(bW + 192 + c0);
    asm volatile("" :: "v"(g4), "v"(b4), "v"(w0), "v"(w1_), "v"(w2_), "v"(w3_));
    #pragma unroll
    for (int r = 0; r < 4; ++r) {
      const float g0 = gelu_f((acc0[mt][r] - mean0) * inv0 * g4[r] + b4[r]);
      a00 = fmaf(w0[r], g0, a00); a01 = fmaf(w1_[r], g0, a01);
      a02 = fmaf(w2_[r], g0, a02); a03 = fmaf(w3_[r], g0, a03);
      const float g1 = gelu_f((acc1[mt][r] - mean1) * inv1 * g4[r] + b4[r]);
      a10 = fmaf(w0[r], g1, a10); a11 = fmaf(w1_[r], g1, a11);
      a12 = fmaf(w2_[r], g1, a12); a13 = fmaf(w3_[r], g1, a13);
    }
  }
  a00 += __shfl_xor(a00, 16, 64); a00 += __shfl_xor(a00, 32, 64);
  a01 += __shfl_xor(a01, 16, 64); a01 += __shfl_xor(a01, 32, 64);
  a02 += __shfl_xor(a02, 16, 64); a02 += __shfl_xor(a02, 32, 64);
  a03 += __shfl_xor(a03, 16, 64); a03 += __shfl_xor(a03, 32, 64);
  a10 += __shfl_xor(a10, 16, 64); a10 += __shfl_xor(a10, 32, 64);
  a11 += __shfl_xor(a11, 16, 64); a11 += __shfl_xor(a11, 32, 64);
  a12 += __shfl_xor(a12, 16, 64); a12 += __shfl_xor(a12, 32, 64);
  a13 += __shfl_xor(a13, 16, 64); a13 += __shfl_xor(a13, 32, 64);

  const float bbl = bb[lg];
  const float bh0 = ((lg == 0) ? a00 : (lg == 1) ? a01 : (lg == 2) ? a02 : a03) + bbl;
  const float bh1 = ((lg == 0) ? a10 : (lg == 1) ? a11 : (lg == 2) ? a12 : a13) + bbl;
  const size_t base = (size_t)b * (Hh * NSQ) + (size_t)lg * NSQ + (size_t)i * Nn;
  biasOut[base + j0]      = bh0 * (ix0.w ? 1.f : 0.f);
  biasOut[base + j0 + 16] = bh1 * (ix1.w ? 1.f : 0.f);
}

// ---------------------------------------------------------------------------
// LayerNorm over last dim (256). One wave per row, 4 rows per block.
// ---------------------------------------------------------------------------
__global__ __launch_bounds__(256) void ln_kernel(
    const float* __restrict__ x, const float* __restrict__ g,
    const float* __restrict__ bta, float* __restrict__ o)
{
  const int row  = blockIdx.x * 4 + (threadIdx.x >> 6);
  const int lane = threadIdx.x & 63;
  const float4 v = *(const float4*)(x + (size_t)row * Dd + lane * 4);
  float s = v.x + v.y + v.z + v.w;
  s = wsum(s);
  const float m = s * (1.f / 256.f);
  const float dx = v.x - m, dy = v.y - m, dz = v.z - m, dw = v.w - m;
  float q = dx*dx + dy*dy + dz*dz + dw*dw;
  q = wsum(q);
  const float inv = rsqrtf(q * (1.f / 256.f) + 1e-5f);
  const int d = lane * 4;
  const float4 gg = *(const float4*)(g + d);
  const float4 bb = *(const float4*)(bta + d);
  float4 out;
  out.x = dx * inv * gg.x + bb.x;
  out.y = dy * inv * gg.y + bb.y;
  out.z = dz * inv * gg.z + bb.z;
  out.w = dw * inv * gg.w + bb.w;
  *(float4*)(o + (size_t)row * Dd + d) = out;
}

// ---------------------------------------------------------------------------
// Fused QKV projection: one launch, blockIdx.z selects {Wq->q, Wk->k, Wv->v}.
// ---------------------------------------------------------------------------
__global__ __launch_bounds__(256) void qkv_kernel(
    const float* __restrict__ xn,
    const float* __restrict__ Wq, const float* __restrict__ Wk,
    const float* __restrict__ Wv,
    float* __restrict__ qb, float* __restrict__ kb, float* __restrict__ vb)
{
  const int tid = threadIdx.x;
  const int lane = tid & 63;
  const int w   = tid >> 6;
  const int l15 = lane & 15, lg = lane >> 4;
  const int m0 = blockIdx.y * 64 + w * 16;
  const int n0 = blockIdx.x * 64;
  const int z  = blockIdx.z;
  const float* Bb = (z == 0) ? Wq : (z == 1) ? Wk : Wv;
  float* Cb = (z == 0) ? qb : (z == 1) ? kb : vb;

  f32x4 acc[4] = {};
  const float* pa = xn + (size_t)(m0 + l15) * Dd + lg * 8;
  for (int k0 = 0; k0 < Dd; k0 += 32) {
    short8 af;
    {
      const float4 a0 = ld4(pa + k0);
      const float4 a1 = ld4(pa + k0 + 4);
      af[0] = f2bf(a0.x); af[1] = f2bf(a0.y); af[2] = f2bf(a0.z); af[3] = f2bf(a0.w);
      af[4] = f2bf(a1.x); af[5] = f2bf(a1.y); af[6] = f2bf(a1.z); af[7] = f2bf(a1.w);
    }
    #pragma unroll
    for (int nt = 0; nt < 4; ++nt) {
      const float* pb = Bb + (size_t)(n0 + nt * 16 + l15) * Dd + k0 + lg * 8;
      const float4 b0 = ld4(pb);
      const float4 b1 = ld4(pb + 4);
      short8 bf;
      bf[0] = f2bf(b0.x); bf[1] = f2bf(b0.y); bf[2] = f2bf(b0.z); bf[3] = f2bf(b0.w);
      bf[4] = f2bf(b1.x); bf[5] = f2bf(b1.y); bf[6] = f2bf(b1.z); bf[7] = f2bf(b1.w);
      acc[nt] = __builtin_amdgcn_mfma_f32_16x16x32_bf16(af, bf, acc[nt], 0, 0, 0);
    }
  }
  #pragma unroll
  for (int nt = 0; nt < 4; ++nt)
    #pragma unroll
    for (int r = 0; r < 4; ++r)
      Cb[(size_t)(m0 + lg * 4 + r) * Dd + n0 + nt * 16 + l15] = acc[nt][r];
}

// ---------------------------------------------------------------------------
// bf16 MFMA GEMM (no LDS). Wave computes 16(M) x 64(N); block = 4 waves = 64x64.
// MODE 0: C = A @ B^T (+bias)(+res)          grid (Nc/64, M/64)
// MODE 1: QK^T*scale + biasT, safe-mask      grid (6, 6, B*H)
// MODE 2: C = A @ B  (B natural KxN, PV)     grid (1, 6, B*H)
// MODE 3: C = (a*gelu(g)) @ B^T (+bias)(+res)
// ---------------------------------------------------------------------------
template<int MODE>
__global__ __launch_bounds__(256) void gemm_mfma(
    const float* __restrict__ A, int lda,
    const float* __restrict__ Bm, int ldb,
    float* __restrict__ Cc, int ldc,
    const float* __restrict__ bias,
    const float* __restrict__ res, int ldr,
    int K,
    const float* __restrict__ biasT, const int* __restrict__ pmask,
    const int* __restrict__ valid)
{
  const int tid = threadIdx.x;
  const int lane = tid & 63;
  const int w   = tid >> 6;
  const int l15 = lane & 15, lg = lane >> 4;
  const int m0 = blockIdx.y * 64 + w * 16;
  const int n0 = blockIdx.x * 64;

  const float* Ab = A; const float* Bb = Bm; float* Cb = Cc;
  const float* biasTb = biasT; const int* pmb = pmask; const int* vlb = valid;
  if (MODE == 1 || MODE == 2) {
    const int bz = blockIdx.z;
    const int b = bz >> 2, h = bz & 3;
    if (MODE == 1) {
      Ab = A  + (size_t)b * Nn * Dd + h * DHh;
      Bb = Bm + (size_t)b * Nn * Dd + h * DHh;
      Cb = Cc + (size_t)bz * NSQ;
      biasTb = biasT + (size_t)bz * NSQ;
      pmb = pmask + (size_t)b * NSQ;
      vlb = valid + b * Nn;
    } else {
      Ab = A  + (size_t)bz * NSQ;
      Bb = Bm + (size_t)b * Nn * Dd + h * DHh;
      Cb = Cc + (size_t)b * Nn * Dd + h * DHh;
    }
  }

  f32x4 acc[4] = {};
  const float* pa = Ab + (size_t)(m0 + l15) * lda + lg * 8;

  for (int k0 = 0; k0 < K; k0 += 32) {
    short8 af;
    if (MODE == 3) {
      const float4 a0 = ld4(pa + k0);
      const float4 a1 = ld4(pa + k0 + 4);
      const float4 g0 = ld4(pa + 512 + k0);
      const float4 g1 = ld4(pa + 512 + k0 + 4);
      af[0] = f2bf(a0.x * gelu_f(g0.x)); af[1] = f2bf(a0.y * gelu_f(g0.y));
      af[2] = f2bf(a0.z * gelu_f(g0.z)); af[3] = f2bf(a0.w * gelu_f(g0.w));
      af[4] = f2bf(a1.x * gelu_f(g1.x)); af[5] = f2bf(a1.y * gelu_f(g1.y));
      af[6] = f2bf(a1.z * gelu_f(g1.z)); af[7] = f2bf(a1.w * gelu_f(g1.w));
    } else {
      const float4 a0 = ld4(pa + k0);
      const float4 a1 = ld4(pa + k0 + 4);
      af[0] = f2bf(a0.x); af[1] = f2bf(a0.y); af[2] = f2bf(a0.z); af[3] = f2bf(a0.w);
      af[4] = f2bf(a1.x); af[5] = f2bf(a1.y); af[6] = f2bf(a1.z); af[7] = f2bf(a1.w);
    }
    #pragma unroll
    for (int nt = 0; nt < 4; ++nt) {
      short8 bf;
      if (MODE != 2) {
        const float* pb = Bb + (size_t)(n0 + nt * 16 + l15) * ldb + k0 + lg * 8;
        const float4 b0 = ld4(pb);
        const float4 b1 = ld4(pb + 4);
        bf[0] = f2bf(b0.x); bf[1] = f2bf(b0.y); bf[2] = f2bf(b0.z); bf[3] = f2bf(b0.w);
        bf[4] = f2bf(b1.x); bf[5] = f2bf(b1.y); bf[6] = f2bf(b1.z); bf[7] = f2bf(b1.w);
      } else {
        const float* pb = Bb + (size_t)(k0 + lg * 8) * ldb + n0 + nt * 16 + l15;
        #pragma unroll
        for (int jj = 0; jj < 8; ++jj) bf[jj] = f2bf(pb[(size_t)jj * ldb]);
      }
      acc[nt] = __builtin_amdgcn_mfma_f32_16x16x32_bf16(af, bf, acc[nt], 0, 0, 0);
    }
  }

  #pragma unroll
  for (int nt = 0; nt < 4; ++nt) {
    #pragma unroll
    for (int r = 0; r < 4; ++r) {
      const int m = m0 + lg * 4 + r;
      const int n = n0 + nt * 16 + l15;
      float v = acc[nt][r];
      if (MODE == 0 || MODE == 3) {
        if (bias) v += bias[n];
        if (res)  v += res[(size_t)m * ldr + n];
        Cb[(size_t)m * ldc + n] = v;
      } else if (MODE == 1) {
        v = v * 0.125f + biasTb[(size_t)m * Nn + n];
        const bool safe = (pmb[(size_t)m * Nn + n] != 0) || (vlb[m] == 0 && m == n);
        Cb[(size_t)m * Nn + n] = safe ? v : NEG_MAX;
      } else {
        Cb[(size_t)m * ldc + n] = v;
      }
    }
  }
}

// ---------------------------------------------------------------------------
// Softmax + pair_mask re-mask + renormalize, in place. Wave per row (384).
// ---------------------------------------------------------------------------
__global__ __launch_bounds__(256) void softmax_kernel(
    float* __restrict__ att, const int* __restrict__ pm)
{
  const int row  = blockIdx.x * 4 + (threadIdx.x >> 6);   // [0, B*H*N)
  const int lane = threadIdx.x & 63;
  const int i  = row % Nn;
  const int bh = row / Nn;
  const int b  = bh / Hh;
  float* ar = att + (size_t)row * Nn;
  const int* pmr = pm + (size_t)b * NSQ + (size_t)i * Nn;

  float v[6];
  float mx = NEG_MAX;
  #pragma unroll
  for (int t = 0; t < 6; ++t) { v[t] = ar[lane + t * 64]; mx = fmaxf(mx, v[t]); }
  mx = wmax(mx);
  float s = 0.f;
  #pragma unroll
  for (int t = 0; t < 6; ++t) { v[t] = __expf(v[t] - mx); s += v[t]; }
  s = wsum(s);
  const float invs = 1.f / s;
  float s2 = 0.f;
  #pragma unroll
  for (int t = 0; t < 6; ++t) {
    const float pv = (float)pmr[lane + t * 64];
    v[t] = v[t] * invs * pv;
    s2 += v[t];
  }
  s2 = wsum(s2);
  const float r = 1.f / fmaxf(s2, 1e-6f);
  #pragma unroll
  for (int t = 0; t < 6; ++t) ar[lane + t * 64] = v[t] * r;
}

// ---------------------------------------------------------------------------
extern "C" void kernel_launch(void* const* d_in, const int* in_sizes, int n_in,
                              void* d_out, int out_size, void* d_ws, size_t ws_size,
                              hipStream_t stream) {
  const float* x    = (const float*)d_in[0];
  const int*   pm   = (const int*)  d_in[1];
  const int*   vld  = (const int*)  d_in[2];
  const float* cont = (const float*)d_in[3];
  const int* dbk = (const int*)d_in[4];
  const int* drk = (const int*)d_in[5];
  const int* rpk = (const int*)d_in[6];
  const int* hdk = (const int*)d_in[7];
  const int* etk = (const int*)d_in[8];
  const int* spk = (const int*)d_in[9];
  const int* sck = (const int*)d_in[10];
  const int* dgk = (const int*)d_in[11];
  const int* ctk = (const int*)d_in[12];
  const float* Wq  = (const float*)d_in[13];
  const float* Wk  = (const float*)d_in[14];
  const float* Wv  = (const float*)d_in[15];
  const float* Wo  = (const float*)d_in[16];
  const float* bo  = (const float*)d_in[17];
  const float* cmW1 = (const float*)d_in[18];
  const float* cmb1 = (const float*)d_in[19];
  const float* cmW2 = (const float*)d_in[20];
  const float* cmb2 = (const float*)d_in[21];
  const float* Ed  = (const float*)d_in[22];
  const float* Edi = (const float*)d_in[23];
  const float* Er  = (const float*)d_in[24];
  const float* Eh  = (const float*)d_in[25];
  const float* Ee  = (const float*)d_in[26];
  const float* Esp = (const float*)d_in[27];
  const float* Edg = (const float*)d_in[28];
  const float* Ec  = (const float*)d_in[29];
  const float* Es  = (const float*)d_in[30];
  const float* blng = (const float*)d_in[31];
  const float* blnb = (const float*)d_in[32];
  const float* bW   = (const float*)d_in[33];
  const float* bb_  = (const float*)d_in[34];
  const float* ln1g = (const float*)d_in[35];
  const float* ln1b = (const float*)d_in[36];
  const float* ln2g = (const float*)d_in[37];
  const float* ln2b = (const float*)d_in[38];
  const float* ffW1 = (const float*)d_in[39];
  const float* ffb1 = (const float*)d_in[40];
  const float* ffW2 = (const float*)d_in[41];
  const float* ffb2 = (const float*)d_in[42];

  float* out   = (float*)d_out;
  float* xout  = out;                       // 393216
  float* attn  = out + 393216;              // 2359296 (logits in place)
  float* biasO = out + 393216 + 2359296;    // 2359296

  float* ws  = (float*)d_ws;
  float* xn  = ws;                 // 393216  (ln1 out; reused for ln2 out)
  float* qb  = ws + 393216;        // 393216
  float* kb  = ws + 786432;        // 393216
  float* vb  = ws + 1179648;       // 393216
  float* ao  = ws + 1572864;       // 393216
  float* x1  = ws + 1966080;       // 393216
  float* hff = ws + 2359296;       // 1572864 (ends 3932160)
  // pair-path scratch: ip overlaps qb..x1+hff-head (all dead during pair);
  // tables live past ip's end, still inside hff region (dead before FF1).
  int4*  ipB  = (int4*)(ws + 393216);              // 589824 int4 -> ends 2752512
  float* dc   = ws + 2752512;                      // 98304  -> 2850816
  float* dcb  = ws + 2850816;                      // 98304  -> 2949120
  unsigned short* w1bf = (unsigned short*)(ws + 2949120);  // 512 ush -> 2949376
  unsigned short* w2bf = (unsigned short*)(ws + 2949376);  // 4096 ush -> 2951424
  float* Edd  = ws + 2951424;                      // 5760 -> 2957184
  float* Ers  = ws + 2957184;                      // 3840 -> 2961024
  float* Ehes = ws + 2961024;                      // 3840 -> 2964864

  // 0a) prep: degcell(+b2), W2->bf16, W1->bf16 pack, combined tables
  prep_kernel<<<118, 256, 0, stream>>>(dgk, ctk, Edg, Ec, cmb2, cmW1, cmb1,
      cmW2, Ed, Edi, Er, Eh, Ee, Esp, Es, dc, dcb, w1bf, w2bf, Edd, Ers, Ehes);
  // 0b) pack per-pair combined indices
  pack_kernel<<<2304, 256, 0, stream>>>(dbk, drk, rpk, hdk, etk, spk, sck, pm,
      ipB);
  // 1) pair bias (MFMA, 2 tiles/wave)
  pair_kernel<<<4608, 256, 0, stream>>>(cont, ipB, w1bf, w2bf, Edd, Ers, Ehes,
      blng, blnb, bW, bb_, dc, dcb, biasO);
  // 2) ln1
  ln_kernel<<<384, 256, 0, stream>>>(x, ln1g, ln1b, xn);
  // 3) q, k, v projections (single launch)
  qkv_kernel<<<dim3(4, 24, 3), 256, 0, stream>>>(xn, Wq, Wk, Wv, qb, kb, vb);
  // 4) logits = qk^T*scale + bias, safe-masked -> attn region
  gemm_mfma<1><<<dim3(6, 6, 16), 256, 0, stream>>>(qb, 256, kb, 256, attn, 384,
      nullptr, nullptr, 0, 64, biasO, pm, vld);
  // 5) softmax + mask + renorm (in place)
  softmax_kernel<<<1536, 256, 0, stream>>>(attn, pm);
  // 6) PV
  gemm_mfma<2><<<dim3(1, 6, 16), 256, 0, stream>>>(attn, 384, vb, 256, ao, 256,
      nullptr, nullptr, 0, 384, nullptr, nullptr, nullptr);
  // 7) Wo + bo + residual(x) -> x1
  gemm_mfma<0><<<dim3(4, 24), 256, 0, stream>>>(ao, 256, Wo, 256, x1, 256,
      bo, x, 256, 256, nullptr, nullptr, nullptr);
  // 8) ln2 -> xn (reuse)
  ln_kernel<<<384, 256, 0, stream>>>(x1, ln2g, ln2b, xn);
  // 9) FF1
  gemm_mfma<0><<<dim3(16, 24), 256, 0, stream>>>(xn, 256, ffW1, 256, hff, 1024,
      ffb1, nullptr, 0, 256, nullptr, nullptr, nullptr);
  // 10) FF2 with fused gate (a*gelu(g)) + ffb2 + residual(x1) -> x_out
  gemm_mfma<3><<<dim3(4, 24), 256, 0, stream>>>(hff, 1024, ffW2, 512, xout, 256,
      ffb2, x1, 256, 512, nullptr, nullptr, nullptr);
}

// Round 11
// 258.248 us; speedup vs baseline: 1.9697x; 1.0305x over previous
//
#include <hip/hip_runtime.h>
#include <hip/hip_bf16.h>
#include <float.h>

// Problem constants
#define Bz   4
#define Nn   384
#define Dd   256
#define Hh   4
#define DHh  64
#define HIDn 64
#define NSQ  (384*384)
#define NEG_MAX (-3.40282346638528859812e+38f)

typedef __attribute__((ext_vector_type(8))) short short8;
typedef __attribute__((ext_vector_type(4))) float f32x4;
typedef __attribute__((ext_vector_type(2))) float f32x2;

// fast exact-gelu: erf via Abramowitz-Stegun 7.1.26 (|err| <= 1.5e-7)
__device__ __forceinline__ float gelu_f(float x){
  const float y = __builtin_fabsf(x) * 0.70710678118654752f;
  const float t = __builtin_amdgcn_rcpf(fmaf(0.3275911f, y, 1.0f));
  float poly = fmaf(1.061405429f, t, -1.453152027f);
  poly = fmaf(poly, t, 1.421413741f);
  poly = fmaf(poly, t, -0.284496736f);
  poly = fmaf(poly, t, 0.254829592f);
  poly *= t;
  const float e = __expf(-y * y);
  const float erfa = fmaf(-poly, e, 1.0f);          // erf(|y|)
  const float er = __builtin_copysignf(erfa, x);
  return 0.5f * x * (1.0f + er);
}
__device__ __forceinline__ float wsum(float v){
  #pragma unroll
  for (int o = 32; o > 0; o >>= 1) v += __shfl_xor(v, o, 64);
  return v;
}
__device__ __forceinline__ float4 ld4(const float* p){ return *(const float4*)p; }
__device__ __forceinline__ f32x4 ldv4(const float* p){ return *(const f32x4*)p; }

// fp32 <-> bf16
__device__ __forceinline__ unsigned short f2bfu(float f){
  union { float f; unsigned u; } v; v.f = f;
  unsigned r = v.u + 0x7FFFu + ((v.u >> 16) & 1u);
  return (unsigned short)(r >> 16);
}
__device__ __forceinline__ short f2bf(float f){ return (short)f2bfu(f); }
__device__ __forceinline__ float bfe2f(unsigned short u){
  union { unsigned u; float f; } v; v.u = ((unsigned)u) << 16; return v.f;
}

// ---------------------------------------------------------------------------
// pack: ip[p] = {xdd, xrs, xhes, pm} (indices pre-combined and <<6)
// ---------------------------------------------------------------------------
__global__ __launch_bounds__(256) void pack_kernel(
    const int* __restrict__ dbk, const int* __restrict__ drk,
    const int* __restrict__ rpk, const int* __restrict__ hdk,
    const int* __restrict__ etk, const int* __restrict__ spk,
    const int* __restrict__ sck, const int* __restrict__ pm,
    int4* __restrict__ ip)
{
  const int p = blockIdx.x * 256 + threadIdx.x;   // 589824 = 2304*256
  int4 v;
  v.x = (dbk[p] * 10 + drk[p]) << 6;
  v.y = (rpk[p] * 6 + spk[p]) << 6;
  v.z = ((hdk[p] * 5 + etk[p]) * 3 + sck[p]) << 6;
  v.w = pm[p];
  ip[p] = v;
}

// ---------------------------------------------------------------------------
// prep: dc/dcb, w2bf, w1bf (bf16 {W1 row, b1, 0}), combined tables
// ---------------------------------------------------------------------------
__global__ __launch_bounds__(256) void prep_kernel(
    const int* __restrict__ dgk, const int* __restrict__ ctk,
    const float* __restrict__ Edg, const float* __restrict__ Ec,
    const float* __restrict__ b2,
    const float* __restrict__ W1, const float* __restrict__ b1,
    const float* __restrict__ W2,
    const float* __restrict__ Ed, const float* __restrict__ Edi,
    const float* __restrict__ Er, const float* __restrict__ Eh,
    const float* __restrict__ Ee, const float* __restrict__ Esp,
    const float* __restrict__ Es,
    float* __restrict__ dc, float* __restrict__ dcb,
    unsigned short* __restrict__ w1bf, unsigned short* __restrict__ w2bf,
    float* __restrict__ Edd, float* __restrict__ Ers,
    float* __restrict__ Ehes)
{
  const int idx = blockIdx.x * 256 + threadIdx.x;
  if (idx < 24576) {                       // dc / dcb
    const int row = idx >> 4;
    const int q   = (idx & 15) << 2;
    const float4 a = ld4(Edg + (dgk[row] << 6) + q);
    const float4 b = ld4(Ec  + (ctk[row] << 6) + q);
    float4 o; o.x = a.x + b.x; o.y = a.y + b.y; o.z = a.z + b.z; o.w = a.w + b.w;
    *(float4*)(dc + ((size_t)row << 6) + q) = o;
    const float4 bb4 = ld4(b2 + q);
    float4 o2; o2.x = o.x + bb4.x; o2.y = o.y + bb4.y;
    o2.z = o.z + bb4.z; o2.w = o.w + bb4.w;
    *(float4*)(dcb + ((size_t)row << 6) + q) = o2;
  } else if (idx < 26624) {                // w2bf
    const int t = idx - 24576;
    const int c = t >> 5, k2 = (t & 31) << 1;
    w2bf[c * 64 + k2]     = f2bfu(W2[c * 64 + k2]);
    w2bf[c * 64 + k2 + 1] = f2bfu(W2[c * 64 + k2 + 1]);
  } else if (idx < 26688) {                // w1bf
    const int k = idx - 26624;
    #pragma unroll
    for (int d = 0; d < 6; ++d) w1bf[k * 8 + d] = f2bfu(W1[k * 6 + d]);
    w1bf[k * 8 + 6] = f2bfu(b1[k]);
    w1bf[k * 8 + 7] = 0;
  } else if (idx < 28128) {                // Edd: 90 rows x 16 chunks
    const int t = idx - 26688;
    const int row = t >> 4, q = (t & 15) << 2;
    const int d = row / 10, r = row - d * 10;
    const float4 a = ld4(Ed + (d << 6) + q);
    const float4 b = ld4(Edi + (r << 6) + q);
    float4 o; o.x = a.x + b.x; o.y = a.y + b.y; o.z = a.z + b.z; o.w = a.w + b.w;
    *(float4*)(Edd + (row << 6) + q) = o;
  } else if (idx < 29088) {                // Ers: 60 rows x 16 chunks
    const int t = idx - 28128;
    const int row = t >> 4, q = (t & 15) << 2;
    const int ro = row / 6, s = row - ro * 6;
    const float4 a = ld4(Er + (ro << 6) + q);
    const float4 b = ld4(Esp + (s << 6) + q);
    float4 o; o.x = a.x + b.x; o.y = a.y + b.y; o.z = a.z + b.z; o.w = a.w + b.w;
    *(float4*)(Ers + (row << 6) + q) = o;
  } else if (idx < 30048) {                // Ehes: 60 rows x 16 chunks
    const int t = idx - 29088;
    const int row = t >> 4, q = (t & 15) << 2;
    const int h = row / 15, rem = row - h * 15;
    const int e = rem / 3, sm = rem - e * 3;
    const float4 a = ld4(Eh + (h << 6) + q);
    const float4 b = ld4(Ee + (e << 6) + q);
    const float4 c = ld4(Es + (sm << 6) + q);
    float4 o; o.x = a.x + b.x + c.x; o.y = a.y + b.y + c.y;
    o.z = a.z + b.z + c.z; o.w = a.w + b.w + c.w;
    *(float4*)(Ehes + (row << 6) + q) = o;
  }
}

// ---------------------------------------------------------------------------
// Fused pair kernel v10 (unchanged from R10): wave = 32 pairs (2 tiles).
// ---------------------------------------------------------------------------
__global__ __launch_bounds__(256, 2) void pair_kernel(
    const float* __restrict__ cont, const int4* __restrict__ ip,
    const unsigned short* __restrict__ w1bf,
    const unsigned short* __restrict__ w2bf,
    const float* __restrict__ Edd, const float* __restrict__ Ers,
    const float* __restrict__ Ehes,
    const float* __restrict__ lng, const float* __restrict__ lnb,
    const float* __restrict__ bW, const float* __restrict__ bb,
    const float* __restrict__ dc, const float* __restrict__ dcb,
    float* __restrict__ biasOut)
{
  const int tid  = threadIdx.x;
  const int lane = tid & 63;
  const int l15  = lane & 15, lg = lane >> 4;
  const int wid  = blockIdx.x * 4 + (tid >> 6);              // [0, 18432)
  const int rowU = __builtin_amdgcn_readfirstlane(wid / 12); // b*N+i
  const int jb2  = wid - rowU * 12;
  const int b    = rowU / Nn;
  const int i    = rowU - b * Nn;
  const int j0   = jb2 * 32 + l15;
  const size_t p0 = (size_t)rowU * Nn + j0;
  const size_t p1 = p0 + 16;
  const int colOff = lg << 2;

  const int4 ix0 = ip[p0];
  const int4 ix1 = ip[p1];
  const float* cp0 = cont + p0 * 6;
  const float* cp1 = cont + p1 * 6;
  const f32x2 fA0 = *(const f32x2*)cp0, fB0 = *(const f32x2*)(cp0 + 2),
              fC0 = *(const f32x2*)(cp0 + 4);
  const f32x2 fA1 = *(const f32x2*)cp1, fB1 = *(const f32x2*)(cp1 + 2),
              fC1 = *(const f32x2*)(cp1 + 4);
  asm volatile("" :: "v"(ix0.x), "v"(ix0.y), "v"(ix0.z), "v"(ix0.w),
                     "v"(ix1.x), "v"(ix1.y), "v"(ix1.z), "v"(ix1.w),
                     "v"(fA0), "v"(fB0), "v"(fC0),
                     "v"(fA1), "v"(fB1), "v"(fC1));

  short8 b00, b01, b10, b11;
  #pragma unroll
  for (int rb = 0; rb < 2; ++rb) {
    const unsigned short* wb_ = w1bf + ((rb * 32 + (lg << 3)) << 3);
    const short8 r0 = *(const short8*)(wb_ +  0);
    const short8 r1 = *(const short8*)(wb_ +  8);
    const short8 r2 = *(const short8*)(wb_ + 16);
    const short8 r3 = *(const short8*)(wb_ + 24);
    const short8 r4 = *(const short8*)(wb_ + 32);
    const short8 r5 = *(const short8*)(wb_ + 40);
    const short8 r6 = *(const short8*)(wb_ + 48);
    const short8 r7 = *(const short8*)(wb_ + 56);
    asm volatile("" :: "v"(r0), "v"(r1), "v"(r2), "v"(r3),
                       "v"(r4), "v"(r5), "v"(r6), "v"(r7));
    short8& d0 = rb ? b01 : b00;
    short8& d1 = rb ? b11 : b10;
#define H1ROW(R, JJ) { \
    const float w0 = bfe2f((unsigned short)R[0]); \
    const float w1 = bfe2f((unsigned short)R[1]); \
    const float w2 = bfe2f((unsigned short)R[2]); \
    const float w3 = bfe2f((unsigned short)R[3]); \
    const float w4 = bfe2f((unsigned short)R[4]); \
    const float w5 = bfe2f((unsigned short)R[5]); \
    const float w6 = bfe2f((unsigned short)R[6]); \
    float s0 = w6, s1 = w6; \
    s0 = fmaf(w0, fA0[0], s0); s0 = fmaf(w1, fA0[1], s0); \
    s0 = fmaf(w2, fB0[0], s0); s0 = fmaf(w3, fB0[1], s0); \
    s0 = fmaf(w4, fC0[0], s0); s0 = fmaf(w5, fC0[1], s0); \
    s1 = fmaf(w0, fA1[0], s1); s1 = fmaf(w1, fA1[1], s1); \
    s1 = fmaf(w2, fB1[0], s1); s1 = fmaf(w3, fB1[1], s1); \
    s1 = fmaf(w4, fC1[0], s1); s1 = fmaf(w5, fC1[1], s1); \
    d0[JJ] = f2bf(gelu_f(s0)); d1[JJ] = f2bf(gelu_f(s1)); }
    H1ROW(r0, 0) H1ROW(r1, 1) H1ROW(r2, 2) H1ROW(r3, 3)
    H1ROW(r4, 4) H1ROW(r5, 5) H1ROW(r6, 6) H1ROW(r7, 7)
#undef H1ROW
  }

  const unsigned short* wbase = w2bf + (size_t)l15 * 64 + (lg << 3);
  const short8 wa0 = *(const short8*)(wbase);
  const short8 wc0 = *(const short8*)(wbase + 32);
  const short8 wa1 = *(const short8*)(wbase + 16 * 64);
  const short8 wc1 = *(const short8*)(wbase + 16 * 64 + 32);
  const short8 wa2 = *(const short8*)(wbase + 32 * 64);
  const short8 wc2 = *(const short8*)(wbase + 32 * 64 + 32);
  const short8 wa3 = *(const short8*)(wbase + 48 * 64);
  const short8 wc3 = *(const short8*)(wbase + 48 * 64 + 32);
  asm volatile("" :: "v"(wa0), "v"(wc0), "v"(wa1), "v"(wc1),
                     "v"(wa2), "v"(wc2), "v"(wa3), "v"(wc3));
  f32x4 acc0[4] = {}, acc1[4] = {};
  acc0[0] = __builtin_amdgcn_mfma_f32_16x16x32_bf16(wa0, b00, acc0[0], 0, 0, 0);
  acc0[0] = __builtin_amdgcn_mfma_f32_16x16x32_bf16(wc0, b01, acc0[0], 0, 0, 0);
  acc0[1] = __builtin_amdgcn_mfma_f32_16x16x32_bf16(wa1, b00, acc0[1], 0, 0, 0);
  acc0[1] = __builtin_amdgcn_mfma_f32_16x16x32_bf16(wc1, b01, acc0[1], 0, 0, 0);
  acc0[2] = __builtin_amdgcn_mfma_f32_16x16x32_bf16(wa2, b00, acc0[2], 0, 0, 0);
  acc0[2] = __builtin_amdgcn_mfma_f32_16x16x32_bf16(wc2, b01, acc0[2], 0, 0, 0);
  acc0[3] = __builtin_amdgcn_mfma_f32_16x16x32_bf16(wa3, b00, acc0[3], 0, 0, 0);
  acc0[3] = __builtin_amdgcn_mfma_f32_16x16x32_bf16(wc3, b01, acc0[3], 0, 0, 0);
  acc1[0] = __builtin_amdgcn_mfma_f32_16x16x32_bf16(wa0, b10, acc1[0], 0, 0, 0);
  acc1[0] = __builtin_amdgcn_mfma_f32_16x16x32_bf16(wc0, b11, acc1[0], 0, 0, 0);
  acc1[1] = __builtin_amdgcn_mfma_f32_16x16x32_bf16(wa1, b10, acc1[1], 0, 0, 0);
  acc1[1] = __builtin_amdgcn_mfma_f32_16x16x32_bf16(wc1, b11, acc1[1], 0, 0, 0);
  acc1[2] = __builtin_amdgcn_mfma_f32_16x16x32_bf16(wa2, b10, acc1[2], 0, 0, 0);
  acc1[2] = __builtin_amdgcn_mfma_f32_16x16x32_bf16(wc2, b11, acc1[2], 0, 0, 0);
  acc1[3] = __builtin_amdgcn_mfma_f32_16x16x32_bf16(wa3, b10, acc1[3], 0, 0, 0);
  acc1[3] = __builtin_amdgcn_mfma_f32_16x16x32_bf16(wc3, b11, acc1[3], 0, 0, 0);

  const float* dcbp = dcb + ((size_t)rowU << 6);
  const f32x4 u0 = ldv4(dcbp + colOff);
  const f32x4 u1 = ldv4(dcbp + 16 + colOff);
  const f32x4 u2 = ldv4(dcbp + 32 + colOff);
  const f32x4 u3 = ldv4(dcbp + 48 + colOff);
  {
    const float* dcjp = dc + ((size_t)(b * Nn + j0) << 6);
    const f32x4 e0 = ldv4(Edd + ix0.x + colOff);
    const f32x4 e1 = ldv4(Edd + ix0.x + 16 + colOff);
    const f32x4 e2 = ldv4(Edd + ix0.x + 32 + colOff);
    const f32x4 e3 = ldv4(Edd + ix0.x + 48 + colOff);
    const f32x4 r0 = ldv4(Ers + ix0.y + colOff);
    const f32x4 r1 = ldv4(Ers + ix0.y + 16 + colOff);
    const f32x4 r2 = ldv4(Ers + ix0.y + 32 + colOff);
    const f32x4 r3 = ldv4(Ers + ix0.y + 48 + colOff);
    asm volatile("" :: "v"(e0), "v"(e1), "v"(e2), "v"(e3),
                       "v"(r0), "v"(r1), "v"(r2), "v"(r3));
    const f32x4 h0 = ldv4(Ehes + ix0.z + colOff);
    const f32x4 h1 = ldv4(Ehes + ix0.z + 16 + colOff);
    const f32x4 h2 = ldv4(Ehes + ix0.z + 32 + colOff);
    const f32x4 h3 = ldv4(Ehes + ix0.z + 48 + colOff);
    const f32x4 q0 = ldv4(dcjp + colOff);
    const f32x4 q1 = ldv4(dcjp + 16 + colOff);
    const f32x4 q2 = ldv4(dcjp + 32 + colOff);
    const f32x4 q3 = ldv4(dcjp + 48 + colOff);
    asm volatile("" :: "v"(h0), "v"(h1), "v"(h2), "v"(h3),
                       "v"(q0), "v"(q1), "v"(q2), "v"(q3));
    acc0[0] += e0 + r0 + h0 + q0 + u0;
    acc0[1] += e1 + r1 + h1 + q1 + u1;
    acc0[2] += e2 + r2 + h2 + q2 + u2;
    acc0[3] += e3 + r3 + h3 + q3 + u3;
  }
  {
    const float* dcjp = dc + ((size_t)(b * Nn + j0 + 16) << 6);
    const f32x4 e0 = ldv4(Edd + ix1.x + colOff);
    const f32x4 e1 = ldv4(Edd + ix1.x + 16 + colOff);
    const f32x4 e2 = ldv4(Edd + ix1.x + 32 + colOff);
    const f32x4 e3 = ldv4(Edd + ix1.x + 48 + colOff);
    const f32x4 r0 = ldv4(Ers + ix1.y + colOff);
    const f32x4 r1 = ldv4(Ers + ix1.y + 16 + colOff);
    const f32x4 r2 = ldv4(Ers + ix1.y + 32 + colOff);
    const f32x4 r3 = ldv4(Ers + ix1.y + 48 + colOff);
    asm volatile("" :: "v"(e0), "v"(e1), "v"(e2), "v"(e3),
                       "v"(r0), "v"(r1), "v"(r2), "v"(r3));
    const f32x4 h0 = ldv4(Ehes + ix1.z + colOff);
    const f32x4 h1 = ldv4(Ehes + ix1.z + 16 + colOff);
    const f32x4 h2 = ldv4(Ehes + ix1.z + 32 + colOff);
    const f32x4 h3 = ldv4(Ehes + ix1.z + 48 + colOff);
    const f32x4 q0 = ldv4(dcjp + colOff);
    const f32x4 q1 = ldv4(dcjp + 16 + colOff);
    const f32x4 q2 = ldv4(dcjp + 32 + colOff);
    const f32x4 q3 = ldv4(dcjp + 48 + colOff);
    asm volatile("" :: "v"(h0), "v"(h1), "v"(h2), "v"(h3),
                       "v"(q0), "v"(q1), "v"(q2), "v"(q3));
    acc1[0] += e0 + r0 + h0 + q0 + u0;
    acc1[1] += e1 + r1 + h1 + q1 + u1;
    acc1[2] += e2 + r2 + h2 + q2 + u2;
    acc1[3] += e3 + r3 + h3 + q3 + u3;
  }

  float sum0 = 0.f, sq0 = 0.f, sum1 = 0.f, sq1 = 0.f;
  #pragma unroll
  for (int mt = 0; mt < 4; ++mt)
    #pragma unroll
    for (int r = 0; r < 4; ++r) {
      const float v0 = acc0[mt][r], v1 = acc1[mt][r];
      sum0 += v0; sq0 = fmaf(v0, v0, sq0);
      sum1 += v1; sq1 = fmaf(v1, v1, sq1);
    }
  sum0 += __shfl_xor(sum0, 16, 64); sum0 += __shfl_xor(sum0, 32, 64);
  sq0  += __shfl_xor(sq0,  16, 64); sq0  += __shfl_xor(sq0,  32, 64);
  sum1 += __shfl_xor(sum1, 16, 64); sum1 += __shfl_xor(sum1, 32, 64);
  sq1  += __shfl_xor(sq1,  16, 64); sq1  += __shfl_xor(sq1,  32, 64);
  const float mean0 = sum0 * (1.f / 64.f);
  const float inv0  = rsqrtf(sq0 * (1.f / 64.f) - mean0 * mean0 + 1e-5f);
  const float mean1 = sum1 * (1.f / 64.f);
  const float inv1  = rsqrtf(sq1 * (1.f / 64.f) - mean1 * mean1 + 1e-5f);

  float a00 = 0.f, a01 = 0.f, a02 = 0.f, a03 = 0.f;
  float a10 = 0.f, a11 = 0.f, a12 = 0.f, a13 = 0.f;
  #pragma unroll
  for (int mt = 0; mt < 4; ++mt) {
    const int c0 = (mt << 4) + colOff;
    const f32x4 g4 = ldv4(lng + c0);
    const f32x4 b4 = ldv4(lnb + c0);
    const f32x4 w0 = ldv4(bW + c0);
    const f32x4 w1_ = ldv4(bW + 64 + c0);
    const f32x4 w2_ = ldv4(bW + 128 + c0);
    const f32x4 w3_ = ldv4(bW + 192 + c0);
    asm volatile("" :: "v"(g4), "v"(b4), "v"(w0), "v"(w1_), "v"(w2_), "v"(w3_));
    #pragma unroll
    for (int r = 0; r < 4; ++r) {
      const float g0 = gelu_f((acc0[mt][r] - mean0) * inv0 * g4[r] + b4[r]);
      a00 = fmaf(w0[r], g0, a00); a01 = fmaf(w1_[r], g0, a01);
      a02 = fmaf(w2_[r], g0, a02); a03 = fmaf(w3_[r], g0, a03);
      const float g1 = gelu_f((acc1[mt][r] - mean1) * inv1 * g4[r] + b4[r]);
      a10 = fmaf(w0[r], g1, a10); a11 = fmaf(w1_[r], g1, a11);
      a12 = fmaf(w2_[r], g1, a12); a13 = fmaf(w3_[r], g1, a13);
    }
  }
  a00 += __shfl_xor(a00, 16, 64); a00 += __shfl_xor(a00, 32, 64);
  a01 += __shfl_xor(a01, 16, 64); a01 += __shfl_xor(a01, 32, 64);
  a02 += __shfl_xor(a02, 16, 64); a02 += __shfl_xor(a02, 32, 64);
  a03 += __shfl_xor(a03, 16, 64); a03 += __shfl_xor(a03, 32, 64);
  a10 += __shfl_xor(a10, 16, 64); a10 += __shfl_xor(a10, 32, 64);
  a11 += __shfl_xor(a11, 16, 64); a11 += __shfl_xor(a11, 32, 64);
  a12 += __shfl_xor(a12, 16, 64); a12 += __shfl_xor(a12, 32, 64);
  a13 += __shfl_xor(a13, 16, 64); a13 += __shfl_xor(a13, 32, 64);

  const float bbl = bb[lg];
  const float bh0 = ((lg == 0) ? a00 : (lg == 1) ? a01 : (lg == 2) ? a02 : a03) + bbl;
  const float bh1 = ((lg == 0) ? a10 : (lg == 1) ? a11 : (lg == 2) ? a12 : a13) + bbl;
  const size_t base = (size_t)b * (Hh * NSQ) + (size_t)lg * NSQ + (size_t)i * Nn;
  biasOut[base + j0]      = bh0 * (ix0.w ? 1.f : 0.f);
  biasOut[base + j0 + 16] = bh1 * (ix1.w ? 1.f : 0.f);
}

// ---------------------------------------------------------------------------
// LayerNorm over last dim (256). One wave per row, 4 rows per block.
// ---------------------------------------------------------------------------
__global__ __launch_bounds__(256) void ln_kernel(
    const float* __restrict__ x, const float* __restrict__ g,
    const float* __restrict__ bta, float* __restrict__ o)
{
  const int row  = blockIdx.x * 4 + (threadIdx.x >> 6);
  const int lane = threadIdx.x & 63;
  const float4 v = *(const float4*)(x + (size_t)row * Dd + lane * 4);
  float s = v.x + v.y + v.z + v.w;
  s = wsum(s);
  const float m = s * (1.f / 256.f);
  const float dx = v.x - m, dy = v.y - m, dz = v.z - m, dw = v.w - m;
  float q = dx*dx + dy*dy + dz*dz + dw*dw;
  q = wsum(q);
  const float inv = rsqrtf(q * (1.f / 256.f) + 1e-5f);
  const int d = lane * 4;
  const float4 gg = *(const float4*)(g + d);
  const float4 bb = *(const float4*)(bta + d);
  float4 out;
  out.x = dx * inv * gg.x + bb.x;
  out.y = dy * inv * gg.y + bb.y;
  out.z = dz * inv * gg.z + bb.z;
  out.w = dw * inv * gg.w + bb.w;
  *(float4*)(o + (size_t)row * Dd + d) = out;
}

// ---------------------------------------------------------------------------
// Fused QKV projection: z selects {Wq->q, Wk->k, Wv->V^T(bf16)}.
// V^T layout: vbT[((b*4+h)*64+dh)*384 + tok], bf16 (PV B-frags = b128 loads).
// ---------------------------------------------------------------------------
__global__ __launch_bounds__(256) void qkv_kernel(
    const float* __restrict__ xn,
    const float* __restrict__ Wq, const float* __restrict__ Wk,
    const float* __restrict__ Wv,
    float* __restrict__ qb, float* __restrict__ kb,
    unsigned short* __restrict__ vbT)
{
  const int tid = threadIdx.x;
  const int lane = tid & 63;
  const int w   = tid >> 6;
  const int l15 = lane & 15, lg = lane >> 4;
  const int m0 = blockIdx.y * 64 + w * 16;
  const int n0 = blockIdx.x * 64;
  const int z  = blockIdx.z;
  const float* Bb = (z == 0) ? Wq : (z == 1) ? Wk : Wv;

  f32x4 acc[4] = {};
  const float* pa = xn + (size_t)(m0 + l15) * Dd + lg * 8;
  for (int k0 = 0; k0 < Dd; k0 += 32) {
    short8 af;
    {
      const float4 a0 = ld4(pa + k0);
      const float4 a1 = ld4(pa + k0 + 4);
      af[0] = f2bf(a0.x); af[1] = f2bf(a0.y); af[2] = f2bf(a0.z); af[3] = f2bf(a0.w);
      af[4] = f2bf(a1.x); af[5] = f2bf(a1.y); af[6] = f2bf(a1.z); af[7] = f2bf(a1.w);
    }
    #pragma unroll
    for (int nt = 0; nt < 4; ++nt) {
      const float* pb = Bb + (size_t)(n0 + nt * 16 + l15) * Dd + k0 + lg * 8;
      const float4 b0 = ld4(pb);
      const float4 b1 = ld4(pb + 4);
      short8 bf;
      bf[0] = f2bf(b0.x); bf[1] = f2bf(b0.y); bf[2] = f2bf(b0.z); bf[3] = f2bf(b0.w);
      bf[4] = f2bf(b1.x); bf[5] = f2bf(b1.y); bf[6] = f2bf(b1.z); bf[7] = f2bf(b1.w);
      acc[nt] = __builtin_amdgcn_mfma_f32_16x16x32_bf16(af, bf, acc[nt], 0, 0, 0);
    }
  }
  if (z < 2) {
    float* Cb = (z == 0) ? qb : kb;
    #pragma unroll
    for (int nt = 0; nt < 4; ++nt)
      #pragma unroll
      for (int r = 0; r < 4; ++r)
        Cb[(size_t)(m0 + lg * 4 + r) * Dd + n0 + nt * 16 + l15] = acc[nt][r];
  } else {
    // V^T bf16: rows = channel (b,h,dh), cols = token; 4 consecutive toks
    const int m = m0 + (lg << 2);
    const int b = m / Nn, tok = m - b * Nn;
    #pragma unroll
    for (int nt = 0; nt < 4; ++nt) {
      const int n = n0 + nt * 16 + l15;
      const int h = n >> 6, dh = n & 63;
      ushort4 s4;
      s4.x = f2bfu(acc[nt][0]); s4.y = f2bfu(acc[nt][1]);
      s4.z = f2bfu(acc[nt][2]); s4.w = f2bfu(acc[nt][3]);
      *(ushort4*)(vbT + ((size_t)((b * 4 + h) * 64 + dh)) * Nn + tok) = s4;
    }
  }
}

// ---------------------------------------------------------------------------
// bf16 MFMA GEMM (no LDS). Wave computes 16(M) x 64(N); block = 4 waves.
// MODE 0: C = A @ B^T (+bias)(+res)          grid (Nc/64, M/64)
// MODE 1: QK^T*scale + biasT, safe-mask      grid (6, 6, B*H)
// MODE 3: C = (a*gelu(g)) @ B^T (+bias)(+res)
// ---------------------------------------------------------------------------
template<int MODE>
__global__ __launch_bounds__(256) void gemm_mfma(
    const float* __restrict__ A, int lda,
    const float* __restrict__ Bm, int ldb,
    float* __restrict__ Cc, int ldc,
    const float* __restrict__ bias,
    const float* __restrict__ res, int ldr,
    int K,
    const float* __restrict__ biasT, const int* __restrict__ pmask,
    const int* __restrict__ valid)
{
  const int tid = threadIdx.x;
  const int lane = tid & 63;
  const int w   = tid >> 6;
  const int l15 = lane & 15, lg = lane >> 4;
  const int m0 = blockIdx.y * 64 + w * 16;
  const int n0 = blockIdx.x * 64;

  const float* Ab = A; const float* Bb = Bm; float* Cb = Cc;
  const float* biasTb = biasT; const int* pmb = pmask; const int* vlb = valid;
  if (MODE == 1) {
    const int bz = blockIdx.z;
    const int b = bz >> 2, h = bz & 3;
    Ab = A  + (size_t)b * Nn * Dd + h * DHh;
    Bb = Bm + (size_t)b * Nn * Dd + h * DHh;
    Cb = Cc + (size_t)bz * NSQ;
    biasTb = biasT + (size_t)bz * NSQ;
    pmb = pmask + (size_t)b * NSQ;
    vlb = valid + b * Nn;
  }

  f32x4 acc[4] = {};
  const float* pa = Ab + (size_t)(m0 + l15) * lda + lg * 8;

  for (int k0 = 0; k0 < K; k0 += 32) {
    short8 af;
    if (MODE == 3) {
      const float4 a0 = ld4(pa + k0);
      const float4 a1 = ld4(pa + k0 + 4);
      const float4 g0 = ld4(pa + 512 + k0);
      const float4 g1 = ld4(pa + 512 + k0 + 4);
      af[0] = f2bf(a0.x * gelu_f(g0.x)); af[1] = f2bf(a0.y * gelu_f(g0.y));
      af[2] = f2bf(a0.z * gelu_f(g0.z)); af[3] = f2bf(a0.w * gelu_f(g0.w));
      af[4] = f2bf(a1.x * gelu_f(g1.x)); af[5] = f2bf(a1.y * gelu_f(g1.y));
      af[6] = f2bf(a1.z * gelu_f(g1.z)); af[7] = f2bf(a1.w * gelu_f(g1.w));
    } else {
      const float4 a0 = ld4(pa + k0);
      const float4 a1 = ld4(pa + k0 + 4);
      af[0] = f2bf(a0.x); af[1] = f2bf(a0.y); af[2] = f2bf(a0.z); af[3] = f2bf(a0.w);
      af[4] = f2bf(a1.x); af[5] = f2bf(a1.y); af[6] = f2bf(a1.z); af[7] = f2bf(a1.w);
    }
    #pragma unroll
    for (int nt = 0; nt < 4; ++nt) {
      const float* pb = Bb + (size_t)(n0 + nt * 16 + l15) * ldb + k0 + lg * 8;
      const float4 b0 = ld4(pb);
      const float4 b1 = ld4(pb + 4);
      short8 bf;
      bf[0] = f2bf(b0.x); bf[1] = f2bf(b0.y); bf[2] = f2bf(b0.z); bf[3] = f2bf(b0.w);
      bf[4] = f2bf(b1.x); bf[5] = f2bf(b1.y); bf[6] = f2bf(b1.z); bf[7] = f2bf(b1.w);
      acc[nt] = __builtin_amdgcn_mfma_f32_16x16x32_bf16(af, bf, acc[nt], 0, 0, 0);
    }
  }

  #pragma unroll
  for (int nt = 0; nt < 4; ++nt) {
    #pragma unroll
    for (int r = 0; r < 4; ++r) {
      const int m = m0 + lg * 4 + r;
      const int n = n0 + nt * 16 + l15;
      float v = acc[nt][r];
      if (MODE == 0 || MODE == 3) {
        if (bias) v += bias[n];
        if (res)  v += res[(size_t)m * ldr + n];
        Cb[(size_t)m * ldc + n] = v;
      } else {
        v = v * 0.125f + biasTb[(size_t)m * Nn + n];
        const bool safe = (pmb[(size_t)m * Nn + n] != 0) || (vlb[m] == 0 && m == n);
        Cb[(size_t)m * Nn + n] = safe ? v : NEG_MAX;
      }
    }
  }
}

// ---------------------------------------------------------------------------
// Fused softmax + PV + attn-write. 1 wave per 16 q-rows. grid (24, B*H).
// Pass 1: stream logits+pm, online (m, sum_e, sum_e*pm) per lane, combine
//         across the 4 lg-groups (xor16/32).
// Pass 2: re-read logits (L2-hot), p = e*pm/max(sum_pm, 1e-6*sum_e);
//         write attn; feed P as bf16 A-frags into PV MFMAs (B = vbT b128).
// ---------------------------------------------------------------------------
__global__ __launch_bounds__(64) void pv_kernel(
    float* __restrict__ att, const int* __restrict__ pm,
    const unsigned short* __restrict__ vbT, float* __restrict__ ao)
{
  const int lane = threadIdx.x;
  const int l15 = lane & 15, lg = lane >> 4;
  const int bz = blockIdx.y;                 // b*4 + h
  const int b = bz >> 2, h = bz & 3;
  const int m0 = blockIdx.x * 16;            // q-row tile
  const int row = m0 + l15;
  float* ar = att + (size_t)bz * NSQ + (size_t)row * Nn;
  const int* pmr = pm + (size_t)b * NSQ + (size_t)row * Nn;

  // pass 1: online softmax stats over this lane's 96 cols (12 chunks of 8)
  float mr = NEG_MAX, sr = 0.f, spr = 0.f;
  for (int t = 0; t < 12; ++t) {
    const int c = t * 32 + lg * 8;
    const f32x4 v0 = ldv4(ar + c);
    const f32x4 v1 = ldv4(ar + c + 4);
    const int4 q0 = *(const int4*)(pmr + c);
    const int4 q1 = *(const int4*)(pmr + c + 4);
    float mc = fmaxf(fmaxf(fmaxf(v0[0], v0[1]), fmaxf(v0[2], v0[3])),
                     fmaxf(fmaxf(v1[0], v1[1]), fmaxf(v1[2], v1[3])));
    if (mc > mr) {
      const float sc = __expf(mr - mc);
      sr *= sc; spr *= sc; mr = mc;
    }
    float e;
    e = __expf(v0[0] - mr); sr += e; spr += q0.x ? e : 0.f;
    e = __expf(v0[1] - mr); sr += e; spr += q0.y ? e : 0.f;
    e = __expf(v0[2] - mr); sr += e; spr += q0.z ? e : 0.f;
    e = __expf(v0[3] - mr); sr += e; spr += q0.w ? e : 0.f;
    e = __expf(v1[0] - mr); sr += e; spr += q1.x ? e : 0.f;
    e = __expf(v1[1] - mr); sr += e; spr += q1.y ? e : 0.f;
    e = __expf(v1[2] - mr); sr += e; spr += q1.z ? e : 0.f;
    e = __expf(v1[3] - mr); sr += e; spr += q1.w ? e : 0.f;
  }
  #pragma unroll
  for (int o = 16; o <= 32; o <<= 1) {
    const float mo = __shfl_xor(mr, o, 64);
    const float so = __shfl_xor(sr, o, 64);
    const float spo = __shfl_xor(spr, o, 64);
    const float mn = fmaxf(mr, mo);
    const float s1 = __expf(mr - mn), s2 = __expf(mo - mn);
    sr = sr * s1 + so * s2;
    spr = spr * s1 + spo * s2;
    mr = mn;
  }
  const float rinv = 1.f / fmaxf(spr, 1e-6f * sr);

  // pass 2: finalize attn + PV
  f32x4 acc[4] = {};
  const unsigned short* vb0 = vbT + (size_t)(bz * 64) * Nn;
  for (int t = 0; t < 12; ++t) {
    const int c = t * 32 + lg * 8;
    const f32x4 v0 = ldv4(ar + c);
    const f32x4 v1 = ldv4(ar + c + 4);
    const int4 q0 = *(const int4*)(pmr + c);
    const int4 q1 = *(const int4*)(pmr + c + 4);
    f32x4 p0, p1;
    p0[0] = q0.x ? __expf(v0[0] - mr) * rinv : 0.f;
    p0[1] = q0.y ? __expf(v0[1] - mr) * rinv : 0.f;
    p0[2] = q0.z ? __expf(v0[2] - mr) * rinv : 0.f;
    p0[3] = q0.w ? __expf(v0[3] - mr) * rinv : 0.f;
    p1[0] = q1.x ? __expf(v1[0] - mr) * rinv : 0.f;
    p1[1] = q1.y ? __expf(v1[1] - mr) * rinv : 0.f;
    p1[2] = q1.z ? __expf(v1[2] - mr) * rinv : 0.f;
    p1[3] = q1.w ? __expf(v1[3] - mr) * rinv : 0.f;
    *(f32x4*)(ar + c) = p0;
    *(f32x4*)(ar + c + 4) = p1;
    short8 af;
    af[0] = f2bf(p0[0]); af[1] = f2bf(p0[1]); af[2] = f2bf(p0[2]); af[3] = f2bf(p0[3]);
    af[4] = f2bf(p1[0]); af[5] = f2bf(p1[1]); af[6] = f2bf(p1[2]); af[7] = f2bf(p1[3]);
    #pragma unroll
    for (int nt = 0; nt < 4; ++nt) {
      const short8 bf = *(const short8*)(vb0 + (size_t)(nt * 16 + l15) * Nn + c);
      acc[nt] = __builtin_amdgcn_mfma_f32_16x16x32_bf16(af, bf, acc[nt], 0, 0, 0);
    }
  }
  // epilogue: ao[(b*Nn + m0 + lg*4 + r)][h*64 + nt*16 + l15]
  #pragma unroll
  for (int nt = 0; nt < 4; ++nt)
    #pragma unroll
    for (int r = 0; r < 4; ++r)
      ao[(size_t)(b * Nn + m0 + lg * 4 + r) * Dd + h * 64 + nt * 16 + l15] =
          acc[nt][r];
}

// ---------------------------------------------------------------------------
extern "C" void kernel_launch(void* const* d_in, const int* in_sizes, int n_in,
                              void* d_out, int out_size, void* d_ws, size_t ws_size,
                              hipStream_t stream) {
  const float* x    = (const float*)d_in[0];
  const int*   pm   = (const int*)  d_in[1];
  const int*   vld  = (const int*)  d_in[2];
  const float* cont = (const float*)d_in[3];
  const int* dbk = (const int*)d_in[4];
  const int* drk = (const int*)d_in[5];
  const int* rpk = (const int*)d_in[6];
  const int* hdk = (const int*)d_in[7];
  const int* etk = (const int*)d_in[8];
  const int* spk = (const int*)d_in[9];
  const int* sck = (const int*)d_in[10];
  const int* dgk = (const int*)d_in[11];
  const int* ctk = (const int*)d_in[12];
  const float* Wq  = (const float*)d_in[13];
  const float* Wk  = (const float*)d_in[14];
  const float* Wv  = (const float*)d_in[15];
  const float* Wo  = (const float*)d_in[16];
  const float* bo  = (const float*)d_in[17];
  const float* cmW1 = (const float*)d_in[18];
  const float* cmb1 = (const float*)d_in[19];
  const float* cmW2 = (const float*)d_in[20];
  const float* cmb2 = (const float*)d_in[21];
  const float* Ed  = (const float*)d_in[22];
  const float* Edi = (const float*)d_in[23];
  const float* Er  = (const float*)d_in[24];
  const float* Eh  = (const float*)d_in[25];
  const float* Ee  = (const float*)d_in[26];
  const float* Esp = (const float*)d_in[27];
  const float* Edg = (const float*)d_in[28];
  const float* Ec  = (const float*)d_in[29];
  const float* Es  = (const float*)d_in[30];
  const float* blng = (const float*)d_in[31];
  const float* blnb = (const float*)d_in[32];
  const float* bW   = (const float*)d_in[33];
  const float* bb_  = (const float*)d_in[34];
  const float* ln1g = (const float*)d_in[35];
  const float* ln1b = (const float*)d_in[36];
  const float* ln2g = (const float*)d_in[37];
  const float* ln2b = (const float*)d_in[38];
  const float* ffW1 = (const float*)d_in[39];
  const float* ffb1 = (const float*)d_in[40];
  const float* ffW2 = (const float*)d_in[41];
  const float* ffb2 = (const float*)d_in[42];

  float* out   = (float*)d_out;
  float* xout  = out;                       // 393216
  float* attn  = out + 393216;              // 2359296 (logits in place)
  float* biasO = out + 393216 + 2359296;    // 2359296

  float* ws  = (float*)d_ws;
  float* xn  = ws;                 // 393216  (ln1 out; reused for ln2 out)
  float* qb  = ws + 393216;        // 393216
  float* kb  = ws + 786432;        // 393216
  unsigned short* vbT = (unsigned short*)(ws + 1179648);   // 393216 ush -> 196608 fl
  float* ao  = ws + 1572864;       // 393216
  float* x1  = ws + 1966080;       // 393216
  float* hff = ws + 2359296;       // 1572864 (ends 3932160)
  // pair-path scratch: ip overlaps qb..; tables past it (dead before FF1).
  int4*  ipB  = (int4*)(ws + 393216);              // ends 2752512
  float* dc   = ws + 2752512;                      // -> 2850816
  float* dcb  = ws + 2850816;                      // -> 2949120
  unsigned short* w1bf = (unsigned short*)(ws + 2949120);  // -> 2949376
  unsigned short* w2bf = (unsigned short*)(ws + 2949376);  // -> 2951424
  float* Edd  = ws + 2951424;                      // -> 2957184
  float* Ers  = ws + 2957184;                      // -> 2961024
  float* Ehes = ws + 2961024;                      // -> 2964864

  // 0a) prep
  prep_kernel<<<118, 256, 0, stream>>>(dgk, ctk, Edg, Ec, cmb2, cmW1, cmb1,
      cmW2, Ed, Edi, Er, Eh, Ee, Esp, Es, dc, dcb, w1bf, w2bf, Edd, Ers, Ehes);
  // 0b) pack per-pair combined indices
  pack_kernel<<<2304, 256, 0, stream>>>(dbk, drk, rpk, hdk, etk, spk, sck, pm,
      ipB);
  // 1) pair bias (MFMA, 2 tiles/wave)
  pair_kernel<<<4608, 256, 0, stream>>>(cont, ipB, w1bf, w2bf, Edd, Ers, Ehes,
      blng, blnb, bW, bb_, dc, dcb, biasO);
  // 2) ln1
  ln_kernel<<<384, 256, 0, stream>>>(x, ln1g, ln1b, xn);
  // 3) q, k, V^T projections (single launch)
  qkv_kernel<<<dim3(4, 24, 3), 256, 0, stream>>>(xn, Wq, Wk, Wv, qb, kb, vbT);
  // 4) logits = qk^T*scale + bias, safe-masked -> attn region
  gemm_mfma<1><<<dim3(6, 6, 16), 256, 0, stream>>>(qb, 256, kb, 256, attn, 384,
      nullptr, nullptr, 0, 64, biasO, pm, vld);
  // 5+6) fused softmax + attn finalize + PV
  pv_kernel<<<dim3(24, 16), 64, 0, stream>>>(attn, pm, vbT, ao);
  // 7) Wo + bo + residual(x) -> x1
  gemm_mfma<0><<<dim3(4, 24), 256, 0, stream>>>(ao, 256, Wo, 256, x1, 256,
      bo, x, 256, 256, nullptr, nullptr, nullptr);
  // 8) ln2 -> xn (reuse)
  ln_kernel<<<384, 256, 0, stream>>>(x1, ln2g, ln2b, xn);
  // 9) FF1
  gemm_mfma<0><<<dim3(16, 24), 256, 0, stream>>>(xn, 256, ffW1, 256, hff, 1024,
      ffb1, nullptr, 0, 256, nullptr, nullptr, nullptr);
  // 10) FF2 with fused gate (a*gelu(g)) + ffb2 + residual(x1) -> x_out
  gemm_mfma<3><<<dim3(4, 24), 256, 0, stream>>>(hff, 1024, ffW2, 512, xout, 256,
      ffb2, x1, 256, 512, nullptr, nullptr, nullptr);
}

// Round 12
// 197.362 us; speedup vs baseline: 2.5774x; 1.3085x over previous
//
#include <hip/hip_runtime.h>
#include <hip/hip_bf16.h>
#include <float.h>

// Problem constants
#define Bz   4
#define Nn   384
#define Dd   256
#define Hh   4
#define DHh  64
#define NSQ  (384*384)
#define NEG_MAX (-3.40282346638528859812e+38f)

typedef __attribute__((ext_vector_type(8))) short short8;
typedef __attribute__((ext_vector_type(4))) float f32x4;
typedef unsigned short ushort_t;

// fast exact-gelu: erf via Abramowitz-Stegun 7.1.26 (|err| <= 1.5e-7)
__device__ __forceinline__ float gelu_f(float x){
  const float y = __builtin_fabsf(x) * 0.70710678118654752f;
  const float t = __builtin_amdgcn_rcpf(fmaf(0.3275911f, y, 1.0f));
  float poly = fmaf(1.061405429f, t, -1.453152027f);
  poly = fmaf(poly, t, 1.421413741f);
  poly = fmaf(poly, t, -0.284496736f);
  poly = fmaf(poly, t, 0.254829592f);
  poly *= t;
  const float e = __expf(-y * y);
  const float erfa = fmaf(-poly, e, 1.0f);
  const float er = __builtin_copysignf(erfa, x);
  return 0.5f * x * (1.0f + er);
}
__device__ __forceinline__ float wsum(float v){
  #pragma unroll
  for (int o = 32; o > 0; o >>= 1) v += __shfl_xor(v, o, 64);
  return v;
}
__device__ __forceinline__ float4 ld4(const float* p){ return *(const float4*)p; }
__device__ __forceinline__ f32x4 ldv4(const float* p){ return *(const f32x4*)p; }

// fp32 <-> bf16
__device__ __forceinline__ ushort_t f2bfu(float f){
  union { float f; unsigned u; } v; v.f = f;
  unsigned r = v.u + 0x7FFFu + ((v.u >> 16) & 1u);
  return (ushort_t)(r >> 16);
}
__device__ __forceinline__ short f2bf(float f){ return (short)f2bfu(f); }
__device__ __forceinline__ float bfe2f(ushort_t u){
  union { unsigned u; float f; } v; v.u = ((unsigned)u) << 16; return v.f;
}
__device__ __forceinline__ void addbf(f32x4& a, f32x4& b, short8 v){
  a[0] += bfe2f((ushort_t)v[0]); a[1] += bfe2f((ushort_t)v[1]);
  a[2] += bfe2f((ushort_t)v[2]); a[3] += bfe2f((ushort_t)v[3]);
  b[0] += bfe2f((ushort_t)v[4]); b[1] += bfe2f((ushort_t)v[5]);
  b[2] += bfe2f((ushort_t)v[6]); b[3] += bfe2f((ushort_t)v[7]);
}

// ---------------------------------------------------------------------------
// pack: contP[p] = {6 x bf16 cont, u32 idx(xdd 7b | xrs 6b<<7 | xhes 6b<<13 |
//                   pm 1b<<19)}  -- one 16B record per pair
// ---------------------------------------------------------------------------
__global__ __launch_bounds__(256) void pack_kernel(
    const int* __restrict__ dbk, const int* __restrict__ drk,
    const int* __restrict__ rpk, const int* __restrict__ hdk,
    const int* __restrict__ etk, const int* __restrict__ spk,
    const int* __restrict__ sck, const int* __restrict__ pm,
    const float* __restrict__ cont, ushort_t* __restrict__ contP)
{
  const int p = blockIdx.x * 256 + threadIdx.x;   // 589824 = 2304*256
  const float* cp = cont + (size_t)p * 6;
  short8 r;
  r[0] = f2bf(cp[0]); r[1] = f2bf(cp[1]); r[2] = f2bf(cp[2]);
  r[3] = f2bf(cp[3]); r[4] = f2bf(cp[4]); r[5] = f2bf(cp[5]);
  const unsigned idx = (unsigned)(dbk[p] * 10 + drk[p])
                     | ((unsigned)(rpk[p] * 6 + spk[p]) << 7)
                     | ((unsigned)((hdk[p] * 5 + etk[p]) * 3 + sck[p]) << 13)
                     | ((pm[p] ? 1u : 0u) << 19);
  r[6] = (short)(idx & 0xffffu);
  r[7] = (short)(idx >> 16);
  *(short8*)(contP + (size_t)p * 8) = r;
}

// ---------------------------------------------------------------------------
// prep: permuted bf16 tables (pos = lg*16+mt*4+r), w1bf/w2bf, bf16 weights.
// ---------------------------------------------------------------------------
__global__ __launch_bounds__(256) void prep_kernel(
    const int* __restrict__ dgk, const int* __restrict__ ctk,
    const float* __restrict__ Edg, const float* __restrict__ Ec,
    const float* __restrict__ b2,
    const float* __restrict__ W1, const float* __restrict__ b1,
    const float* __restrict__ W2,
    const float* __restrict__ Ed, const float* __restrict__ Edi,
    const float* __restrict__ Er, const float* __restrict__ Eh,
    const float* __restrict__ Ee, const float* __restrict__ Esp,
    const float* __restrict__ Es,
    const float* __restrict__ Wq, const float* __restrict__ Wk,
    const float* __restrict__ Wv, const float* __restrict__ Wo,
    const float* __restrict__ ffW1, const float* __restrict__ ffW2,
    ushort_t* __restrict__ dcP, ushort_t* __restrict__ dcbP,
    ushort_t* __restrict__ w1bf, ushort_t* __restrict__ w2bf,
    ushort_t* __restrict__ EddP, ushort_t* __restrict__ ErsP,
    ushort_t* __restrict__ EhesP,
    ushort_t* __restrict__ wqB, ushort_t* __restrict__ wkB,
    ushort_t* __restrict__ wvB, ushort_t* __restrict__ woB,
    ushort_t* __restrict__ ffW1B, ushort_t* __restrict__ ffW2B)
{
  const int idx = blockIdx.x * 256 + threadIdx.x;
  if (idx < 24576) {                       // dcP / dcbP (permuted bf16)
    const int row = idx >> 4;
    const int q   = (idx & 15) << 2;
    const int pos = ((q >> 2) & 3) * 16 + (q >> 4) * 4;
    const float4 a = ld4(Edg + (dgk[row] << 6) + q);
    const float4 b = ld4(Ec  + (ctk[row] << 6) + q);
    const float4 bb4 = ld4(b2 + q);
    ushort4 o, o2;
    o.x = f2bfu(a.x + b.x); o.y = f2bfu(a.y + b.y);
    o.z = f2bfu(a.z + b.z); o.w = f2bfu(a.w + b.w);
    o2.x = f2bfu(a.x + b.x + bb4.x); o2.y = f2bfu(a.y + b.y + bb4.y);
    o2.z = f2bfu(a.z + b.z + bb4.z); o2.w = f2bfu(a.w + b.w + bb4.w);
    *(ushort4*)(dcP  + row * 64 + pos) = o;
    *(ushort4*)(dcbP + row * 64 + pos) = o2;
  } else if (idx < 26624) {                // w2bf [c][k]
    const int t = idx - 24576;
    const int c = t >> 5, k2 = (t & 31) << 1;
    w2bf[c * 64 + k2]     = f2bfu(W2[c * 64 + k2]);
    w2bf[c * 64 + k2 + 1] = f2bfu(W2[c * 64 + k2 + 1]);
  } else if (idx < 26688) {                // w1bf {W1 row, b1, 0} bf16
    const int k = idx - 26624;
    #pragma unroll
    for (int d = 0; d < 6; ++d) w1bf[k * 8 + d] = f2bfu(W1[k * 6 + d]);
    w1bf[k * 8 + 6] = f2bfu(b1[k]);
    w1bf[k * 8 + 7] = 0;
  } else if (idx < 28128) {                // EddP: 90 rows, permuted bf16
    const int t = idx - 26688;
    const int row = t >> 4, q = (t & 15) << 2;
    const int pos = ((q >> 2) & 3) * 16 + (q >> 4) * 4;
    const int d = row / 10, r = row - d * 10;
    const float4 a = ld4(Ed + (d << 6) + q);
    const float4 b = ld4(Edi + (r << 6) + q);
    ushort4 o;
    o.x = f2bfu(a.x + b.x); o.y = f2bfu(a.y + b.y);
    o.z = f2bfu(a.z + b.z); o.w = f2bfu(a.w + b.w);
    *(ushort4*)(EddP + row * 64 + pos) = o;
  } else if (idx < 29088) {                // ErsP: 60 rows
    const int t = idx - 28128;
    const int row = t >> 4, q = (t & 15) << 2;
    const int pos = ((q >> 2) & 3) * 16 + (q >> 4) * 4;
    const int ro = row / 6, s = row - ro * 6;
    const float4 a = ld4(Er + (ro << 6) + q);
    const float4 b = ld4(Esp + (s << 6) + q);
    ushort4 o;
    o.x = f2bfu(a.x + b.x); o.y = f2bfu(a.y + b.y);
    o.z = f2bfu(a.z + b.z); o.w = f2bfu(a.w + b.w);
    *(ushort4*)(ErsP + row * 64 + pos) = o;
  } else if (idx < 30048) {                // EhesP: 60 rows
    const int t = idx - 29088;
    const int row = t >> 4, q = (t & 15) << 2;
    const int pos = ((q >> 2) & 3) * 16 + (q >> 4) * 4;
    const int h = row / 15, rem = row - h * 15;
    const int e = rem / 3, sm = rem - e * 3;
    const float4 a = ld4(Eh + (h << 6) + q);
    const float4 b = ld4(Ee + (e << 6) + q);
    const float4 c = ld4(Es + (sm << 6) + q);
    ushort4 o;
    o.x = f2bfu(a.x + b.x + c.x); o.y = f2bfu(a.y + b.y + c.y);
    o.z = f2bfu(a.z + b.z + c.z); o.w = f2bfu(a.w + b.w + c.w);
    *(ushort4*)(EhesP + row * 64 + pos) = o;
  } else if (idx < 193888) {               // weight bf16 packs, 4 elems/thread
    const int t = idx - 30048;
    const float* src; ushort_t* dst; int e;
    if (t < 16384)      { src = Wq;   dst = wqB;   e = t << 2; }
    else if (t < 32768) { src = Wk;   dst = wkB;   e = (t - 16384) << 2; }
    else if (t < 49152) { src = Wv;   dst = wvB;   e = (t - 32768) << 2; }
    else if (t < 65536) { src = Wo;   dst = woB;   e = (t - 49152) << 2; }
    else if (t < 131072){ src = ffW1; dst = ffW1B; e = (t - 65536) << 2; }
    else                { src = ffW2; dst = ffW2B; e = (t - 131072) << 2; }
    const float4 v = ld4(src + e);
    ushort4 o;
    o.x = f2bfu(v.x); o.y = f2bfu(v.y); o.z = f2bfu(v.z); o.w = f2bfu(v.w);
    *(ushort4*)(dst + e) = o;
  }
}

// ---------------------------------------------------------------------------
// Fused pair kernel v11: wave = 64 pairs (4 tiles of 16).  Gathers from
// channel-permuted bf16 tables (2 x 16B per table per tile); init = one 16B
// record per tile; wave-invariant streams amortize over 64 pairs.
// ---------------------------------------------------------------------------
__global__ __launch_bounds__(256, 2) void pair_kernel(
    const ushort_t* __restrict__ contP,
    const ushort_t* __restrict__ w1bf, const ushort_t* __restrict__ w2bf,
    const ushort_t* __restrict__ EddP, const ushort_t* __restrict__ ErsP,
    const ushort_t* __restrict__ EhesP,
    const float* __restrict__ lng, const float* __restrict__ lnb,
    const float* __restrict__ bW, const float* __restrict__ bb,
    const ushort_t* __restrict__ dcP, const ushort_t* __restrict__ dcbP,
    float* __restrict__ biasOut)
{
  const int tid  = threadIdx.x;
  const int lane = tid & 63;
  const int l15  = lane & 15, lg = lane >> 4;
  const int wid  = blockIdx.x * 4 + (tid >> 6);             // [0, 9216)
  const int rowU = __builtin_amdgcn_readfirstlane(wid / 6); // b*N+i
  const int jb   = wid - rowU * 6;
  const int b    = rowU / Nn;
  const int i    = rowU - b * Nn;
  const int j0   = jb * 64 + l15;
  const size_t pbase = (size_t)rowU * Nn + j0;
  const int colOff = lg << 2;

  // ---- init: 1 record load per tile ----
  const short8 rec0 = *(const short8*)(contP + (pbase + 0) * 8);
  const short8 rec1 = *(const short8*)(contP + (pbase + 16) * 8);
  const short8 rec2 = *(const short8*)(contP + (pbase + 32) * 8);
  const short8 rec3 = *(const short8*)(contP + (pbase + 48) * 8);
  asm volatile("" :: "v"(rec0), "v"(rec1), "v"(rec2), "v"(rec3));
  const unsigned ix0 = (unsigned)(ushort_t)rec0[6] | ((unsigned)(ushort_t)rec0[7] << 16);
  const unsigned ix1 = (unsigned)(ushort_t)rec1[6] | ((unsigned)(ushort_t)rec1[7] << 16);
  const unsigned ix2 = (unsigned)(ushort_t)rec2[6] | ((unsigned)(ushort_t)rec2[7] << 16);
  const unsigned ix3 = (unsigned)(ushort_t)rec3[6] | ((unsigned)(ushort_t)rec3[7] << 16);
  const float c00 = bfe2f((ushort_t)rec0[0]), c01 = bfe2f((ushort_t)rec0[1]),
              c02 = bfe2f((ushort_t)rec0[2]), c03 = bfe2f((ushort_t)rec0[3]),
              c04 = bfe2f((ushort_t)rec0[4]), c05 = bfe2f((ushort_t)rec0[5]);
  const float c10 = bfe2f((ushort_t)rec1[0]), c11 = bfe2f((ushort_t)rec1[1]),
              c12 = bfe2f((ushort_t)rec1[2]), c13 = bfe2f((ushort_t)rec1[3]),
              c14 = bfe2f((ushort_t)rec1[4]), c15 = bfe2f((ushort_t)rec1[5]);
  const float c20 = bfe2f((ushort_t)rec2[0]), c21 = bfe2f((ushort_t)rec2[1]),
              c22 = bfe2f((ushort_t)rec2[2]), c23 = bfe2f((ushort_t)rec2[3]),
              c24 = bfe2f((ushort_t)rec2[4]), c25 = bfe2f((ushort_t)rec2[5]);
  const float c30 = bfe2f((ushort_t)rec3[0]), c31 = bfe2f((ushort_t)rec3[1]),
              c32 = bfe2f((ushort_t)rec3[2]), c33 = bfe2f((ushort_t)rec3[3]),
              c34 = bfe2f((ushort_t)rec3[4]), c35 = bfe2f((ushort_t)rec3[5]);

  // ---- phase a: h1 for 4 tiles; w1bf rows loaded once per wave ----
  short8 b0a, b0b, b1a, b1b, b2a, b2b, b3a, b3b;
#define H1ROW(R, JJ, D0, D1, D2, D3) { \
    const float w0 = bfe2f((ushort_t)R[0]), w1 = bfe2f((ushort_t)R[1]), \
                w2 = bfe2f((ushort_t)R[2]), w3 = bfe2f((ushort_t)R[3]), \
                w4 = bfe2f((ushort_t)R[4]), w5 = bfe2f((ushort_t)R[5]), \
                w6 = bfe2f((ushort_t)R[6]); \
    float s0 = w6, s1 = w6, s2 = w6, s3 = w6; \
    s0 = fmaf(w0, c00, s0); s0 = fmaf(w1, c01, s0); s0 = fmaf(w2, c02, s0); \
    s0 = fmaf(w3, c03, s0); s0 = fmaf(w4, c04, s0); s0 = fmaf(w5, c05, s0); \
    s1 = fmaf(w0, c10, s1); s1 = fmaf(w1, c11, s1); s1 = fmaf(w2, c12, s1); \
    s1 = fmaf(w3, c13, s1); s1 = fmaf(w4, c14, s1); s1 = fmaf(w5, c15, s1); \
    s2 = fmaf(w0, c20, s2); s2 = fmaf(w1, c21, s2); s2 = fmaf(w2, c22, s2); \
    s2 = fmaf(w3, c23, s2); s2 = fmaf(w4, c24, s2); s2 = fmaf(w5, c25, s2); \
    s3 = fmaf(w0, c30, s3); s3 = fmaf(w1, c31, s3); s3 = fmaf(w2, c32, s3); \
    s3 = fmaf(w3, c33, s3); s3 = fmaf(w4, c34, s3); s3 = fmaf(w5, c35, s3); \
    D0[JJ] = f2bf(gelu_f(s0)); D1[JJ] = f2bf(gelu_f(s1)); \
    D2[JJ] = f2bf(gelu_f(s2)); D3[JJ] = f2bf(gelu_f(s3)); }
  {
    const ushort_t* wb_ = w1bf + ((lg << 3) << 3);
    const short8 r0 = *(const short8*)(wb_ +  0);
    const short8 r1 = *(const short8*)(wb_ +  8);
    const short8 r2 = *(const short8*)(wb_ + 16);
    const short8 r3 = *(const short8*)(wb_ + 24);
    const short8 r4 = *(const short8*)(wb_ + 32);
    const short8 r5 = *(const short8*)(wb_ + 40);
    const short8 r6 = *(const short8*)(wb_ + 48);
    const short8 r7 = *(const short8*)(wb_ + 56);
    asm volatile("" :: "v"(r0), "v"(r1), "v"(r2), "v"(r3),
                       "v"(r4), "v"(r5), "v"(r6), "v"(r7));
    H1ROW(r0, 0, b0a, b1a, b2a, b3a) H1ROW(r1, 1, b0a, b1a, b2a, b3a)
    H1ROW(r2, 2, b0a, b1a, b2a, b3a) H1ROW(r3, 3, b0a, b1a, b2a, b3a)
    H1ROW(r4, 4, b0a, b1a, b2a, b3a) H1ROW(r5, 5, b0a, b1a, b2a, b3a)
    H1ROW(r6, 6, b0a, b1a, b2a, b3a) H1ROW(r7, 7, b0a, b1a, b2a, b3a)
  }
  {
    const ushort_t* wb_ = w1bf + ((32 + (lg << 3)) << 3);
    const short8 r0 = *(const short8*)(wb_ +  0);
    const short8 r1 = *(const short8*)(wb_ +  8);
    const short8 r2 = *(const short8*)(wb_ + 16);
    const short8 r3 = *(const short8*)(wb_ + 24);
    const short8 r4 = *(const short8*)(wb_ + 32);
    const short8 r5 = *(const short8*)(wb_ + 40);
    const short8 r6 = *(const short8*)(wb_ + 48);
    const short8 r7 = *(const short8*)(wb_ + 56);
    asm volatile("" :: "v"(r0), "v"(r1), "v"(r2), "v"(r3),
                       "v"(r4), "v"(r5), "v"(r6), "v"(r7));
    H1ROW(r0, 0, b0b, b1b, b2b, b3b) H1ROW(r1, 1, b0b, b1b, b2b, b3b)
    H1ROW(r2, 2, b0b, b1b, b2b, b3b) H1ROW(r3, 3, b0b, b1b, b2b, b3b)
    H1ROW(r4, 4, b0b, b1b, b2b, b3b) H1ROW(r5, 5, b0b, b1b, b2b, b3b)
    H1ROW(r6, 6, b0b, b1b, b2b, b3b) H1ROW(r7, 7, b0b, b1b, b2b, b3b)
  }
#undef H1ROW

  // ---- phase b: A-frags once; 32 MFMAs ----
  const ushort_t* wbase = w2bf + (size_t)l15 * 64 + (lg << 3);
  const short8 wa0 = *(const short8*)(wbase);
  const short8 wc0 = *(const short8*)(wbase + 32);
  const short8 wa1 = *(const short8*)(wbase + 16 * 64);
  const short8 wc1 = *(const short8*)(wbase + 16 * 64 + 32);
  const short8 wa2 = *(const short8*)(wbase + 32 * 64);
  const short8 wc2 = *(const short8*)(wbase + 32 * 64 + 32);
  const short8 wa3 = *(const short8*)(wbase + 48 * 64);
  const short8 wc3 = *(const short8*)(wbase + 48 * 64 + 32);
  asm volatile("" :: "v"(wa0), "v"(wc0), "v"(wa1), "v"(wc1),
                     "v"(wa2), "v"(wc2), "v"(wa3), "v"(wc3));
  f32x4 acc0[4] = {}, acc1[4] = {}, acc2[4] = {}, acc3[4] = {};
#define MM(ACC, BA, BB) \
  ACC[0] = __builtin_amdgcn_mfma_f32_16x16x32_bf16(wa0, BA, ACC[0], 0, 0, 0); \
  ACC[0] = __builtin_amdgcn_mfma_f32_16x16x32_bf16(wc0, BB, ACC[0], 0, 0, 0); \
  ACC[1] = __builtin_amdgcn_mfma_f32_16x16x32_bf16(wa1, BA, ACC[1], 0, 0, 0); \
  ACC[1] = __builtin_amdgcn_mfma_f32_16x16x32_bf16(wc1, BB, ACC[1], 0, 0, 0); \
  ACC[2] = __builtin_amdgcn_mfma_f32_16x16x32_bf16(wa2, BA, ACC[2], 0, 0, 0); \
  ACC[2] = __builtin_amdgcn_mfma_f32_16x16x32_bf16(wc2, BB, ACC[2], 0, 0, 0); \
  ACC[3] = __builtin_amdgcn_mfma_f32_16x16x32_bf16(wa3, BA, ACC[3], 0, 0, 0); \
  ACC[3] = __builtin_amdgcn_mfma_f32_16x16x32_bf16(wc3, BB, ACC[3], 0, 0, 0);
  MM(acc0, b0a, b0b) MM(acc1, b1a, b1b) MM(acc2, b2a, b2b) MM(acc3, b3a, b3b)
#undef MM

  // ---- phase c: permuted bf16 gathers, 8 ops per tile + shared dcb ----
#define GATHER(ACC, IX, JOFF) { \
    const int xdd  = ((IX) & 127) << 6; \
    const int xrs  = (((IX) >> 7) & 63) << 6; \
    const int xhes = (((IX) >> 13) & 63) << 6; \
    const ushort_t* ep = EddP  + xdd  + (lg << 4); \
    const ushort_t* rp = ErsP  + xrs  + (lg << 4); \
    const ushort_t* hp = EhesP + xhes + (lg << 4); \
    const ushort_t* jp = dcP + (((size_t)(b * Nn + j0 + (JOFF))) << 6) + (lg << 4); \
    const short8 e0 = *(const short8*)ep,       e1 = *(const short8*)(ep + 8); \
    const short8 r0 = *(const short8*)rp,       r1 = *(const short8*)(rp + 8); \
    const short8 h0 = *(const short8*)hp,       h1 = *(const short8*)(hp + 8); \
    const short8 jv0 = *(const short8*)jp,      jv1 = *(const short8*)(jp + 8); \
    asm volatile("" :: "v"(e0), "v"(e1), "v"(r0), "v"(r1), \
                       "v"(h0), "v"(h1), "v"(jv0), "v"(jv1)); \
    addbf(ACC[0], ACC[1], e0);  addbf(ACC[2], ACC[3], e1); \
    addbf(ACC[0], ACC[1], r0);  addbf(ACC[2], ACC[3], r1); \
    addbf(ACC[0], ACC[1], h0);  addbf(ACC[2], ACC[3], h1); \
    addbf(ACC[0], ACC[1], jv0); addbf(ACC[2], ACC[3], jv1); }
  GATHER(acc0, ix0, 0)
  GATHER(acc1, ix1, 16)
  GATHER(acc2, ix2, 32)
  GATHER(acc3, ix3, 48)
#undef GATHER
  {
    const ushort_t* up = dcbP + (((size_t)rowU) << 6) + (lg << 4);
    const short8 u0 = *(const short8*)up, u1 = *(const short8*)(up + 8);
    f32x4 du0, du1, du2, du3;
    #pragma unroll
    for (int r = 0; r < 4; ++r) {
      du0[r] = bfe2f((ushort_t)u0[r]);     du1[r] = bfe2f((ushort_t)u0[4 + r]);
      du2[r] = bfe2f((ushort_t)u1[r]);     du3[r] = bfe2f((ushort_t)u1[4 + r]);
    }
    acc0[0] += du0; acc0[1] += du1; acc0[2] += du2; acc0[3] += du3;
    acc1[0] += du0; acc1[1] += du1; acc1[2] += du2; acc1[3] += du3;
    acc2[0] += du0; acc2[1] += du1; acc2[2] += du2; acc2[3] += du3;
    acc3[0] += du0; acc3[1] += du1; acc3[2] += du2; acc3[3] += du3;
  }

  // ---- phase d: LN stats per tile (xor16/32 over lg) ----
  float mean0, inv0, mean1, inv1, mean2, inv2, mean3, inv3;
#define STATS(ACC, MEAN, INV) { \
    float sum = 0.f, sq = 0.f; \
    _Pragma("unroll") \
    for (int mt = 0; mt < 4; ++mt) \
      _Pragma("unroll") \
      for (int r = 0; r < 4; ++r) { \
        const float v = ACC[mt][r]; sum += v; sq = fmaf(v, v, sq); } \
    sum += __shfl_xor(sum, 16, 64); sum += __shfl_xor(sum, 32, 64); \
    sq  += __shfl_xor(sq,  16, 64); sq  += __shfl_xor(sq,  32, 64); \
    MEAN = sum * (1.f / 64.f); \
    INV  = rsqrtf(sq * (1.f / 64.f) - MEAN * MEAN + 1e-5f); }
  STATS(acc0, mean0, inv0) STATS(acc1, mean1, inv1)
  STATS(acc2, mean2, inv2) STATS(acc3, mean3, inv3)
#undef STATS

  float h00 = 0.f, h01 = 0.f, h02 = 0.f, h03 = 0.f;
  float h10 = 0.f, h11 = 0.f, h12 = 0.f, h13 = 0.f;
  float h20 = 0.f, h21 = 0.f, h22 = 0.f, h23 = 0.f;
  float h30 = 0.f, h31 = 0.f, h32 = 0.f, h33 = 0.f;
  #pragma unroll
  for (int mt = 0; mt < 4; ++mt) {
    const int c0i = (mt << 4) + colOff;
    const f32x4 g4 = ldv4(lng + c0i);
    const f32x4 b4 = ldv4(lnb + c0i);
    const f32x4 w0 = ldv4(bW + c0i);
    const f32x4 w1_ = ldv4(bW + 64 + c0i);
    const f32x4 w2_ = ldv4(bW + 128 + c0i);
    const f32x4 w3_ = ldv4(bW + 192 + c0i);
    asm volatile("" :: "v"(g4), "v"(b4), "v"(w0), "v"(w1_), "v"(w2_), "v"(w3_));
    #pragma unroll
    for (int r = 0; r < 4; ++r) {
      float g;
      g = gelu_f((acc0[mt][r] - mean0) * inv0 * g4[r] + b4[r]);
      h00 = fmaf(w0[r], g, h00); h01 = fmaf(w1_[r], g, h01);
      h02 = fmaf(w2_[r], g, h02); h03 = fmaf(w3_[r], g, h03);
      g = gelu_f((acc1[mt][r] - mean1) * inv1 * g4[r] + b4[r]);
      h10 = fmaf(w0[r], g, h10); h11 = fmaf(w1_[r], g, h11);
      h12 = fmaf(w2_[r], g, h12); h13 = fmaf(w3_[r], g, h13);
      g = gelu_f((acc2[mt][r] - mean2) * inv2 * g4[r] + b4[r]);
      h20 = fmaf(w0[r], g, h20); h21 = fmaf(w1_[r], g, h21);
      h22 = fmaf(w2_[r], g, h22); h23 = fmaf(w3_[r], g, h23);
      g = gelu_f((acc3[mt][r] - mean3) * inv3 * g4[r] + b4[r]);
      h30 = fmaf(w0[r], g, h30); h31 = fmaf(w1_[r], g, h31);
      h32 = fmaf(w2_[r], g, h32); h33 = fmaf(w3_[r], g, h33);
    }
  }
#define RED(H) H += __shfl_xor(H, 16, 64); H += __shfl_xor(H, 32, 64);
  RED(h00) RED(h01) RED(h02) RED(h03)
  RED(h10) RED(h11) RED(h12) RED(h13)
  RED(h20) RED(h21) RED(h22) RED(h23)
  RED(h30) RED(h31) RED(h32) RED(h33)
#undef RED

  const float bbl = bb[lg];
  const float bh0 = ((lg == 0) ? h00 : (lg == 1) ? h01 : (lg == 2) ? h02 : h03) + bbl;
  const float bh1 = ((lg == 0) ? h10 : (lg == 1) ? h11 : (lg == 2) ? h12 : h13) + bbl;
  const float bh2 = ((lg == 0) ? h20 : (lg == 1) ? h21 : (lg == 2) ? h22 : h23) + bbl;
  const float bh3 = ((lg == 0) ? h30 : (lg == 1) ? h31 : (lg == 2) ? h32 : h33) + bbl;
  const size_t base = (size_t)b * (Hh * NSQ) + (size_t)lg * NSQ + (size_t)i * Nn;
  biasOut[base + j0]      = bh0 * (((ix0 >> 19) & 1) ? 1.f : 0.f);
  biasOut[base + j0 + 16] = bh1 * (((ix1 >> 19) & 1) ? 1.f : 0.f);
  biasOut[base + j0 + 32] = bh2 * (((ix2 >> 19) & 1) ? 1.f : 0.f);
  biasOut[base + j0 + 48] = bh3 * (((ix3 >> 19) & 1) ? 1.f : 0.f);
}

// ---------------------------------------------------------------------------
// LayerNorm over last dim (256), bf16 output. One wave per row.
// ---------------------------------------------------------------------------
__global__ __launch_bounds__(256) void ln_kernel(
    const float* __restrict__ x, const float* __restrict__ g,
    const float* __restrict__ bta, ushort_t* __restrict__ o)
{
  const int row  = blockIdx.x * 4 + (threadIdx.x >> 6);
  const int lane = threadIdx.x & 63;
  const float4 v = *(const float4*)(x + (size_t)row * Dd + lane * 4);
  float s = v.x + v.y + v.z + v.w;
  s = wsum(s);
  const float m = s * (1.f / 256.f);
  const float dx = v.x - m, dy = v.y - m, dz = v.z - m, dw = v.w - m;
  float q = dx*dx + dy*dy + dz*dz + dw*dw;
  q = wsum(q);
  const float inv = rsqrtf(q * (1.f / 256.f) + 1e-5f);
  const int d = lane * 4;
  const float4 gg = *(const float4*)(g + d);
  const float4 bb = *(const float4*)(bta + d);
  ushort4 out;
  out.x = f2bfu(dx * inv * gg.x + bb.x);
  out.y = f2bfu(dy * inv * gg.y + bb.y);
  out.z = f2bfu(dz * inv * gg.z + bb.z);
  out.w = f2bfu(dw * inv * gg.w + bb.w);
  *(ushort4*)(o + (size_t)row * Dd + d) = out;
}

// ---------------------------------------------------------------------------
// Fused QKV: all-bf16 fragments. z: {wqB->qbB, wkB->kbB, wvB->vbT}.
// ---------------------------------------------------------------------------
__global__ __launch_bounds__(256) void qkv_kernel(
    const ushort_t* __restrict__ xnb,
    const ushort_t* __restrict__ wqB, const ushort_t* __restrict__ wkB,
    const ushort_t* __restrict__ wvB,
    ushort_t* __restrict__ qbB, ushort_t* __restrict__ kbB,
    ushort_t* __restrict__ vbT)
{
  const int tid = threadIdx.x;
  const int lane = tid & 63;
  const int w   = tid >> 6;
  const int l15 = lane & 15, lg = lane >> 4;
  const int m0 = blockIdx.y * 64 + w * 16;
  const int n0 = blockIdx.x * 64;
  const int z  = blockIdx.z;
  const ushort_t* Bb = (z == 0) ? wqB : (z == 1) ? wkB : wvB;

  f32x4 acc[4] = {};
  const ushort_t* pa = xnb + (size_t)(m0 + l15) * Dd + lg * 8;
  for (int k0 = 0; k0 < Dd; k0 += 32) {
    const short8 af = *(const short8*)(pa + k0);
    #pragma unroll
    for (int nt = 0; nt < 4; ++nt) {
      const short8 bf = *(const short8*)(Bb +
          (size_t)(n0 + nt * 16 + l15) * Dd + k0 + lg * 8);
      acc[nt] = __builtin_amdgcn_mfma_f32_16x16x32_bf16(af, bf, acc[nt], 0, 0, 0);
    }
  }
  if (z < 2) {
    ushort_t* Cb = (z == 0) ? qbB : kbB;
    #pragma unroll
    for (int nt = 0; nt < 4; ++nt)
      #pragma unroll
      for (int r = 0; r < 4; ++r)
        Cb[(size_t)(m0 + lg * 4 + r) * Dd + n0 + nt * 16 + l15] = f2bfu(acc[nt][r]);
  } else {
    const int m = m0 + (lg << 2);
    const int b = m / Nn, tok = m - b * Nn;
    #pragma unroll
    for (int nt = 0; nt < 4; ++nt) {
      const int n = n0 + nt * 16 + l15;
      const int h = n >> 6, dh = n & 63;
      ushort4 s4;
      s4.x = f2bfu(acc[nt][0]); s4.y = f2bfu(acc[nt][1]);
      s4.z = f2bfu(acc[nt][2]); s4.w = f2bfu(acc[nt][3]);
      *(ushort4*)(vbT + ((size_t)((b * 4 + h) * 64 + dh)) * Nn + tok) = s4;
    }
  }
}

// ---------------------------------------------------------------------------
// bf16-operand MFMA GEMM. Wave = 16(M) x 64(N); block = 4 waves.
// MODE 0: C(f32) = A16 @ B^T (+bias)(+res)   grid (Nc/64, M/64)
// MODE 1: QK^T*scale + biasT, safe-mask      grid (6, 6, B*H), A16/B bf16
// MODE 3: C = (a*gelu(g)) @ B^T (+bias)(+res), A32 = hff f32
// ---------------------------------------------------------------------------
template<int MODE>
__global__ __launch_bounds__(256) void gemm2(
    const ushort_t* __restrict__ A16, const float* __restrict__ A32, int lda,
    const ushort_t* __restrict__ Bm, int ldb,
    float* __restrict__ Cc, int ldc,
    const float* __restrict__ bias,
    const float* __restrict__ res, int ldr,
    int K,
    const float* __restrict__ biasT, const int* __restrict__ pmask,
    const int* __restrict__ valid)
{
  const int tid = threadIdx.x;
  const int lane = tid & 63;
  const int w   = tid >> 6;
  const int l15 = lane & 15, lg = lane >> 4;
  const int m0 = blockIdx.y * 64 + w * 16;
  const int n0 = blockIdx.x * 64;

  const ushort_t* Ab = A16; const ushort_t* Bb = Bm; float* Cb = Cc;
  const float* biasTb = biasT; const int* pmb = pmask; const int* vlb = valid;
  if (MODE == 1) {
    const int bz = blockIdx.z;
    const int b = bz >> 2, h = bz & 3;
    Ab = A16 + (size_t)b * Nn * Dd + h * DHh;
    Bb = Bm  + (size_t)b * Nn * Dd + h * DHh;
    Cb = Cc + (size_t)bz * NSQ;
    biasTb = biasT + (size_t)bz * NSQ;
    pmb = pmask + (size_t)b * NSQ;
    vlb = valid + b * Nn;
  }

  f32x4 acc[4] = {};
  const ushort_t* pa16 = Ab + (size_t)(m0 + l15) * lda + lg * 8;
  const float* pa32 = (MODE == 3) ? (A32 + (size_t)(m0 + l15) * lda + lg * 8) : nullptr;

  for (int k0 = 0; k0 < K; k0 += 32) {
    short8 af;
    if (MODE == 3) {
      const float4 a0 = ld4(pa32 + k0);
      const float4 a1 = ld4(pa32 + k0 + 4);
      const float4 g0 = ld4(pa32 + 512 + k0);
      const float4 g1 = ld4(pa32 + 512 + k0 + 4);
      af[0] = f2bf(a0.x * gelu_f(g0.x)); af[1] = f2bf(a0.y * gelu_f(g0.y));
      af[2] = f2bf(a0.z * gelu_f(g0.z)); af[3] = f2bf(a0.w * gelu_f(g0.w));
      af[4] = f2bf(a1.x * gelu_f(g1.x)); af[5] = f2bf(a1.y * gelu_f(g1.y));
      af[6] = f2bf(a1.z * gelu_f(g1.z)); af[7] = f2bf(a1.w * gelu_f(g1.w));
    } else {
      af = *(const short8*)(pa16 + k0);
    }
    #pragma unroll
    for (int nt = 0; nt < 4; ++nt) {
      const short8 bf = *(const short8*)(Bb +
          (size_t)(n0 + nt * 16 + l15) * ldb + k0 + lg * 8);
      acc[nt] = __builtin_amdgcn_mfma_f32_16x16x32_bf16(af, bf, acc[nt], 0, 0, 0);
    }
  }

  #pragma unroll
  for (int nt = 0; nt < 4; ++nt) {
    #pragma unroll
    for (int r = 0; r < 4; ++r) {
      const int m = m0 + lg * 4 + r;
      const int n = n0 + nt * 16 + l15;
      float v = acc[nt][r];
      if (MODE != 1) {
        if (bias) v += bias[n];
        if (res)  v += res[(size_t)m * ldr + n];
        Cb[(size_t)m * ldc + n] = v;
      } else {
        v = v * 0.125f + biasTb[(size_t)m * Nn + n];
        const bool safe = (pmb[(size_t)m * Nn + n] != 0) || (vlb[m] == 0 && m == n);
        Cb[(size_t)m * Nn + n] = safe ? v : NEG_MAX;
      }
    }
  }
}

// ---------------------------------------------------------------------------
// Fused softmax + PV + attn-write -> aoB bf16. 1 wave per 16 q-rows.
// ---------------------------------------------------------------------------
__global__ __launch_bounds__(64) void pv_kernel(
    float* __restrict__ att, const int* __restrict__ pm,
    const ushort_t* __restrict__ vbT, ushort_t* __restrict__ aoB)
{
  const int lane = threadIdx.x;
  const int l15 = lane & 15, lg = lane >> 4;
  const int bz = blockIdx.y;
  const int b = bz >> 2, h = bz & 3;
  const int m0 = blockIdx.x * 16;
  const int row = m0 + l15;
  float* ar = att + (size_t)bz * NSQ + (size_t)row * Nn;
  const int* pmr = pm + (size_t)b * NSQ + (size_t)row * Nn;

  float mr = NEG_MAX, sr = 0.f, spr = 0.f;
  for (int t = 0; t < 12; ++t) {
    const int c = t * 32 + lg * 8;
    const f32x4 v0 = ldv4(ar + c);
    const f32x4 v1 = ldv4(ar + c + 4);
    const int4 q0 = *(const int4*)(pmr + c);
    const int4 q1 = *(const int4*)(pmr + c + 4);
    float mc = fmaxf(fmaxf(fmaxf(v0[0], v0[1]), fmaxf(v0[2], v0[3])),
                     fmaxf(fmaxf(v1[0], v1[1]), fmaxf(v1[2], v1[3])));
    if (mc > mr) {
      const float sc = __expf(mr - mc);
      sr *= sc; spr *= sc; mr = mc;
    }
    float e;
    e = __expf(v0[0] - mr); sr += e; spr += q0.x ? e : 0.f;
    e = __expf(v0[1] - mr); sr += e; spr += q0.y ? e : 0.f;
    e = __expf(v0[2] - mr); sr += e; spr += q0.z ? e : 0.f;
    e = __expf(v0[3] - mr); sr += e; spr += q0.w ? e : 0.f;
    e = __expf(v1[0] - mr); sr += e; spr += q1.x ? e : 0.f;
    e = __expf(v1[1] - mr); sr += e; spr += q1.y ? e : 0.f;
    e = __expf(v1[2] - mr); sr += e; spr += q1.z ? e : 0.f;
    e = __expf(v1[3] - mr); sr += e; spr += q1.w ? e : 0.f;
  }
  #pragma unroll
  for (int o = 16; o <= 32; o <<= 1) {
    const float mo = __shfl_xor(mr, o, 64);
    const float so = __shfl_xor(sr, o, 64);
    const float spo = __shfl_xor(spr, o, 64);
    const float mn = fmaxf(mr, mo);
    const float s1 = __expf(mr - mn), s2 = __expf(mo - mn);
    sr = sr * s1 + so * s2;
    spr = spr * s1 + spo * s2;
    mr = mn;
  }
  const float rinv = 1.f / fmaxf(spr, 1e-6f * sr);

  f32x4 acc[4] = {};
  const ushort_t* vb0 = vbT + (size_t)(bz * 64) * Nn;
  for (int t = 0; t < 12; ++t) {
    const int c = t * 32 + lg * 8;
    const f32x4 v0 = ldv4(ar + c);
    const f32x4 v1 = ldv4(ar + c + 4);
    const int4 q0 = *(const int4*)(pmr + c);
    const int4 q1 = *(const int4*)(pmr + c + 4);
    f32x4 p0, p1;
    p0[0] = q0.x ? __expf(v0[0] - mr) * rinv : 0.f;
    p0[1] = q0.y ? __expf(v0[1] - mr) * rinv : 0.f;
    p0[2] = q0.z ? __expf(v0[2] - mr) * rinv : 0.f;
    p0[3] = q0.w ? __expf(v0[3] - mr) * rinv : 0.f;
    p1[0] = q1.x ? __expf(v1[0] - mr) * rinv : 0.f;
    p1[1] = q1.y ? __expf(v1[1] - mr) * rinv : 0.f;
    p1[2] = q1.z ? __expf(v1[2] - mr) * rinv : 0.f;
    p1[3] = q1.w ? __expf(v1[3] - mr) * rinv : 0.f;
    *(f32x4*)(ar + c) = p0;
    *(f32x4*)(ar + c + 4) = p1;
    short8 af;
    af[0] = f2bf(p0[0]); af[1] = f2bf(p0[1]); af[2] = f2bf(p0[2]); af[3] = f2bf(p0[3]);
    af[4] = f2bf(p1[0]); af[5] = f2bf(p1[1]); af[6] = f2bf(p1[2]); af[7] = f2bf(p1[3]);
    #pragma unroll
    for (int nt = 0; nt < 4; ++nt) {
      const short8 bf = *(const short8*)(vb0 + (size_t)(nt * 16 + l15) * Nn + c);
      acc[nt] = __builtin_amdgcn_mfma_f32_16x16x32_bf16(af, bf, acc[nt], 0, 0, 0);
    }
  }
  #pragma unroll
  for (int nt = 0; nt < 4; ++nt)
    #pragma unroll
    for (int r = 0; r < 4; ++r)
      aoB[(size_t)(b * Nn + m0 + lg * 4 + r) * Dd + h * 64 + nt * 16 + l15] =
          f2bfu(acc[nt][r]);
}

// ---------------------------------------------------------------------------
extern "C" void kernel_launch(void* const* d_in, const int* in_sizes, int n_in,
                              void* d_out, int out_size, void* d_ws, size_t ws_size,
                              hipStream_t stream) {
  const float* x    = (const float*)d_in[0];
  const int*   pm   = (const int*)  d_in[1];
  const int*   vld  = (const int*)  d_in[2];
  const float* cont = (const float*)d_in[3];
  const int* dbk = (const int*)d_in[4];
  const int* drk = (const int*)d_in[5];
  const int* rpk = (const int*)d_in[6];
  const int* hdk = (const int*)d_in[7];
  const int* etk = (const int*)d_in[8];
  const int* spk = (const int*)d_in[9];
  const int* sck = (const int*)d_in[10];
  const int* dgk = (const int*)d_in[11];
  const int* ctk = (const int*)d_in[12];
  const float* Wq  = (const float*)d_in[13];
  const float* Wk  = (const float*)d_in[14];
  const float* Wv  = (const float*)d_in[15];
  const float* Wo  = (const float*)d_in[16];
  const float* bo  = (const float*)d_in[17];
  const float* cmW1 = (const float*)d_in[18];
  const float* cmb1 = (const float*)d_in[19];
  const float* cmW2 = (const float*)d_in[20];
  const float* cmb2 = (const float*)d_in[21];
  const float* Ed  = (const float*)d_in[22];
  const float* Edi = (const float*)d_in[23];
  const float* Er  = (const float*)d_in[24];
  const float* Eh  = (const float*)d_in[25];
  const float* Ee  = (const float*)d_in[26];
  const float* Esp = (const float*)d_in[27];
  const float* Edg = (const float*)d_in[28];
  const float* Ec  = (const float*)d_in[29];
  const float* Es  = (const float*)d_in[30];
  const float* blng = (const float*)d_in[31];
  const float* blnb = (const float*)d_in[32];
  const float* bW   = (const float*)d_in[33];
  const float* bb_  = (const float*)d_in[34];
  const float* ln1g = (const float*)d_in[35];
  const float* ln1b = (const float*)d_in[36];
  const float* ln2g = (const float*)d_in[37];
  const float* ln2b = (const float*)d_in[38];
  const float* ffW1 = (const float*)d_in[39];
  const float* ffb1 = (const float*)d_in[40];
  const float* ffW2 = (const float*)d_in[41];
  const float* ffb2 = (const float*)d_in[42];

  float* out   = (float*)d_out;
  float* xout  = out;                       // 393216
  float* attn  = out + 393216;              // 2359296 (logits in place)
  float* biasO = out + 393216 + 2359296;    // 2359296

  float* ws = (float*)d_ws;
  // persistent bf16 weights [0, 327680)
  ushort_t* wqB   = (ushort_t*)(ws);             // 65536 ush
  ushort_t* wkB   = (ushort_t*)(ws + 32768);
  ushort_t* wvB   = (ushort_t*)(ws + 65536);
  ushort_t* woB   = (ushort_t*)(ws + 98304);
  ushort_t* ffW1B = (ushort_t*)(ws + 131072);    // 262144 ush
  ushort_t* ffW2B = (ushort_t*)(ws + 262144);    // 131072 ush
  // epoch 1 (pair path; dead after pair_kernel) [327680, 2794304)
  ushort_t* contP = (ushort_t*)(ws + 327680);    // 4718592 ush
  ushort_t* dcP   = (ushort_t*)(ws + 2686976);   // 98304 ush
  ushort_t* dcbP  = (ushort_t*)(ws + 2736128);   // 98304 ush
  ushort_t* EddP  = (ushort_t*)(ws + 2785280);   // 5760 ush
  ushort_t* ErsP  = (ushort_t*)(ws + 2788160);   // 3840 ush
  ushort_t* EhesP = (ushort_t*)(ws + 2790080);   // 3840 ush
  ushort_t* w1bf  = (ushort_t*)(ws + 2792000);   // 512 ush
  ushort_t* w2bf  = (ushort_t*)(ws + 2792256);   // 4096 ush
  // epoch 2 (attention/FFN; lives after pair) [327680, 3276800)
  ushort_t* xnb = (ushort_t*)(ws + 327680);      // 393216 ush
  ushort_t* qbB = (ushort_t*)(ws + 524288);
  ushort_t* kbB = (ushort_t*)(ws + 720896);
  ushort_t* vbT = (ushort_t*)(ws + 917504);
  ushort_t* aoB = (ushort_t*)(ws + 1114112);
  float* x1  = ws + 1310720;                     // 393216 f32
  float* hff = ws + 1703936;                     // 1572864 f32

  // 0a) prep: permuted bf16 tables + weight packs
  prep_kernel<<<758, 256, 0, stream>>>(dgk, ctk, Edg, Ec, cmb2, cmW1, cmb1,
      cmW2, Ed, Edi, Er, Eh, Ee, Esp, Es, Wq, Wk, Wv, Wo, ffW1, ffW2,
      dcP, dcbP, w1bf, w2bf, EddP, ErsP, EhesP,
      wqB, wkB, wvB, woB, ffW1B, ffW2B);
  // 0b) pack per-pair records
  pack_kernel<<<2304, 256, 0, stream>>>(dbk, drk, rpk, hdk, etk, spk, sck, pm,
      cont, contP);
  // 1) pair bias (MFMA, 4 tiles/wave)
  pair_kernel<<<2304, 256, 0, stream>>>(contP, w1bf, w2bf, EddP, ErsP, EhesP,
      blng, blnb, bW, bb_, dcP, dcbP, biasO);
  // 2) ln1 -> xnb (bf16)
  ln_kernel<<<384, 256, 0, stream>>>(x, ln1g, ln1b, xnb);
  // 3) q, k, V^T projections (all-bf16)
  qkv_kernel<<<dim3(4, 24, 3), 256, 0, stream>>>(xnb, wqB, wkB, wvB,
      qbB, kbB, vbT);
  // 4) logits = qk^T*scale + bias, safe-masked -> attn
  gemm2<1><<<dim3(6, 6, 16), 256, 0, stream>>>(qbB, nullptr, 256, kbB, 256,
      attn, 384, nullptr, nullptr, 0, 64, biasO, pm, vld);
  // 5+6) fused softmax + attn finalize + PV -> aoB
  pv_kernel<<<dim3(24, 16), 64, 0, stream>>>(attn, pm, vbT, aoB);
  // 7) Wo + bo + residual(x) -> x1
  gemm2<0><<<dim3(4, 24), 256, 0, stream>>>(aoB, nullptr, 256, woB, 256,
      x1, 256, bo, x, 256, 256, nullptr, nullptr, nullptr);
  // 8) ln2 -> xnb
  ln_kernel<<<384, 256, 0, stream>>>(x1, ln2g, ln2b, xnb);
  // 9) FF1 -> hff
  gemm2<0><<<dim3(16, 24), 256, 0, stream>>>(xnb, nullptr, 256, ffW1B, 256,
      hff, 1024, ffb1, nullptr, 0, 256, nullptr, nullptr, nullptr);
  // 10) FF2 with fused gate + ffb2 + residual(x1) -> x_out
  gemm2<3><<<dim3(4, 24), 256, 0, stream>>>(nullptr, hff, 1024, ffW2B, 512,
      xout, 256, ffb2, x1, 256, 512, nullptr, nullptr, nullptr);
}

// Round 13
// 188.708 us; speedup vs baseline: 2.6956x; 1.0459x over previous
//
#include <hip/hip_runtime.h>
#include <hip/hip_bf16.h>
#include <float.h>

// Problem constants
#define Bz   4
#define Nn   384
#define Dd   256
#define Hh   4
#define DHh  64
#define NSQ  (384*384)
#define NEG_MAX (-3.40282346638528859812e+38f)

typedef __attribute__((ext_vector_type(8))) short short8;
typedef __attribute__((ext_vector_type(4))) float f32x4;
typedef unsigned short ushort_t;

// fast exact-gelu: erf via Abramowitz-Stegun 7.1.26 (|err| <= 1.5e-7)
__device__ __forceinline__ float gelu_f(float x){
  const float y = __builtin_fabsf(x) * 0.70710678118654752f;
  const float t = __builtin_amdgcn_rcpf(fmaf(0.3275911f, y, 1.0f));
  float poly = fmaf(1.061405429f, t, -1.453152027f);
  poly = fmaf(poly, t, 1.421413741f);
  poly = fmaf(poly, t, -0.284496736f);
  poly = fmaf(poly, t, 0.254829592f);
  poly *= t;
  const float e = __expf(-y * y);
  const float erfa = fmaf(-poly, e, 1.0f);
  const float er = __builtin_copysignf(erfa, x);
  return 0.5f * x * (1.0f + er);
}
__device__ __forceinline__ float wsum(float v){
  #pragma unroll
  for (int o = 32; o > 0; o >>= 1) v += __shfl_xor(v, o, 64);
  return v;
}
__device__ __forceinline__ float4 ld4(const float* p){ return *(const float4*)p; }
__device__ __forceinline__ f32x4 ldv4(const float* p){ return *(const f32x4*)p; }

// fp32 <-> bf16
__device__ __forceinline__ ushort_t f2bfu(float f){
  union { float f; unsigned u; } v; v.f = f;
  unsigned r = v.u + 0x7FFFu + ((v.u >> 16) & 1u);
  return (ushort_t)(r >> 16);
}
__device__ __forceinline__ short f2bf(float f){ return (short)f2bfu(f); }
__device__ __forceinline__ float bfe2f(ushort_t u){
  union { unsigned u; float f; } v; v.u = ((unsigned)u) << 16; return v.f;
}
__device__ __forceinline__ void addbf(f32x4& a, f32x4& b, short8 v){
  a[0] += bfe2f((ushort_t)v[0]); a[1] += bfe2f((ushort_t)v[1]);
  a[2] += bfe2f((ushort_t)v[2]); a[3] += bfe2f((ushort_t)v[3]);
  b[0] += bfe2f((ushort_t)v[4]); b[1] += bfe2f((ushort_t)v[5]);
  b[2] += bfe2f((ushort_t)v[6]); b[3] += bfe2f((ushort_t)v[7]);
}

// ---------------------------------------------------------------------------
// prep (merged with pack): permuted bf16 tables, w1bf/w2bf, bf16 weights,
// and per-pair 16B records contP.
// ---------------------------------------------------------------------------
__global__ __launch_bounds__(256) void prep_kernel(
    const int* __restrict__ dgk, const int* __restrict__ ctk,
    const float* __restrict__ Edg, const float* __restrict__ Ec,
    const float* __restrict__ b2,
    const float* __restrict__ W1, const float* __restrict__ b1,
    const float* __restrict__ W2,
    const float* __restrict__ Ed, const float* __restrict__ Edi,
    const float* __restrict__ Er, const float* __restrict__ Eh,
    const float* __restrict__ Ee, const float* __restrict__ Esp,
    const float* __restrict__ Es,
    const float* __restrict__ Wq, const float* __restrict__ Wk,
    const float* __restrict__ Wv, const float* __restrict__ Wo,
    const float* __restrict__ ffW1, const float* __restrict__ ffW2,
    const int* __restrict__ dbk, const int* __restrict__ drk,
    const int* __restrict__ rpk, const int* __restrict__ hdk,
    const int* __restrict__ etk, const int* __restrict__ spk,
    const int* __restrict__ sck, const int* __restrict__ pm,
    const float* __restrict__ cont,
    ushort_t* __restrict__ dcP, ushort_t* __restrict__ dcbP,
    ushort_t* __restrict__ w1bf, ushort_t* __restrict__ w2bf,
    ushort_t* __restrict__ EddP, ushort_t* __restrict__ ErsP,
    ushort_t* __restrict__ EhesP,
    ushort_t* __restrict__ wqB, ushort_t* __restrict__ wkB,
    ushort_t* __restrict__ wvB, ushort_t* __restrict__ woB,
    ushort_t* __restrict__ ffW1B, ushort_t* __restrict__ ffW2B,
    ushort_t* __restrict__ contP)
{
  const int idx = blockIdx.x * 256 + threadIdx.x;
  if (idx < 24576) {                       // dcP / dcbP (permuted bf16)
    const int row = idx >> 4;
    const int q   = (idx & 15) << 2;
    const int pos = ((q >> 2) & 3) * 16 + (q >> 4) * 4;
    const float4 a = ld4(Edg + (dgk[row] << 6) + q);
    const float4 b = ld4(Ec  + (ctk[row] << 6) + q);
    const float4 bb4 = ld4(b2 + q);
    ushort4 o, o2;
    o.x = f2bfu(a.x + b.x); o.y = f2bfu(a.y + b.y);
    o.z = f2bfu(a.z + b.z); o.w = f2bfu(a.w + b.w);
    o2.x = f2bfu(a.x + b.x + bb4.x); o2.y = f2bfu(a.y + b.y + bb4.y);
    o2.z = f2bfu(a.z + b.z + bb4.z); o2.w = f2bfu(a.w + b.w + bb4.w);
    *(ushort4*)(dcP  + row * 64 + pos) = o;
    *(ushort4*)(dcbP + row * 64 + pos) = o2;
  } else if (idx < 26624) {                // w2bf [c][k]
    const int t = idx - 24576;
    const int c = t >> 5, k2 = (t & 31) << 1;
    w2bf[c * 64 + k2]     = f2bfu(W2[c * 64 + k2]);
    w2bf[c * 64 + k2 + 1] = f2bfu(W2[c * 64 + k2 + 1]);
  } else if (idx < 26688) {                // w1bf {W1 row, b1, 0} bf16
    const int k = idx - 26624;
    #pragma unroll
    for (int d = 0; d < 6; ++d) w1bf[k * 8 + d] = f2bfu(W1[k * 6 + d]);
    w1bf[k * 8 + 6] = f2bfu(b1[k]);
    w1bf[k * 8 + 7] = 0;
  } else if (idx < 28128) {                // EddP: 90 rows, permuted bf16
    const int t = idx - 26688;
    const int row = t >> 4, q = (t & 15) << 2;
    const int pos = ((q >> 2) & 3) * 16 + (q >> 4) * 4;
    const int d = row / 10, r = row - d * 10;
    const float4 a = ld4(Ed + (d << 6) + q);
    const float4 b = ld4(Edi + (r << 6) + q);
    ushort4 o;
    o.x = f2bfu(a.x + b.x); o.y = f2bfu(a.y + b.y);
    o.z = f2bfu(a.z + b.z); o.w = f2bfu(a.w + b.w);
    *(ushort4*)(EddP + row * 64 + pos) = o;
  } else if (idx < 29088) {                // ErsP: 60 rows
    const int t = idx - 28128;
    const int row = t >> 4, q = (t & 15) << 2;
    const int pos = ((q >> 2) & 3) * 16 + (q >> 4) * 4;
    const int ro = row / 6, s = row - ro * 6;
    const float4 a = ld4(Er + (ro << 6) + q);
    const float4 b = ld4(Esp + (s << 6) + q);
    ushort4 o;
    o.x = f2bfu(a.x + b.x); o.y = f2bfu(a.y + b.y);
    o.z = f2bfu(a.z + b.z); o.w = f2bfu(a.w + b.w);
    *(ushort4*)(ErsP + row * 64 + pos) = o;
  } else if (idx < 30048) {                // EhesP: 60 rows
    const int t = idx - 29088;
    const int row = t >> 4, q = (t & 15) << 2;
    const int pos = ((q >> 2) & 3) * 16 + (q >> 4) * 4;
    const int h = row / 15, rem = row - h * 15;
    const int e = rem / 3, sm = rem - e * 3;
    const float4 a = ld4(Eh + (h << 6) + q);
    const float4 b = ld4(Ee + (e << 6) + q);
    const float4 c = ld4(Es + (sm << 6) + q);
    ushort4 o;
    o.x = f2bfu(a.x + b.x + c.x); o.y = f2bfu(a.y + b.y + c.y);
    o.z = f2bfu(a.z + b.z + c.z); o.w = f2bfu(a.w + b.w + c.w);
    *(ushort4*)(EhesP + row * 64 + pos) = o;
  } else if (idx < 193888) {               // weight bf16 packs, 4 elems/thread
    const int t = idx - 30048;
    const float* src; ushort_t* dst; int e;
    if (t < 16384)      { src = Wq;   dst = wqB;   e = t << 2; }
    else if (t < 32768) { src = Wk;   dst = wkB;   e = (t - 16384) << 2; }
    else if (t < 49152) { src = Wv;   dst = wvB;   e = (t - 32768) << 2; }
    else if (t < 65536) { src = Wo;   dst = woB;   e = (t - 49152) << 2; }
    else if (t < 131072){ src = ffW1; dst = ffW1B; e = (t - 65536) << 2; }
    else                { src = ffW2; dst = ffW2B; e = (t - 131072) << 2; }
    const float4 v = ld4(src + e);
    ushort4 o;
    o.x = f2bfu(v.x); o.y = f2bfu(v.y); o.z = f2bfu(v.z); o.w = f2bfu(v.w);
    *(ushort4*)(dst + e) = o;
  } else if (idx < 193888 + Bz * Nn * Nn) { // pack: per-pair 16B record
    const int p = idx - 193888;
    const float* cp = cont + (size_t)p * 6;
    short8 r;
    r[0] = f2bf(cp[0]); r[1] = f2bf(cp[1]); r[2] = f2bf(cp[2]);
    r[3] = f2bf(cp[3]); r[4] = f2bf(cp[4]); r[5] = f2bf(cp[5]);
    const unsigned iv = (unsigned)(dbk[p] * 10 + drk[p])
                      | ((unsigned)(rpk[p] * 6 + spk[p]) << 7)
                      | ((unsigned)((hdk[p] * 5 + etk[p]) * 3 + sck[p]) << 13)
                      | ((pm[p] ? 1u : 0u) << 19);
    r[6] = (short)(iv & 0xffffu);
    r[7] = (short)(iv >> 16);
    *(short8*)(contP + (size_t)p * 8) = r;
  }
}

// ---------------------------------------------------------------------------
// Fused pair kernel v12: v11 structure, launch_bounds(256,3) for occupancy.
// ---------------------------------------------------------------------------
__global__ __launch_bounds__(256, 3) void pair_kernel(
    const ushort_t* __restrict__ contP,
    const ushort_t* __restrict__ w1bf, const ushort_t* __restrict__ w2bf,
    const ushort_t* __restrict__ EddP, const ushort_t* __restrict__ ErsP,
    const ushort_t* __restrict__ EhesP,
    const float* __restrict__ lng, const float* __restrict__ lnb,
    const float* __restrict__ bW, const float* __restrict__ bb,
    const ushort_t* __restrict__ dcP, const ushort_t* __restrict__ dcbP,
    float* __restrict__ biasOut)
{
  const int tid  = threadIdx.x;
  const int lane = tid & 63;
  const int l15  = lane & 15, lg = lane >> 4;
  const int wid  = blockIdx.x * 4 + (tid >> 6);             // [0, 9216)
  const int rowU = __builtin_amdgcn_readfirstlane(wid / 6); // b*N+i
  const int jb   = wid - rowU * 6;
  const int b    = rowU / Nn;
  const int i    = rowU - b * Nn;
  const int j0   = jb * 64 + l15;
  const size_t pbase = (size_t)rowU * Nn + j0;
  const int colOff = lg << 2;

  // ---- init: 1 record load per tile ----
  const short8 rec0 = *(const short8*)(contP + (pbase + 0) * 8);
  const short8 rec1 = *(const short8*)(contP + (pbase + 16) * 8);
  const short8 rec2 = *(const short8*)(contP + (pbase + 32) * 8);
  const short8 rec3 = *(const short8*)(contP + (pbase + 48) * 8);
  asm volatile("" :: "v"(rec0), "v"(rec1), "v"(rec2), "v"(rec3));
  const unsigned ix0 = (unsigned)(ushort_t)rec0[6] | ((unsigned)(ushort_t)rec0[7] << 16);
  const unsigned ix1 = (unsigned)(ushort_t)rec1[6] | ((unsigned)(ushort_t)rec1[7] << 16);
  const unsigned ix2 = (unsigned)(ushort_t)rec2[6] | ((unsigned)(ushort_t)rec2[7] << 16);
  const unsigned ix3 = (unsigned)(ushort_t)rec3[6] | ((unsigned)(ushort_t)rec3[7] << 16);
  const float c00 = bfe2f((ushort_t)rec0[0]), c01 = bfe2f((ushort_t)rec0[1]),
              c02 = bfe2f((ushort_t)rec0[2]), c03 = bfe2f((ushort_t)rec0[3]),
              c04 = bfe2f((ushort_t)rec0[4]), c05 = bfe2f((ushort_t)rec0[5]);
  const float c10 = bfe2f((ushort_t)rec1[0]), c11 = bfe2f((ushort_t)rec1[1]),
              c12 = bfe2f((ushort_t)rec1[2]), c13 = bfe2f((ushort_t)rec1[3]),
              c14 = bfe2f((ushort_t)rec1[4]), c15 = bfe2f((ushort_t)rec1[5]);
  const float c20 = bfe2f((ushort_t)rec2[0]), c21 = bfe2f((ushort_t)rec2[1]),
              c22 = bfe2f((ushort_t)rec2[2]), c23 = bfe2f((ushort_t)rec2[3]),
              c24 = bfe2f((ushort_t)rec2[4]), c25 = bfe2f((ushort_t)rec2[5]);
  const float c30 = bfe2f((ushort_t)rec3[0]), c31 = bfe2f((ushort_t)rec3[1]),
              c32 = bfe2f((ushort_t)rec3[2]), c33 = bfe2f((ushort_t)rec3[3]),
              c34 = bfe2f((ushort_t)rec3[4]), c35 = bfe2f((ushort_t)rec3[5]);

  // ---- phase a: h1 for 4 tiles; w1bf rows loaded once per wave ----
  short8 b0a, b0b, b1a, b1b, b2a, b2b, b3a, b3b;
#define H1ROW(R, JJ, D0, D1, D2, D3) { \
    const float w0 = bfe2f((ushort_t)R[0]), w1 = bfe2f((ushort_t)R[1]), \
                w2 = bfe2f((ushort_t)R[2]), w3 = bfe2f((ushort_t)R[3]), \
                w4 = bfe2f((ushort_t)R[4]), w5 = bfe2f((ushort_t)R[5]), \
                w6 = bfe2f((ushort_t)R[6]); \
    float s0 = w6, s1 = w6, s2 = w6, s3 = w6; \
    s0 = fmaf(w0, c00, s0); s0 = fmaf(w1, c01, s0); s0 = fmaf(w2, c02, s0); \
    s0 = fmaf(w3, c03, s0); s0 = fmaf(w4, c04, s0); s0 = fmaf(w5, c05, s0); \
    s1 = fmaf(w0, c10, s1); s1 = fmaf(w1, c11, s1); s1 = fmaf(w2, c12, s1); \
    s1 = fmaf(w3, c13, s1); s1 = fmaf(w4, c14, s1); s1 = fmaf(w5, c15, s1); \
    s2 = fmaf(w0, c20, s2); s2 = fmaf(w1, c21, s2); s2 = fmaf(w2, c22, s2); \
    s2 = fmaf(w3, c23, s2); s2 = fmaf(w4, c24, s2); s2 = fmaf(w5, c25, s2); \
    s3 = fmaf(w0, c30, s3); s3 = fmaf(w1, c31, s3); s3 = fmaf(w2, c32, s3); \
    s3 = fmaf(w3, c33, s3); s3 = fmaf(w4, c34, s3); s3 = fmaf(w5, c35, s3); \
    D0[JJ] = f2bf(gelu_f(s0)); D1[JJ] = f2bf(gelu_f(s1)); \
    D2[JJ] = f2bf(gelu_f(s2)); D3[JJ] = f2bf(gelu_f(s3)); }
  {
    const ushort_t* wb_ = w1bf + ((lg << 3) << 3);
    const short8 r0 = *(const short8*)(wb_ +  0);
    const short8 r1 = *(const short8*)(wb_ +  8);
    const short8 r2 = *(const short8*)(wb_ + 16);
    const short8 r3 = *(const short8*)(wb_ + 24);
    const short8 r4 = *(const short8*)(wb_ + 32);
    const short8 r5 = *(const short8*)(wb_ + 40);
    const short8 r6 = *(const short8*)(wb_ + 48);
    const short8 r7 = *(const short8*)(wb_ + 56);
    asm volatile("" :: "v"(r0), "v"(r1), "v"(r2), "v"(r3),
                       "v"(r4), "v"(r5), "v"(r6), "v"(r7));
    H1ROW(r0, 0, b0a, b1a, b2a, b3a) H1ROW(r1, 1, b0a, b1a, b2a, b3a)
    H1ROW(r2, 2, b0a, b1a, b2a, b3a) H1ROW(r3, 3, b0a, b1a, b2a, b3a)
    H1ROW(r4, 4, b0a, b1a, b2a, b3a) H1ROW(r5, 5, b0a, b1a, b2a, b3a)
    H1ROW(r6, 6, b0a, b1a, b2a, b3a) H1ROW(r7, 7, b0a, b1a, b2a, b3a)
  }
  {
    const ushort_t* wb_ = w1bf + ((32 + (lg << 3)) << 3);
    const short8 r0 = *(const short8*)(wb_ +  0);
    const short8 r1 = *(const short8*)(wb_ +  8);
    const short8 r2 = *(const short8*)(wb_ + 16);
    const short8 r3 = *(const short8*)(wb_ + 24);
    const short8 r4 = *(const short8*)(wb_ + 32);
    const short8 r5 = *(const short8*)(wb_ + 40);
    const short8 r6 = *(const short8*)(wb_ + 48);
    const short8 r7 = *(const short8*)(wb_ + 56);
    asm volatile("" :: "v"(r0), "v"(r1), "v"(r2), "v"(r3),
                       "v"(r4), "v"(r5), "v"(r6), "v"(r7));
    H1ROW(r0, 0, b0b, b1b, b2b, b3b) H1ROW(r1, 1, b0b, b1b, b2b, b3b)
    H1ROW(r2, 2, b0b, b1b, b2b, b3b) H1ROW(r3, 3, b0b, b1b, b2b, b3b)
    H1ROW(r4, 4, b0b, b1b, b2b, b3b) H1ROW(r5, 5, b0b, b1b, b2b, b3b)
    H1ROW(r6, 6, b0b, b1b, b2b, b3b) H1ROW(r7, 7, b0b, b1b, b2b, b3b)
  }
#undef H1ROW

  // ---- phase b: A-frags once; 32 MFMAs ----
  const ushort_t* wbase = w2bf + (size_t)l15 * 64 + (lg << 3);
  const short8 wa0 = *(const short8*)(wbase);
  const short8 wc0 = *(const short8*)(wbase + 32);
  const short8 wa1 = *(const short8*)(wbase + 16 * 64);
  const short8 wc1 = *(const short8*)(wbase + 16 * 64 + 32);
  const short8 wa2 = *(const short8*)(wbase + 32 * 64);
  const short8 wc2 = *(const short8*)(wbase + 32 * 64 + 32);
  const short8 wa3 = *(const short8*)(wbase + 48 * 64);
  const short8 wc3 = *(const short8*)(wbase + 48 * 64 + 32);
  asm volatile("" :: "v"(wa0), "v"(wc0), "v"(wa1), "v"(wc1),
                     "v"(wa2), "v"(wc2), "v"(wa3), "v"(wc3));
  f32x4 acc0[4] = {}, acc1[4] = {}, acc2[4] = {}, acc3[4] = {};
#define MM(ACC, BA, BB) \
  ACC[0] = __builtin_amdgcn_mfma_f32_16x16x32_bf16(wa0, BA, ACC[0], 0, 0, 0); \
  ACC[0] = __builtin_amdgcn_mfma_f32_16x16x32_bf16(wc0, BB, ACC[0], 0, 0, 0); \
  ACC[1] = __builtin_amdgcn_mfma_f32_16x16x32_bf16(wa1, BA, ACC[1], 0, 0, 0); \
  ACC[1] = __builtin_amdgcn_mfma_f32_16x16x32_bf16(wc1, BB, ACC[1], 0, 0, 0); \
  ACC[2] = __builtin_amdgcn_mfma_f32_16x16x32_bf16(wa2, BA, ACC[2], 0, 0, 0); \
  ACC[2] = __builtin_amdgcn_mfma_f32_16x16x32_bf16(wc2, BB, ACC[2], 0, 0, 0); \
  ACC[3] = __builtin_amdgcn_mfma_f32_16x16x32_bf16(wa3, BA, ACC[3], 0, 0, 0); \
  ACC[3] = __builtin_amdgcn_mfma_f32_16x16x32_bf16(wc3, BB, ACC[3], 0, 0, 0);
  MM(acc0, b0a, b0b) MM(acc1, b1a, b1b) MM(acc2, b2a, b2b) MM(acc3, b3a, b3b)
#undef MM

  // ---- phase c: permuted bf16 gathers, 8 ops per tile + shared dcb ----
#define GATHER(ACC, IX, JOFF) { \
    const int xdd  = ((IX) & 127) << 6; \
    const int xrs  = (((IX) >> 7) & 63) << 6; \
    const int xhes = (((IX) >> 13) & 63) << 6; \
    const ushort_t* ep = EddP  + xdd  + (lg << 4); \
    const ushort_t* rp = ErsP  + xrs  + (lg << 4); \
    const ushort_t* hp = EhesP + xhes + (lg << 4); \
    const ushort_t* jp = dcP + (((size_t)(b * Nn + j0 + (JOFF))) << 6) + (lg << 4); \
    const short8 e0 = *(const short8*)ep,       e1 = *(const short8*)(ep + 8); \
    const short8 r0 = *(const short8*)rp,       r1 = *(const short8*)(rp + 8); \
    const short8 h0 = *(const short8*)hp,       h1 = *(const short8*)(hp + 8); \
    const short8 jv0 = *(const short8*)jp,      jv1 = *(const short8*)(jp + 8); \
    asm volatile("" :: "v"(e0), "v"(e1), "v"(r0), "v"(r1), \
                       "v"(h0), "v"(h1), "v"(jv0), "v"(jv1)); \
    addbf(ACC[0], ACC[1], e0);  addbf(ACC[2], ACC[3], e1); \
    addbf(ACC[0], ACC[1], r0);  addbf(ACC[2], ACC[3], r1); \
    addbf(ACC[0], ACC[1], h0);  addbf(ACC[2], ACC[3], h1); \
    addbf(ACC[0], ACC[1], jv0); addbf(ACC[2], ACC[3], jv1); }
  GATHER(acc0, ix0, 0)
  GATHER(acc1, ix1, 16)
  GATHER(acc2, ix2, 32)
  GATHER(acc3, ix3, 48)
#undef GATHER
  {
    const ushort_t* up = dcbP + (((size_t)rowU) << 6) + (lg << 4);
    const short8 u0 = *(const short8*)up, u1 = *(const short8*)(up + 8);
    f32x4 du0, du1, du2, du3;
    #pragma unroll
    for (int r = 0; r < 4; ++r) {
      du0[r] = bfe2f((ushort_t)u0[r]);     du1[r] = bfe2f((ushort_t)u0[4 + r]);
      du2[r] = bfe2f((ushort_t)u1[r]);     du3[r] = bfe2f((ushort_t)u1[4 + r]);
    }
    acc0[0] += du0; acc0[1] += du1; acc0[2] += du2; acc0[3] += du3;
    acc1[0] += du0; acc1[1] += du1; acc1[2] += du2; acc1[3] += du3;
    acc2[0] += du0; acc2[1] += du1; acc2[2] += du2; acc2[3] += du3;
    acc3[0] += du0; acc3[1] += du1; acc3[2] += du2; acc3[3] += du3;
  }

  // ---- phase d: LN stats per tile (xor16/32 over lg) ----
  float mean0, inv0, mean1, inv1, mean2, inv2, mean3, inv3;
#define STATS(ACC, MEAN, INV) { \
    float sum = 0.f, sq = 0.f; \
    _Pragma("unroll") \
    for (int mt = 0; mt < 4; ++mt) \
      _Pragma("unroll") \
      for (int r = 0; r < 4; ++r) { \
        const float v = ACC[mt][r]; sum += v; sq = fmaf(v, v, sq); } \
    sum += __shfl_xor(sum, 16, 64); sum += __shfl_xor(sum, 32, 64); \
    sq  += __shfl_xor(sq,  16, 64); sq  += __shfl_xor(sq,  32, 64); \
    MEAN = sum * (1.f / 64.f); \
    INV  = rsqrtf(sq * (1.f / 64.f) - MEAN * MEAN + 1e-5f); }
  STATS(acc0, mean0, inv0) STATS(acc1, mean1, inv1)
  STATS(acc2, mean2, inv2) STATS(acc3, mean3, inv3)
#undef STATS

  float h00 = 0.f, h01 = 0.f, h02 = 0.f, h03 = 0.f;
  float h10 = 0.f, h11 = 0.f, h12 = 0.f, h13 = 0.f;
  float h20 = 0.f, h21 = 0.f, h22 = 0.f, h23 = 0.f;
  float h30 = 0.f, h31 = 0.f, h32 = 0.f, h33 = 0.f;
  #pragma unroll
  for (int mt = 0; mt < 4; ++mt) {
    const int c0i = (mt << 4) + colOff;
    const f32x4 g4 = ldv4(lng + c0i);
    const f32x4 b4 = ldv4(lnb + c0i);
    const f32x4 w0 = ldv4(bW + c0i);
    const f32x4 w1_ = ldv4(bW + 64 + c0i);
    const f32x4 w2_ = ldv4(bW + 128 + c0i);
    const f32x4 w3_ = ldv4(bW + 192 + c0i);
    asm volatile("" :: "v"(g4), "v"(b4), "v"(w0), "v"(w1_), "v"(w2_), "v"(w3_));
    #pragma unroll
    for (int r = 0; r < 4; ++r) {
      float g;
      g = gelu_f((acc0[mt][r] - mean0) * inv0 * g4[r] + b4[r]);
      h00 = fmaf(w0[r], g, h00); h01 = fmaf(w1_[r], g, h01);
      h02 = fmaf(w2_[r], g, h02); h03 = fmaf(w3_[r], g, h03);
      g = gelu_f((acc1[mt][r] - mean1) * inv1 * g4[r] + b4[r]);
      h10 = fmaf(w0[r], g, h10); h11 = fmaf(w1_[r], g, h11);
      h12 = fmaf(w2_[r], g, h12); h13 = fmaf(w3_[r], g, h13);
      g = gelu_f((acc2[mt][r] - mean2) * inv2 * g4[r] + b4[r]);
      h20 = fmaf(w0[r], g, h20); h21 = fmaf(w1_[r], g, h21);
      h22 = fmaf(w2_[r], g, h22); h23 = fmaf(w3_[r], g, h23);
      g = gelu_f((acc3[mt][r] - mean3) * inv3 * g4[r] + b4[r]);
      h30 = fmaf(w0[r], g, h30); h31 = fmaf(w1_[r], g, h31);
      h32 = fmaf(w2_[r], g, h32); h33 = fmaf(w3_[r], g, h33);
    }
  }
#define RED(H) H += __shfl_xor(H, 16, 64); H += __shfl_xor(H, 32, 64);
  RED(h00) RED(h01) RED(h02) RED(h03)
  RED(h10) RED(h11) RED(h12) RED(h13)
  RED(h20) RED(h21) RED(h22) RED(h23)
  RED(h30) RED(h31) RED(h32) RED(h33)
#undef RED

  const float bbl = bb[lg];
  const float bh0 = ((lg == 0) ? h00 : (lg == 1) ? h01 : (lg == 2) ? h02 : h03) + bbl;
  const float bh1 = ((lg == 0) ? h10 : (lg == 1) ? h11 : (lg == 2) ? h12 : h13) + bbl;
  const float bh2 = ((lg == 0) ? h20 : (lg == 1) ? h21 : (lg == 2) ? h22 : h23) + bbl;
  const float bh3 = ((lg == 0) ? h30 : (lg == 1) ? h31 : (lg == 2) ? h32 : h33) + bbl;
  const size_t base = (size_t)b * (Hh * NSQ) + (size_t)lg * NSQ + (size_t)i * Nn;
  biasOut[base + j0]      = bh0 * (((ix0 >> 19) & 1) ? 1.f : 0.f);
  biasOut[base + j0 + 16] = bh1 * (((ix1 >> 19) & 1) ? 1.f : 0.f);
  biasOut[base + j0 + 32] = bh2 * (((ix2 >> 19) & 1) ? 1.f : 0.f);
  biasOut[base + j0 + 48] = bh3 * (((ix3 >> 19) & 1) ? 1.f : 0.f);
}

// ---------------------------------------------------------------------------
// LayerNorm over last dim (256), bf16 output. One wave per row.
// ---------------------------------------------------------------------------
__global__ __launch_bounds__(256) void ln_kernel(
    const float* __restrict__ x, const float* __restrict__ g,
    const float* __restrict__ bta, ushort_t* __restrict__ o)
{
  const int row  = blockIdx.x * 4 + (threadIdx.x >> 6);
  const int lane = threadIdx.x & 63;
  const float4 v = *(const float4*)(x + (size_t)row * Dd + lane * 4);
  float s = v.x + v.y + v.z + v.w;
  s = wsum(s);
  const float m = s * (1.f / 256.f);
  const float dx = v.x - m, dy = v.y - m, dz = v.z - m, dw = v.w - m;
  float q = dx*dx + dy*dy + dz*dz + dw*dw;
  q = wsum(q);
  const float inv = rsqrtf(q * (1.f / 256.f) + 1e-5f);
  const int d = lane * 4;
  const float4 gg = *(const float4*)(g + d);
  const float4 bb = *(const float4*)(bta + d);
  ushort4 out;
  out.x = f2bfu(dx * inv * gg.x + bb.x);
  out.y = f2bfu(dy * inv * gg.y + bb.y);
  out.z = f2bfu(dz * inv * gg.z + bb.z);
  out.w = f2bfu(dw * inv * gg.w + bb.w);
  *(ushort4*)(o + (size_t)row * Dd + d) = out;
}

// ---------------------------------------------------------------------------
// Fused QKV: all-bf16 fragments. z: {wqB->qbB, wkB->kbB, wvB->vbT}.
// ---------------------------------------------------------------------------
__global__ __launch_bounds__(256) void qkv_kernel(
    const ushort_t* __restrict__ xnb,
    const ushort_t* __restrict__ wqB, const ushort_t* __restrict__ wkB,
    const ushort_t* __restrict__ wvB,
    ushort_t* __restrict__ qbB, ushort_t* __restrict__ kbB,
    ushort_t* __restrict__ vbT)
{
  const int tid = threadIdx.x;
  const int lane = tid & 63;
  const int w   = tid >> 6;
  const int l15 = lane & 15, lg = lane >> 4;
  const int m0 = blockIdx.y * 64 + w * 16;
  const int n0 = blockIdx.x * 64;
  const int z  = blockIdx.z;
  const ushort_t* Bb = (z == 0) ? wqB : (z == 1) ? wkB : wvB;

  f32x4 acc[4] = {};
  const ushort_t* pa = xnb + (size_t)(m0 + l15) * Dd + lg * 8;
  for (int k0 = 0; k0 < Dd; k0 += 32) {
    const short8 af = *(const short8*)(pa + k0);
    #pragma unroll
    for (int nt = 0; nt < 4; ++nt) {
      const short8 bf = *(const short8*)(Bb +
          (size_t)(n0 + nt * 16 + l15) * Dd + k0 + lg * 8);
      acc[nt] = __builtin_amdgcn_mfma_f32_16x16x32_bf16(af, bf, acc[nt], 0, 0, 0);
    }
  }
  if (z < 2) {
    ushort_t* Cb = (z == 0) ? qbB : kbB;
    #pragma unroll
    for (int nt = 0; nt < 4; ++nt)
      #pragma unroll
      for (int r = 0; r < 4; ++r)
        Cb[(size_t)(m0 + lg * 4 + r) * Dd + n0 + nt * 16 + l15] = f2bfu(acc[nt][r]);
  } else {
    const int m = m0 + (lg << 2);
    const int b = m / Nn, tok = m - b * Nn;
    #pragma unroll
    for (int nt = 0; nt < 4; ++nt) {
      const int n = n0 + nt * 16 + l15;
      const int h = n >> 6, dh = n & 63;
      ushort4 s4;
      s4.x = f2bfu(acc[nt][0]); s4.y = f2bfu(acc[nt][1]);
      s4.z = f2bfu(acc[nt][2]); s4.w = f2bfu(acc[nt][3]);
      *(ushort4*)(vbT + ((size_t)((b * 4 + h) * 64 + dh)) * Nn + tok) = s4;
    }
  }
}

// ---------------------------------------------------------------------------
// bf16-operand MFMA GEMM. Wave = 16(M) x 64(N); block = 4 waves.
// MODE 0: C(f32) = A16 @ B^T (+bias)(+res)   grid (Nc/64, M/64)
// MODE 1: QK^T*scale + biasT, safe-mask      grid (6, 6, B*H), A16/B bf16
// MODE 3: C = (a*gelu(g)) @ B^T (+bias)(+res), A32 = hff f32
// ---------------------------------------------------------------------------
template<int MODE>
__global__ __launch_bounds__(256) void gemm2(
    const ushort_t* __restrict__ A16, const float* __restrict__ A32, int lda,
    const ushort_t* __restrict__ Bm, int ldb,
    float* __restrict__ Cc, int ldc,
    const float* __restrict__ bias,
    const float* __restrict__ res, int ldr,
    int K,
    const float* __restrict__ biasT, const int* __restrict__ pmask,
    const int* __restrict__ valid)
{
  const int tid = threadIdx.x;
  const int lane = tid & 63;
  const int w   = tid >> 6;
  const int l15 = lane & 15, lg = lane >> 4;
  const int m0 = blockIdx.y * 64 + w * 16;
  const int n0 = blockIdx.x * 64;

  const ushort_t* Ab = A16; const ushort_t* Bb = Bm; float* Cb = Cc;
  const float* biasTb = biasT; const int* pmb = pmask; const int* vlb = valid;
  if (MODE == 1) {
    const int bz = blockIdx.z;
    const int b = bz >> 2, h = bz & 3;
    Ab = A16 + (size_t)b * Nn * Dd + h * DHh;
    Bb = Bm  + (size_t)b * Nn * Dd + h * DHh;
    Cb = Cc + (size_t)bz * NSQ;
    biasTb = biasT + (size_t)bz * NSQ;
    pmb = pmask + (size_t)b * NSQ;
    vlb = valid + b * Nn;
  }

  f32x4 acc[4] = {};
  const ushort_t* pa16 = Ab + (size_t)(m0 + l15) * lda + lg * 8;
  const float* pa32 = (MODE == 3) ? (A32 + (size_t)(m0 + l15) * lda + lg * 8) : nullptr;

  for (int k0 = 0; k0 < K; k0 += 32) {
    short8 af;
    if (MODE == 3) {
      const float4 a0 = ld4(pa32 + k0);
      const float4 a1 = ld4(pa32 + k0 + 4);
      const float4 g0 = ld4(pa32 + 512 + k0);
      const float4 g1 = ld4(pa32 + 512 + k0 + 4);
      af[0] = f2bf(a0.x * gelu_f(g0.x)); af[1] = f2bf(a0.y * gelu_f(g0.y));
      af[2] = f2bf(a0.z * gelu_f(g0.z)); af[3] = f2bf(a0.w * gelu_f(g0.w));
      af[4] = f2bf(a1.x * gelu_f(g1.x)); af[5] = f2bf(a1.y * gelu_f(g1.y));
      af[6] = f2bf(a1.z * gelu_f(g1.z)); af[7] = f2bf(a1.w * gelu_f(g1.w));
    } else {
      af = *(const short8*)(pa16 + k0);
    }
    #pragma unroll
    for (int nt = 0; nt < 4; ++nt) {
      const short8 bf = *(const short8*)(Bb +
          (size_t)(n0 + nt * 16 + l15) * ldb + k0 + lg * 8);
      acc[nt] = __builtin_amdgcn_mfma_f32_16x16x32_bf16(af, bf, acc[nt], 0, 0, 0);
    }
  }

  #pragma unroll
  for (int nt = 0; nt < 4; ++nt) {
    #pragma unroll
    for (int r = 0; r < 4; ++r) {
      const int m = m0 + lg * 4 + r;
      const int n = n0 + nt * 16 + l15;
      float v = acc[nt][r];
      if (MODE != 1) {
        if (bias) v += bias[n];
        if (res)  v += res[(size_t)m * ldr + n];
        Cb[(size_t)m * ldc + n] = v;
      } else {
        v = v * 0.125f + biasTb[(size_t)m * Nn + n];
        const bool safe = (pmb[(size_t)m * Nn + n] != 0) || (vlb[m] == 0 && m == n);
        Cb[(size_t)m * Nn + n] = safe ? v : NEG_MAX;
      }
    }
  }
}

// ---------------------------------------------------------------------------
// Fused softmax + PV + attn-write -> aoB bf16. 1 wave per 16 q-rows.
// ---------------------------------------------------------------------------
__global__ __launch_bounds__(64) void pv_kernel(
    float* __restrict__ att, const int* __restrict__ pm,
    const ushort_t* __restrict__ vbT, ushort_t* __restrict__ aoB)
{
  const int lane = threadIdx.x;
  const int l15 = lane & 15, lg = lane >> 4;
  const int bz = blockIdx.y;
  const int b = bz >> 2, h = bz & 3;
  const int m0 = blockIdx.x * 16;
  const int row = m0 + l15;
  float* ar = att + (size_t)bz * NSQ + (size_t)row * Nn;
  const int* pmr = pm + (size_t)b * NSQ + (size_t)row * Nn;

  float mr = NEG_MAX, sr = 0.f, spr = 0.f;
  for (int t = 0; t < 12; ++t) {
    const int c = t * 32 + lg * 8;
    const f32x4 v0 = ldv4(ar + c);
    const f32x4 v1 = ldv4(ar + c + 4);
    const int4 q0 = *(const int4*)(pmr + c);
    const int4 q1 = *(const int4*)(pmr + c + 4);
    float mc = fmaxf(fmaxf(fmaxf(v0[0], v0[1]), fmaxf(v0[2], v0[3])),
                     fmaxf(fmaxf(v1[0], v1[1]), fmaxf(v1[2], v1[3])));
    if (mc > mr) {
      const float sc = __expf(mr - mc);
      sr *= sc; spr *= sc; mr = mc;
    }
    float e;
    e = __expf(v0[0] - mr); sr += e; spr += q0.x ? e : 0.f;
    e = __expf(v0[1] - mr); sr += e; spr += q0.y ? e : 0.f;
    e = __expf(v0[2] - mr); sr += e; spr += q0.z ? e : 0.f;
    e = __expf(v0[3] - mr); sr += e; spr += q0.w ? e : 0.f;
    e = __expf(v1[0] - mr); sr += e; spr += q1.x ? e : 0.f;
    e = __expf(v1[1] - mr); sr += e; spr += q1.y ? e : 0.f;
    e = __expf(v1[2] - mr); sr += e; spr += q1.z ? e : 0.f;
    e = __expf(v1[3] - mr); sr += e; spr += q1.w ? e : 0.f;
  }
  #pragma unroll
  for (int o = 16; o <= 32; o <<= 1) {
    const float mo = __shfl_xor(mr, o, 64);
    const float so = __shfl_xor(sr, o, 64);
    const float spo = __shfl_xor(spr, o, 64);
    const float mn = fmaxf(mr, mo);
    const float s1 = __expf(mr - mn), s2 = __expf(mo - mn);
    sr = sr * s1 + so * s2;
    spr = spr * s1 + spo * s2;
    mr = mn;
  }
  const float rinv = 1.f / fmaxf(spr, 1e-6f * sr);

  f32x4 acc[4] = {};
  const ushort_t* vb0 = vbT + (size_t)(bz * 64) * Nn;
  for (int t = 0; t < 12; ++t) {
    const int c = t * 32 + lg * 8;
    const f32x4 v0 = ldv4(ar + c);
    const f32x4 v1 = ldv4(ar + c + 4);
    const int4 q0 = *(const int4*)(pmr + c);
    const int4 q1 = *(const int4*)(pmr + c + 4);
    f32x4 p0, p1;
    p0[0] = q0.x ? __expf(v0[0] - mr) * rinv : 0.f;
    p0[1] = q0.y ? __expf(v0[1] - mr) * rinv : 0.f;
    p0[2] = q0.z ? __expf(v0[2] - mr) * rinv : 0.f;
    p0[3] = q0.w ? __expf(v0[3] - mr) * rinv : 0.f;
    p1[0] = q1.x ? __expf(v1[0] - mr) * rinv : 0.f;
    p1[1] = q1.y ? __expf(v1[1] - mr) * rinv : 0.f;
    p1[2] = q1.z ? __expf(v1[2] - mr) * rinv : 0.f;
    p1[3] = q1.w ? __expf(v1[3] - mr) * rinv : 0.f;
    *(f32x4*)(ar + c) = p0;
    *(f32x4*)(ar + c + 4) = p1;
    short8 af;
    af[0] = f2bf(p0[0]); af[1] = f2bf(p0[1]); af[2] = f2bf(p0[2]); af[3] = f2bf(p0[3]);
    af[4] = f2bf(p1[0]); af[5] = f2bf(p1[1]); af[6] = f2bf(p1[2]); af[7] = f2bf(p1[3]);
    #pragma unroll
    for (int nt = 0; nt < 4; ++nt) {
      const short8 bf = *(const short8*)(vb0 + (size_t)(nt * 16 + l15) * Nn + c);
      acc[nt] = __builtin_amdgcn_mfma_f32_16x16x32_bf16(af, bf, acc[nt], 0, 0, 0);
    }
  }
  #pragma unroll
  for (int nt = 0; nt < 4; ++nt)
    #pragma unroll
    for (int r = 0; r < 4; ++r)
      aoB[(size_t)(b * Nn + m0 + lg * 4 + r) * Dd + h * 64 + nt * 16 + l15] =
          f2bfu(acc[nt][r]);
}

// ---------------------------------------------------------------------------
extern "C" void kernel_launch(void* const* d_in, const int* in_sizes, int n_in,
                              void* d_out, int out_size, void* d_ws, size_t ws_size,
                              hipStream_t stream) {
  const float* x    = (const float*)d_in[0];
  const int*   pm   = (const int*)  d_in[1];
  const int*   vld  = (const int*)  d_in[2];
  const float* cont = (const float*)d_in[3];
  const int* dbk = (const int*)d_in[4];
  const int* drk = (const int*)d_in[5];
  const int* rpk = (const int*)d_in[6];
  const int* hdk = (const int*)d_in[7];
  const int* etk = (const int*)d_in[8];
  const int* spk = (const int*)d_in[9];
  const int* sck = (const int*)d_in[10];
  const int* dgk = (const int*)d_in[11];
  const int* ctk = (const int*)d_in[12];
  const float* Wq  = (const float*)d_in[13];
  const float* Wk  = (const float*)d_in[14];
  const float* Wv  = (const float*)d_in[15];
  const float* Wo  = (const float*)d_in[16];
  const float* bo  = (const float*)d_in[17];
  const float* cmW1 = (const float*)d_in[18];
  const float* cmb1 = (const float*)d_in[19];
  const float* cmW2 = (const float*)d_in[20];
  const float* cmb2 = (const float*)d_in[21];
  const float* Ed  = (const float*)d_in[22];
  const float* Edi = (const float*)d_in[23];
  const float* Er  = (const float*)d_in[24];
  const float* Eh  = (const float*)d_in[25];
  const float* Ee  = (const float*)d_in[26];
  const float* Esp = (const float*)d_in[27];
  const float* Edg = (const float*)d_in[28];
  const float* Ec  = (const float*)d_in[29];
  const float* Es  = (const float*)d_in[30];
  const float* blng = (const float*)d_in[31];
  const float* blnb = (const float*)d_in[32];
  const float* bW   = (const float*)d_in[33];
  const float* bb_  = (const float*)d_in[34];
  const float* ln1g = (const float*)d_in[35];
  const float* ln1b = (const float*)d_in[36];
  const float* ln2g = (const float*)d_in[37];
  const float* ln2b = (const float*)d_in[38];
  const float* ffW1 = (const float*)d_in[39];
  const float* ffb1 = (const float*)d_in[40];
  const float* ffW2 = (const float*)d_in[41];
  const float* ffb2 = (const float*)d_in[42];

  float* out   = (float*)d_out;
  float* xout  = out;                       // 393216
  float* attn  = out + 393216;              // 2359296 (logits in place)
  float* biasO = out + 393216 + 2359296;    // 2359296

  float* ws = (float*)d_ws;
  // persistent bf16 weights [0, 327680)
  ushort_t* wqB   = (ushort_t*)(ws);             // 65536 ush
  ushort_t* wkB   = (ushort_t*)(ws + 32768);
  ushort_t* wvB   = (ushort_t*)(ws + 65536);
  ushort_t* woB   = (ushort_t*)(ws + 98304);
  ushort_t* ffW1B = (ushort_t*)(ws + 131072);    // 262144 ush
  ushort_t* ffW2B = (ushort_t*)(ws + 262144);    // 131072 ush
  // epoch 1 (pair path; dead after pair_kernel) [327680, 2794304)
  ushort_t* contP = (ushort_t*)(ws + 327680);    // 4718592 ush
  ushort_t* dcP   = (ushort_t*)(ws + 2686976);   // 98304 ush
  ushort_t* dcbP  = (ushort_t*)(ws + 2736128);   // 98304 ush
  ushort_t* EddP  = (ushort_t*)(ws + 2785280);   // 5760 ush
  ushort_t* ErsP  = (ushort_t*)(ws + 2788160);   // 3840 ush
  ushort_t* EhesP = (ushort_t*)(ws + 2790080);   // 3840 ush
  ushort_t* w1bf  = (ushort_t*)(ws + 2792000);   // 512 ush
  ushort_t* w2bf  = (ushort_t*)(ws + 2792256);   // 4096 ush
  // epoch 2 (attention/FFN; lives after pair) [327680, 3276800)
  ushort_t* xnb = (ushort_t*)(ws + 327680);      // 393216 ush
  ushort_t* qbB = (ushort_t*)(ws + 524288);
  ushort_t* kbB = (ushort_t*)(ws + 720896);
  ushort_t* vbT = (ushort_t*)(ws + 917504);
  ushort_t* aoB = (ushort_t*)(ws + 1114112);
  float* x1  = ws + 1310720;                     // 393216 f32
  float* hff = ws + 1703936;                     // 1572864 f32

  // 0) prep + pack (merged)
  prep_kernel<<<3062, 256, 0, stream>>>(dgk, ctk, Edg, Ec, cmb2, cmW1, cmb1,
      cmW2, Ed, Edi, Er, Eh, Ee, Esp, Es, Wq, Wk, Wv, Wo, ffW1, ffW2,
      dbk, drk, rpk, hdk, etk, spk, sck, pm, cont,
      dcP, dcbP, w1bf, w2bf, EddP, ErsP, EhesP,
      wqB, wkB, wvB, woB, ffW1B, ffW2B, contP);
  // 1) pair bias (MFMA, 4 tiles/wave, 3 blocks/CU)
  pair_kernel<<<2304, 256, 0, stream>>>(contP, w1bf, w2bf, EddP, ErsP, EhesP,
      blng, blnb, bW, bb_, dcP, dcbP, biasO);
  // 2) ln1 -> xnb (bf16)
  ln_kernel<<<384, 256, 0, stream>>>(x, ln1g, ln1b, xnb);
  // 3) q, k, V^T projections (all-bf16)
  qkv_kernel<<<dim3(4, 24, 3), 256, 0, stream>>>(xnb, wqB, wkB, wvB,
      qbB, kbB, vbT);
  // 4) logits = qk^T*scale + bias, safe-masked -> attn
  gemm2<1><<<dim3(6, 6, 16), 256, 0, stream>>>(qbB, nullptr, 256, kbB, 256,
      attn, 384, nullptr, nullptr, 0, 64, biasO, pm, vld);
  // 5+6) fused softmax + attn finalize + PV -> aoB
  pv_kernel<<<dim3(24, 16), 64, 0, stream>>>(attn, pm, vbT, aoB);
  // 7) Wo + bo + residual(x) -> x1
  gemm2<0><<<dim3(4, 24), 256, 0, stream>>>(aoB, nullptr, 256, woB, 256,
      x1, 256, bo, x, 256, 256, nullptr, nullptr, nullptr);
  // 8) ln2 -> xnb
  ln_kernel<<<384, 256, 0, stream>>>(x1, ln2g, ln2b, xnb);
  // 9) FF1 -> hff
  gemm2<0><<<dim3(16, 24), 256, 0, stream>>>(xnb, nullptr, 256, ffW1B, 256,
      hff, 1024, ffb1, nullptr, 0, 256, nullptr, nullptr, nullptr);
  // 10) FF2 with fused gate + ffb2 + residual(x1) -> x_out
  gemm2<3><<<dim3(4, 24), 256, 0, stream>>>(nullptr, hff, 1024, ffW2B, 512,
      xout, 256, ffb2, x1, 256, 512, nullptr, nullptr, nullptr);
}

// Round 14
// 185.184 us; speedup vs baseline: 2.7469x; 1.0190x over previous
//
#include <hip/hip_runtime.h>
#include <hip/hip_bf16.h>
#include <float.h>

// Problem constants
#define Bz   4
#define Nn   384
#define Dd   256
#define Hh   4
#define DHh  64
#define NSQ  (384*384)
#define NEG_MAX (-3.40282346638528859812e+38f)

typedef __attribute__((ext_vector_type(8))) short short8;
typedef __attribute__((ext_vector_type(4))) float f32x4;
typedef unsigned short ushort_t;

// fast exact-gelu: erf via Abramowitz-Stegun 7.1.26 (|err| <= 1.5e-7)
__device__ __forceinline__ float gelu_f(float x){
  const float y = __builtin_fabsf(x) * 0.70710678118654752f;
  const float t = __builtin_amdgcn_rcpf(fmaf(0.3275911f, y, 1.0f));
  float poly = fmaf(1.061405429f, t, -1.453152027f);
  poly = fmaf(poly, t, 1.421413741f);
  poly = fmaf(poly, t, -0.284496736f);
  poly = fmaf(poly, t, 0.254829592f);
  poly *= t;
  const float e = __expf(-y * y);
  const float erfa = fmaf(-poly, e, 1.0f);
  const float er = __builtin_copysignf(erfa, x);
  return 0.5f * x * (1.0f + er);
}
__device__ __forceinline__ float wsum(float v){
  #pragma unroll
  for (int o = 32; o > 0; o >>= 1) v += __shfl_xor(v, o, 64);
  return v;
}
__device__ __forceinline__ float4 ld4(const float* p){ return *(const float4*)p; }
__device__ __forceinline__ f32x4 ldv4(const float* p){ return *(const f32x4*)p; }

// fp32 <-> bf16
__device__ __forceinline__ ushort_t f2bfu(float f){
  union { float f; unsigned u; } v; v.f = f;
  unsigned r = v.u + 0x7FFFu + ((v.u >> 16) & 1u);
  return (ushort_t)(r >> 16);
}
__device__ __forceinline__ short f2bf(float f){ return (short)f2bfu(f); }
__device__ __forceinline__ float bfe2f(ushort_t u){
  union { unsigned u; float f; } v; v.u = ((unsigned)u) << 16; return v.f;
}
__device__ __forceinline__ void addbf(f32x4& a, f32x4& b, short8 v){
  a[0] += bfe2f((ushort_t)v[0]); a[1] += bfe2f((ushort_t)v[1]);
  a[2] += bfe2f((ushort_t)v[2]); a[3] += bfe2f((ushort_t)v[3]);
  b[0] += bfe2f((ushort_t)v[4]); b[1] += bfe2f((ushort_t)v[5]);
  b[2] += bfe2f((ushort_t)v[6]); b[3] += bfe2f((ushort_t)v[7]);
}

// ---------------------------------------------------------------------------
// prep (merged with pack): permuted bf16 tables, w1bf/w2bf, bf16 weights,
// and per-pair 16B records contP.
// ---------------------------------------------------------------------------
__global__ __launch_bounds__(256) void prep_kernel(
    const int* __restrict__ dgk, const int* __restrict__ ctk,
    const float* __restrict__ Edg, const float* __restrict__ Ec,
    const float* __restrict__ b2,
    const float* __restrict__ W1, const float* __restrict__ b1,
    const float* __restrict__ W2,
    const float* __restrict__ Ed, const float* __restrict__ Edi,
    const float* __restrict__ Er, const float* __restrict__ Eh,
    const float* __restrict__ Ee, const float* __restrict__ Esp,
    const float* __restrict__ Es,
    const float* __restrict__ Wq, const float* __restrict__ Wk,
    const float* __restrict__ Wv, const float* __restrict__ Wo,
    const float* __restrict__ ffW1, const float* __restrict__ ffW2,
    const int* __restrict__ dbk, const int* __restrict__ drk,
    const int* __restrict__ rpk, const int* __restrict__ hdk,
    const int* __restrict__ etk, const int* __restrict__ spk,
    const int* __restrict__ sck, const int* __restrict__ pm,
    const float* __restrict__ cont,
    ushort_t* __restrict__ dcP, ushort_t* __restrict__ dcbP,
    ushort_t* __restrict__ w1bf, ushort_t* __restrict__ w2bf,
    ushort_t* __restrict__ EddP, ushort_t* __restrict__ ErsP,
    ushort_t* __restrict__ EhesP,
    ushort_t* __restrict__ wqB, ushort_t* __restrict__ wkB,
    ushort_t* __restrict__ wvB, ushort_t* __restrict__ woB,
    ushort_t* __restrict__ ffW1B, ushort_t* __restrict__ ffW2B,
    ushort_t* __restrict__ contP)
{
  const int idx = blockIdx.x * 256 + threadIdx.x;
  if (idx < 24576) {                       // dcP / dcbP (permuted bf16)
    const int row = idx >> 4;
    const int q   = (idx & 15) << 2;
    const int pos = ((q >> 2) & 3) * 16 + (q >> 4) * 4;
    const float4 a = ld4(Edg + (dgk[row] << 6) + q);
    const float4 b = ld4(Ec  + (ctk[row] << 6) + q);
    const float4 bb4 = ld4(b2 + q);
    ushort4 o, o2;
    o.x = f2bfu(a.x + b.x); o.y = f2bfu(a.y + b.y);
    o.z = f2bfu(a.z + b.z); o.w = f2bfu(a.w + b.w);
    o2.x = f2bfu(a.x + b.x + bb4.x); o2.y = f2bfu(a.y + b.y + bb4.y);
    o2.z = f2bfu(a.z + b.z + bb4.z); o2.w = f2bfu(a.w + b.w + bb4.w);
    *(ushort4*)(dcP  + row * 64 + pos) = o;
    *(ushort4*)(dcbP + row * 64 + pos) = o2;
  } else if (idx < 26624) {                // w2bf [c][k]
    const int t = idx - 24576;
    const int c = t >> 5, k2 = (t & 31) << 1;
    w2bf[c * 64 + k2]     = f2bfu(W2[c * 64 + k2]);
    w2bf[c * 64 + k2 + 1] = f2bfu(W2[c * 64 + k2 + 1]);
  } else if (idx < 26688) {                // w1bf {W1 row, b1, 0} bf16
    const int k = idx - 26624;
    #pragma unroll
    for (int d = 0; d < 6; ++d) w1bf[k * 8 + d] = f2bfu(W1[k * 6 + d]);
    w1bf[k * 8 + 6] = f2bfu(b1[k]);
    w1bf[k * 8 + 7] = 0;
  } else if (idx < 28128) {                // EddP: 90 rows, permuted bf16
    const int t = idx - 26688;
    const int row = t >> 4, q = (t & 15) << 2;
    const int pos = ((q >> 2) & 3) * 16 + (q >> 4) * 4;
    const int d = row / 10, r = row - d * 10;
    const float4 a = ld4(Ed + (d << 6) + q);
    const float4 b = ld4(Edi + (r << 6) + q);
    ushort4 o;
    o.x = f2bfu(a.x + b.x); o.y = f2bfu(a.y + b.y);
    o.z = f2bfu(a.z + b.z); o.w = f2bfu(a.w + b.w);
    *(ushort4*)(EddP + row * 64 + pos) = o;
  } else if (idx < 29088) {                // ErsP: 60 rows
    const int t = idx - 28128;
    const int row = t >> 4, q = (t & 15) << 2;
    const int pos = ((q >> 2) & 3) * 16 + (q >> 4) * 4;
    const int ro = row / 6, s = row - ro * 6;
    const float4 a = ld4(Er + (ro << 6) + q);
    const float4 b = ld4(Esp + (s << 6) + q);
    ushort4 o;
    o.x = f2bfu(a.x + b.x); o.y = f2bfu(a.y + b.y);
    o.z = f2bfu(a.z + b.z); o.w = f2bfu(a.w + b.w);
    *(ushort4*)(ErsP + row * 64 + pos) = o;
  } else if (idx < 30048) {                // EhesP: 60 rows
    const int t = idx - 29088;
    const int row = t >> 4, q = (t & 15) << 2;
    const int pos = ((q >> 2) & 3) * 16 + (q >> 4) * 4;
    const int h = row / 15, rem = row - h * 15;
    const int e = rem / 3, sm = rem - e * 3;
    const float4 a = ld4(Eh + (h << 6) + q);
    const float4 b = ld4(Ee + (e << 6) + q);
    const float4 c = ld4(Es + (sm << 6) + q);
    ushort4 o;
    o.x = f2bfu(a.x + b.x + c.x); o.y = f2bfu(a.y + b.y + c.y);
    o.z = f2bfu(a.z + b.z + c.z); o.w = f2bfu(a.w + b.w + c.w);
    *(ushort4*)(EhesP + row * 64 + pos) = o;
  } else if (idx < 193888) {               // weight bf16 packs, 4 elems/thread
    const int t = idx - 30048;
    const float* src; ushort_t* dst; int e;
    if (t < 16384)      { src = Wq;   dst = wqB;   e = t << 2; }
    else if (t < 32768) { src = Wk;   dst = wkB;   e = (t - 16384) << 2; }
    else if (t < 49152) { src = Wv;   dst = wvB;   e = (t - 32768) << 2; }
    else if (t < 65536) { src = Wo;   dst = woB;   e = (t - 49152) << 2; }
    else if (t < 131072){ src = ffW1; dst = ffW1B; e = (t - 65536) << 2; }
    else                { src = ffW2; dst = ffW2B; e = (t - 131072) << 2; }
    const float4 v = ld4(src + e);
    ushort4 o;
    o.x = f2bfu(v.x); o.y = f2bfu(v.y); o.z = f2bfu(v.z); o.w = f2bfu(v.w);
    *(ushort4*)(dst + e) = o;
  } else if (idx < 193888 + Bz * Nn * Nn) { // pack: per-pair 16B record
    const int p = idx - 193888;
    const float* cp = cont + (size_t)p * 6;
    short8 r;
    r[0] = f2bf(cp[0]); r[1] = f2bf(cp[1]); r[2] = f2bf(cp[2]);
    r[3] = f2bf(cp[3]); r[4] = f2bf(cp[4]); r[5] = f2bf(cp[5]);
    const unsigned iv = (unsigned)(dbk[p] * 10 + drk[p])
                      | ((unsigned)(rpk[p] * 6 + spk[p]) << 7)
                      | ((unsigned)((hdk[p] * 5 + etk[p]) * 3 + sck[p]) << 13)
                      | ((pm[p] ? 1u : 0u) << 19);
    r[6] = (short)(iv & 0xffffu);
    r[7] = (short)(iv >> 16);
    *(short8*)(contP + (size_t)p * 8) = r;
  }
}

// ---------------------------------------------------------------------------
// Fused pair kernel (v11 structure, launch_bounds(256,2): no-spill config).
// ---------------------------------------------------------------------------
__global__ __launch_bounds__(256, 2) void pair_kernel(
    const ushort_t* __restrict__ contP,
    const ushort_t* __restrict__ w1bf, const ushort_t* __restrict__ w2bf,
    const ushort_t* __restrict__ EddP, const ushort_t* __restrict__ ErsP,
    const ushort_t* __restrict__ EhesP,
    const float* __restrict__ lng, const float* __restrict__ lnb,
    const float* __restrict__ bW, const float* __restrict__ bb,
    const ushort_t* __restrict__ dcP, const ushort_t* __restrict__ dcbP,
    float* __restrict__ biasOut)
{
  const int tid  = threadIdx.x;
  const int lane = tid & 63;
  const int l15  = lane & 15, lg = lane >> 4;
  const int wid  = blockIdx.x * 4 + (tid >> 6);             // [0, 9216)
  const int rowU = __builtin_amdgcn_readfirstlane(wid / 6); // b*N+i
  const int jb   = wid - rowU * 6;
  const int b    = rowU / Nn;
  const int i    = rowU - b * Nn;
  const int j0   = jb * 64 + l15;
  const size_t pbase = (size_t)rowU * Nn + j0;
  const int colOff = lg << 2;

  const short8 rec0 = *(const short8*)(contP + (pbase + 0) * 8);
  const short8 rec1 = *(const short8*)(contP + (pbase + 16) * 8);
  const short8 rec2 = *(const short8*)(contP + (pbase + 32) * 8);
  const short8 rec3 = *(const short8*)(contP + (pbase + 48) * 8);
  asm volatile("" :: "v"(rec0), "v"(rec1), "v"(rec2), "v"(rec3));
  const unsigned ix0 = (unsigned)(ushort_t)rec0[6] | ((unsigned)(ushort_t)rec0[7] << 16);
  const unsigned ix1 = (unsigned)(ushort_t)rec1[6] | ((unsigned)(ushort_t)rec1[7] << 16);
  const unsigned ix2 = (unsigned)(ushort_t)rec2[6] | ((unsigned)(ushort_t)rec2[7] << 16);
  const unsigned ix3 = (unsigned)(ushort_t)rec3[6] | ((unsigned)(ushort_t)rec3[7] << 16);
  const float c00 = bfe2f((ushort_t)rec0[0]), c01 = bfe2f((ushort_t)rec0[1]),
              c02 = bfe2f((ushort_t)rec0[2]), c03 = bfe2f((ushort_t)rec0[3]),
              c04 = bfe2f((ushort_t)rec0[4]), c05 = bfe2f((ushort_t)rec0[5]);
  const float c10 = bfe2f((ushort_t)rec1[0]), c11 = bfe2f((ushort_t)rec1[1]),
              c12 = bfe2f((ushort_t)rec1[2]), c13 = bfe2f((ushort_t)rec1[3]),
              c14 = bfe2f((ushort_t)rec1[4]), c15 = bfe2f((ushort_t)rec1[5]);
  const float c20 = bfe2f((ushort_t)rec2[0]), c21 = bfe2f((ushort_t)rec2[1]),
              c22 = bfe2f((ushort_t)rec2[2]), c23 = bfe2f((ushort_t)rec2[3]),
              c24 = bfe2f((ushort_t)rec2[4]), c25 = bfe2f((ushort_t)rec2[5]);
  const float c30 = bfe2f((ushort_t)rec3[0]), c31 = bfe2f((ushort_t)rec3[1]),
              c32 = bfe2f((ushort_t)rec3[2]), c33 = bfe2f((ushort_t)rec3[3]),
              c34 = bfe2f((ushort_t)rec3[4]), c35 = bfe2f((ushort_t)rec3[5]);

  short8 b0a, b0b, b1a, b1b, b2a, b2b, b3a, b3b;
#define H1ROW(R, JJ, D0, D1, D2, D3) { \
    const float w0 = bfe2f((ushort_t)R[0]), w1 = bfe2f((ushort_t)R[1]), \
                w2 = bfe2f((ushort_t)R[2]), w3 = bfe2f((ushort_t)R[3]), \
                w4 = bfe2f((ushort_t)R[4]), w5 = bfe2f((ushort_t)R[5]), \
                w6 = bfe2f((ushort_t)R[6]); \
    float s0 = w6, s1 = w6, s2 = w6, s3 = w6; \
    s0 = fmaf(w0, c00, s0); s0 = fmaf(w1, c01, s0); s0 = fmaf(w2, c02, s0); \
    s0 = fmaf(w3, c03, s0); s0 = fmaf(w4, c04, s0); s0 = fmaf(w5, c05, s0); \
    s1 = fmaf(w0, c10, s1); s1 = fmaf(w1, c11, s1); s1 = fmaf(w2, c12, s1); \
    s1 = fmaf(w3, c13, s1); s1 = fmaf(w4, c14, s1); s1 = fmaf(w5, c15, s1); \
    s2 = fmaf(w0, c20, s2); s2 = fmaf(w1, c21, s2); s2 = fmaf(w2, c22, s2); \
    s2 = fmaf(w3, c23, s2); s2 = fmaf(w4, c24, s2); s2 = fmaf(w5, c25, s2); \
    s3 = fmaf(w0, c30, s3); s3 = fmaf(w1, c31, s3); s3 = fmaf(w2, c32, s3); \
    s3 = fmaf(w3, c33, s3); s3 = fmaf(w4, c34, s3); s3 = fmaf(w5, c35, s3); \
    D0[JJ] = f2bf(gelu_f(s0)); D1[JJ] = f2bf(gelu_f(s1)); \
    D2[JJ] = f2bf(gelu_f(s2)); D3[JJ] = f2bf(gelu_f(s3)); }
  {
    const ushort_t* wb_ = w1bf + ((lg << 3) << 3);
    const short8 r0 = *(const short8*)(wb_ +  0);
    const short8 r1 = *(const short8*)(wb_ +  8);
    const short8 r2 = *(const short8*)(wb_ + 16);
    const short8 r3 = *(const short8*)(wb_ + 24);
    const short8 r4 = *(const short8*)(wb_ + 32);
    const short8 r5 = *(const short8*)(wb_ + 40);
    const short8 r6 = *(const short8*)(wb_ + 48);
    const short8 r7 = *(const short8*)(wb_ + 56);
    asm volatile("" :: "v"(r0), "v"(r1), "v"(r2), "v"(r3),
                       "v"(r4), "v"(r5), "v"(r6), "v"(r7));
    H1ROW(r0, 0, b0a, b1a, b2a, b3a) H1ROW(r1, 1, b0a, b1a, b2a, b3a)
    H1ROW(r2, 2, b0a, b1a, b2a, b3a) H1ROW(r3, 3, b0a, b1a, b2a, b3a)
    H1ROW(r4, 4, b0a, b1a, b2a, b3a) H1ROW(r5, 5, b0a, b1a, b2a, b3a)
    H1ROW(r6, 6, b0a, b1a, b2a, b3a) H1ROW(r7, 7, b0a, b1a, b2a, b3a)
  }
  {
    const ushort_t* wb_ = w1bf + ((32 + (lg << 3)) << 3);
    const short8 r0 = *(const short8*)(wb_ +  0);
    const short8 r1 = *(const short8*)(wb_ +  8);
    const short8 r2 = *(const short8*)(wb_ + 16);
    const short8 r3 = *(const short8*)(wb_ + 24);
    const short8 r4 = *(const short8*)(wb_ + 32);
    const short8 r5 = *(const short8*)(wb_ + 40);
    const short8 r6 = *(const short8*)(wb_ + 48);
    const short8 r7 = *(const short8*)(wb_ + 56);
    asm volatile("" :: "v"(r0), "v"(r1), "v"(r2), "v"(r3),
                       "v"(r4), "v"(r5), "v"(r6), "v"(r7));
    H1ROW(r0, 0, b0b, b1b, b2b, b3b) H1ROW(r1, 1, b0b, b1b, b2b, b3b)
    H1ROW(r2, 2, b0b, b1b, b2b, b3b) H1ROW(r3, 3, b0b, b1b, b2b, b3b)
    H1ROW(r4, 4, b0b, b1b, b2b, b3b) H1ROW(r5, 5, b0b, b1b, b2b, b3b)
    H1ROW(r6, 6, b0b, b1b, b2b, b3b) H1ROW(r7, 7, b0b, b1b, b2b, b3b)
  }
#undef H1ROW

  const ushort_t* wbase = w2bf + (size_t)l15 * 64 + (lg << 3);
  const short8 wa0 = *(const short8*)(wbase);
  const short8 wc0 = *(const short8*)(wbase + 32);
  const short8 wa1 = *(const short8*)(wbase + 16 * 64);
  const short8 wc1 = *(const short8*)(wbase + 16 * 64 + 32);
  const short8 wa2 = *(const short8*)(wbase + 32 * 64);
  const short8 wc2 = *(const short8*)(wbase + 32 * 64 + 32);
  const short8 wa3 = *(const short8*)(wbase + 48 * 64);
  const short8 wc3 = *(const short8*)(wbase + 48 * 64 + 32);
  asm volatile("" :: "v"(wa0), "v"(wc0), "v"(wa1), "v"(wc1),
                     "v"(wa2), "v"(wc2), "v"(wa3), "v"(wc3));
  f32x4 acc0[4] = {}, acc1[4] = {}, acc2[4] = {}, acc3[4] = {};
#define MM(ACC, BA, BB) \
  ACC[0] = __builtin_amdgcn_mfma_f32_16x16x32_bf16(wa0, BA, ACC[0], 0, 0, 0); \
  ACC[0] = __builtin_amdgcn_mfma_f32_16x16x32_bf16(wc0, BB, ACC[0], 0, 0, 0); \
  ACC[1] = __builtin_amdgcn_mfma_f32_16x16x32_bf16(wa1, BA, ACC[1], 0, 0, 0); \
  ACC[1] = __builtin_amdgcn_mfma_f32_16x16x32_bf16(wc1, BB, ACC[1], 0, 0, 0); \
  ACC[2] = __builtin_amdgcn_mfma_f32_16x16x32_bf16(wa2, BA, ACC[2], 0, 0, 0); \
  ACC[2] = __builtin_amdgcn_mfma_f32_16x16x32_bf16(wc2, BB, ACC[2], 0, 0, 0); \
  ACC[3] = __builtin_amdgcn_mfma_f32_16x16x32_bf16(wa3, BA, ACC[3], 0, 0, 0); \
  ACC[3] = __builtin_amdgcn_mfma_f32_16x16x32_bf16(wc3, BB, ACC[3], 0, 0, 0);
  MM(acc0, b0a, b0b) MM(acc1, b1a, b1b) MM(acc2, b2a, b2b) MM(acc3, b3a, b3b)
#undef MM

#define GATHER(ACC, IX, JOFF) { \
    const int xdd  = ((IX) & 127) << 6; \
    const int xrs  = (((IX) >> 7) & 63) << 6; \
    const int xhes = (((IX) >> 13) & 63) << 6; \
    const ushort_t* ep = EddP  + xdd  + (lg << 4); \
    const ushort_t* rp = ErsP  + xrs  + (lg << 4); \
    const ushort_t* hp = EhesP + xhes + (lg << 4); \
    const ushort_t* jp = dcP + (((size_t)(b * Nn + j0 + (JOFF))) << 6) + (lg << 4); \
    const short8 e0 = *(const short8*)ep,       e1 = *(const short8*)(ep + 8); \
    const short8 r0 = *(const short8*)rp,       r1 = *(const short8*)(rp + 8); \
    const short8 h0 = *(const short8*)hp,       h1 = *(const short8*)(hp + 8); \
    const short8 jv0 = *(const short8*)jp,      jv1 = *(const short8*)(jp + 8); \
    asm volatile("" :: "v"(e0), "v"(e1), "v"(r0), "v"(r1), \
                       "v"(h0), "v"(h1), "v"(jv0), "v"(jv1)); \
    addbf(ACC[0], ACC[1], e0);  addbf(ACC[2], ACC[3], e1); \
    addbf(ACC[0], ACC[1], r0);  addbf(ACC[2], ACC[3], r1); \
    addbf(ACC[0], ACC[1], h0);  addbf(ACC[2], ACC[3], h1); \
    addbf(ACC[0], ACC[1], jv0); addbf(ACC[2], ACC[3], jv1); }
  GATHER(acc0, ix0, 0)
  GATHER(acc1, ix1, 16)
  GATHER(acc2, ix2, 32)
  GATHER(acc3, ix3, 48)
#undef GATHER
  {
    const ushort_t* up = dcbP + (((size_t)rowU) << 6) + (lg << 4);
    const short8 u0 = *(const short8*)up, u1 = *(const short8*)(up + 8);
    f32x4 du0, du1, du2, du3;
    #pragma unroll
    for (int r = 0; r < 4; ++r) {
      du0[r] = bfe2f((ushort_t)u0[r]);     du1[r] = bfe2f((ushort_t)u0[4 + r]);
      du2[r] = bfe2f((ushort_t)u1[r]);     du3[r] = bfe2f((ushort_t)u1[4 + r]);
    }
    acc0[0] += du0; acc0[1] += du1; acc0[2] += du2; acc0[3] += du3;
    acc1[0] += du0; acc1[1] += du1; acc1[2] += du2; acc1[3] += du3;
    acc2[0] += du0; acc2[1] += du1; acc2[2] += du2; acc2[3] += du3;
    acc3[0] += du0; acc3[1] += du1; acc3[2] += du2; acc3[3] += du3;
  }

  float mean0, inv0, mean1, inv1, mean2, inv2, mean3, inv3;
#define STATS(ACC, MEAN, INV) { \
    float sum = 0.f, sq = 0.f; \
    _Pragma("unroll") \
    for (int mt = 0; mt < 4; ++mt) \
      _Pragma("unroll") \
      for (int r = 0; r < 4; ++r) { \
        const float v = ACC[mt][r]; sum += v; sq = fmaf(v, v, sq); } \
    sum += __shfl_xor(sum, 16, 64); sum += __shfl_xor(sum, 32, 64); \
    sq  += __shfl_xor(sq,  16, 64); sq  += __shfl_xor(sq,  32, 64); \
    MEAN = sum * (1.f / 64.f); \
    INV  = rsqrtf(sq * (1.f / 64.f) - MEAN * MEAN + 1e-5f); }
  STATS(acc0, mean0, inv0) STATS(acc1, mean1, inv1)
  STATS(acc2, mean2, inv2) STATS(acc3, mean3, inv3)
#undef STATS

  float h00 = 0.f, h01 = 0.f, h02 = 0.f, h03 = 0.f;
  float h10 = 0.f, h11 = 0.f, h12 = 0.f, h13 = 0.f;
  float h20 = 0.f, h21 = 0.f, h22 = 0.f, h23 = 0.f;
  float h30 = 0.f, h31 = 0.f, h32 = 0.f, h33 = 0.f;
  #pragma unroll
  for (int mt = 0; mt < 4; ++mt) {
    const int c0i = (mt << 4) + colOff;
    const f32x4 g4 = ldv4(lng + c0i);
    const f32x4 b4 = ldv4(lnb + c0i);
    const f32x4 w0 = ldv4(bW + c0i);
    const f32x4 w1_ = ldv4(bW + 64 + c0i);
    const f32x4 w2_ = ldv4(bW + 128 + c0i);
    const f32x4 w3_ = ldv4(bW + 192 + c0i);
    asm volatile("" :: "v"(g4), "v"(b4), "v"(w0), "v"(w1_), "v"(w2_), "v"(w3_));
    #pragma unroll
    for (int r = 0; r < 4; ++r) {
      float g;
      g = gelu_f((acc0[mt][r] - mean0) * inv0 * g4[r] + b4[r]);
      h00 = fmaf(w0[r], g, h00); h01 = fmaf(w1_[r], g, h01);
      h02 = fmaf(w2_[r], g, h02); h03 = fmaf(w3_[r], g, h03);
      g = gelu_f((acc1[mt][r] - mean1) * inv1 * g4[r] + b4[r]);
      h10 = fmaf(w0[r], g, h10); h11 = fmaf(w1_[r], g, h11);
      h12 = fmaf(w2_[r], g, h12); h13 = fmaf(w3_[r], g, h13);
      g = gelu_f((acc2[mt][r] - mean2) * inv2 * g4[r] + b4[r]);
      h20 = fmaf(w0[r], g, h20); h21 = fmaf(w1_[r], g, h21);
      h22 = fmaf(w2_[r], g, h22); h23 = fmaf(w3_[r], g, h23);
      g = gelu_f((acc3[mt][r] - mean3) * inv3 * g4[r] + b4[r]);
      h30 = fmaf(w0[r], g, h30); h31 = fmaf(w1_[r], g, h31);
      h32 = fmaf(w2_[r], g, h32); h33 = fmaf(w3_[r], g, h33);
    }
  }
#define RED(H) H += __shfl_xor(H, 16, 64); H += __shfl_xor(H, 32, 64);
  RED(h00) RED(h01) RED(h02) RED(h03)
  RED(h10) RED(h11) RED(h12) RED(h13)
  RED(h20) RED(h21) RED(h22) RED(h23)
  RED(h30) RED(h31) RED(h32) RED(h33)
#undef RED

  const float bbl = bb[lg];
  const float bh0 = ((lg == 0) ? h00 : (lg == 1) ? h01 : (lg == 2) ? h02 : h03) + bbl;
  const float bh1 = ((lg == 0) ? h10 : (lg == 1) ? h11 : (lg == 2) ? h12 : h13) + bbl;
  const float bh2 = ((lg == 0) ? h20 : (lg == 1) ? h21 : (lg == 2) ? h22 : h23) + bbl;
  const float bh3 = ((lg == 0) ? h30 : (lg == 1) ? h31 : (lg == 2) ? h32 : h33) + bbl;
  const size_t base = (size_t)b * (Hh * NSQ) + (size_t)lg * NSQ + (size_t)i * Nn;
  biasOut[base + j0]      = bh0 * (((ix0 >> 19) & 1) ? 1.f : 0.f);
  biasOut[base + j0 + 16] = bh1 * (((ix1 >> 19) & 1) ? 1.f : 0.f);
  biasOut[base + j0 + 32] = bh2 * (((ix2 >> 19) & 1) ? 1.f : 0.f);
  biasOut[base + j0 + 48] = bh3 * (((ix3 >> 19) & 1) ? 1.f : 0.f);
}

// ---------------------------------------------------------------------------
// LayerNorm over last dim (256), bf16 output. One wave per row.
// ---------------------------------------------------------------------------
__global__ __launch_bounds__(256) void ln_kernel(
    const float* __restrict__ x, const float* __restrict__ g,
    const float* __restrict__ bta, ushort_t* __restrict__ o)
{
  const int row  = blockIdx.x * 4 + (threadIdx.x >> 6);
  const int lane = threadIdx.x & 63;
  const float4 v = *(const float4*)(x + (size_t)row * Dd + lane * 4);
  float s = v.x + v.y + v.z + v.w;
  s = wsum(s);
  const float m = s * (1.f / 256.f);
  const float dx = v.x - m, dy = v.y - m, dz = v.z - m, dw = v.w - m;
  float q = dx*dx + dy*dy + dz*dz + dw*dw;
  q = wsum(q);
  const float inv = rsqrtf(q * (1.f / 256.f) + 1e-5f);
  const int d = lane * 4;
  const float4 gg = *(const float4*)(g + d);
  const float4 bb = *(const float4*)(bta + d);
  ushort4 out;
  out.x = f2bfu(dx * inv * gg.x + bb.x);
  out.y = f2bfu(dy * inv * gg.y + bb.y);
  out.z = f2bfu(dz * inv * gg.z + bb.z);
  out.w = f2bfu(dw * inv * gg.w + bb.w);
  *(ushort4*)(o + (size_t)row * Dd + d) = out;
}

// ---------------------------------------------------------------------------
// Fused QKV: all-bf16 fragments. z: {wqB->qbB, wkB->kbB, wvB->vbT}.
// ---------------------------------------------------------------------------
__global__ __launch_bounds__(256) void qkv_kernel(
    const ushort_t* __restrict__ xnb,
    const ushort_t* __restrict__ wqB, const ushort_t* __restrict__ wkB,
    const ushort_t* __restrict__ wvB,
    ushort_t* __restrict__ qbB, ushort_t* __restrict__ kbB,
    ushort_t* __restrict__ vbT)
{
  const int tid = threadIdx.x;
  const int lane = tid & 63;
  const int w   = tid >> 6;
  const int l15 = lane & 15, lg = lane >> 4;
  const int m0 = blockIdx.y * 64 + w * 16;
  const int n0 = blockIdx.x * 64;
  const int z  = blockIdx.z;
  const ushort_t* Bb = (z == 0) ? wqB : (z == 1) ? wkB : wvB;

  f32x4 acc[4] = {};
  const ushort_t* pa = xnb + (size_t)(m0 + l15) * Dd + lg * 8;
  for (int k0 = 0; k0 < Dd; k0 += 32) {
    const short8 af = *(const short8*)(pa + k0);
    #pragma unroll
    for (int nt = 0; nt < 4; ++nt) {
      const short8 bf = *(const short8*)(Bb +
          (size_t)(n0 + nt * 16 + l15) * Dd + k0 + lg * 8);
      acc[nt] = __builtin_amdgcn_mfma_f32_16x16x32_bf16(af, bf, acc[nt], 0, 0, 0);
    }
  }
  if (z < 2) {
    ushort_t* Cb = (z == 0) ? qbB : kbB;
    #pragma unroll
    for (int nt = 0; nt < 4; ++nt)
      #pragma unroll
      for (int r = 0; r < 4; ++r)
        Cb[(size_t)(m0 + lg * 4 + r) * Dd + n0 + nt * 16 + l15] = f2bfu(acc[nt][r]);
  } else {
    const int m = m0 + (lg << 2);
    const int b = m / Nn, tok = m - b * Nn;
    #pragma unroll
    for (int nt = 0; nt < 4; ++nt) {
      const int n = n0 + nt * 16 + l15;
      const int h = n >> 6, dh = n & 63;
      ushort4 s4;
      s4.x = f2bfu(acc[nt][0]); s4.y = f2bfu(acc[nt][1]);
      s4.z = f2bfu(acc[nt][2]); s4.w = f2bfu(acc[nt][3]);
      *(ushort4*)(vbT + ((size_t)((b * 4 + h) * 64 + dh)) * Nn + tok) = s4;
    }
  }
}

// ---------------------------------------------------------------------------
// Fused attention: QK^T + bias + safe-mask + softmax + pair-mask renorm +
// attn write + PV, one block per (16-row tile, bz). 4 waves; wave w owns
// 96 columns. P staged per-wave in LDS for the PV transpose.
// ---------------------------------------------------------------------------
__global__ __launch_bounds__(256) void attn_kernel(
    const ushort_t* __restrict__ qbB, const ushort_t* __restrict__ kbB,
    const ushort_t* __restrict__ vbT,
    const float* __restrict__ biasO, const int* __restrict__ pm,
    const int* __restrict__ vld,
    float* __restrict__ attn, ushort_t* __restrict__ aoB)
{
  __shared__ float stats[3][4][16];
  __shared__ float part[4][16][64];          // 16 KB
  __shared__ ushort_t pstage[4][16][104];    // 13 KB
  const int tid = threadIdx.x;
  const int lane = tid & 63, w = tid >> 6;
  const int l15 = lane & 15, lg = lane >> 4;
  const int bz = blockIdx.y, b = bz >> 2, h = bz & 3;
  const int m0 = blockIdx.x * 16;
  const int n0 = w * 96;

  // ---- QK^T: 16 x 96 logits per wave ----
  f32x4 acc[6];
  const ushort_t* paq = qbB + ((size_t)(b * Nn + m0 + l15)) * Dd + h * DHh;
  const short8 aq0 = *(const short8*)(paq + lg * 8);
  const short8 aq1 = *(const short8*)(paq + 32 + lg * 8);
  #pragma unroll
  for (int nt = 0; nt < 6; ++nt) {
    const ushort_t* pk = kbB + ((size_t)(b * Nn + n0 + nt * 16 + l15)) * Dd
                       + h * DHh + lg * 8;
    const short8 bk0 = *(const short8*)pk;
    const short8 bk1 = *(const short8*)(pk + 32);
    f32x4 a = {};
    a = __builtin_amdgcn_mfma_f32_16x16x32_bf16(aq0, bk0, a, 0, 0, 0);
    a = __builtin_amdgcn_mfma_f32_16x16x32_bf16(aq1, bk1, a, 0, 0, 0);
    acc[nt] = a;
  }

  // ---- bias + safe mask (in place in acc), pm bits packed ----
  const float* bias_r = biasO + (size_t)bz * NSQ;
  const int* pm_b = pm + (size_t)b * NSQ;
  int vldv[4];
  #pragma unroll
  for (int r = 0; r < 4; ++r) vldv[r] = vld[b * Nn + m0 + lg * 4 + r];
  unsigned pmmask = 0;
  #pragma unroll
  for (int nt = 0; nt < 6; ++nt) {
    #pragma unroll
    for (int r = 0; r < 4; ++r) {
      const int m = m0 + lg * 4 + r;
      const int n = n0 + nt * 16 + l15;
      const size_t off = (size_t)m * Nn + n;
      const float bv = bias_r[off];
      const int q = pm_b[off];
      const bool sf = (q != 0) || (vldv[r] == 0 && m == n);
      if (q) pmmask |= 1u << (nt * 4 + r);
      acc[nt][r] = sf ? fmaf(acc[nt][r], 0.125f, bv) : NEG_MAX;
    }
  }

  // ---- per-row stats over this wave's 96 cols ----
  float mx[4], sr[4], spr[4];
  #pragma unroll
  for (int r = 0; r < 4; ++r) {
    float m_ = NEG_MAX;
    #pragma unroll
    for (int nt = 0; nt < 6; ++nt) m_ = fmaxf(m_, acc[nt][r]);
    #pragma unroll
    for (int o = 1; o <= 8; o <<= 1) m_ = fmaxf(m_, __shfl_xor(m_, o, 64));
    float s_ = 0.f, sp_ = 0.f;
    #pragma unroll
    for (int nt = 0; nt < 6; ++nt) {
      const float e = __expf(acc[nt][r] - m_);
      s_ += e;
      sp_ += ((pmmask >> (nt * 4 + r)) & 1) ? e : 0.f;
    }
    #pragma unroll
    for (int o = 1; o <= 8; o <<= 1) {
      s_ += __shfl_xor(s_, o, 64);
      sp_ += __shfl_xor(sp_, o, 64);
    }
    mx[r] = m_; sr[r] = s_; spr[r] = sp_;
  }
  if (l15 == 0) {
    #pragma unroll
    for (int r = 0; r < 4; ++r) {
      stats[0][w][lg * 4 + r] = mx[r];
      stats[1][w][lg * 4 + r] = sr[r];
      stats[2][w][lg * 4 + r] = spr[r];
    }
  }
  __syncthreads();
  float mr[4], rinv[4];
  #pragma unroll
  for (int r = 0; r < 4; ++r) {
    const int row = lg * 4 + r;
    float M = NEG_MAX, S = 0.f, SP = 0.f;
    #pragma unroll
    for (int wv = 0; wv < 4; ++wv) {
      const float m2 = stats[0][wv][row];
      const float s2 = stats[1][wv][row];
      const float sp2 = stats[2][wv][row];
      const float mn = fmaxf(M, m2);
      const float f1 = __expf(M - mn), f2 = __expf(m2 - mn);
      S = S * f1 + s2 * f2;
      SP = SP * f1 + sp2 * f2;
      M = mn;
    }
    mr[r] = M;
    rinv[r] = 1.f / fmaxf(SP, 1e-6f * S);
  }

  // ---- attn values: write global + stage bf16 P in per-wave LDS ----
  float* attn_b = attn + (size_t)bz * NSQ;
  #pragma unroll
  for (int nt = 0; nt < 6; ++nt) {
    #pragma unroll
    for (int r = 0; r < 4; ++r) {
      const int m = m0 + lg * 4 + r;
      const int n = n0 + nt * 16 + l15;
      const float e = __expf(acc[nt][r] - mr[r]);
      const float a = ((pmmask >> (nt * 4 + r)) & 1) ? e * rinv[r] : 0.f;
      attn_b[(size_t)m * Nn + n] = a;
      pstage[w][lg * 4 + r][nt * 16 + l15] = f2bfu(a);
    }
  }
  __syncthreads();

  // ---- PV: wave w covers tok in [n0, n0+96); A = P from own LDS region ----
  f32x4 pacc[4] = {};
  const ushort_t* vb0 = vbT + (size_t)(bz * 64) * Nn;
  #pragma unroll
  for (int ks = 0; ks < 3; ++ks) {
    const int ktok = ks * 32 + lg * 8;           // local tok offset
    const short8 ap = *(const short8*)&pstage[w][l15][ktok];
    #pragma unroll
    for (int nt = 0; nt < 4; ++nt) {
      const short8 bvv = *(const short8*)(vb0 +
          (size_t)(nt * 16 + l15) * Nn + n0 + ktok);
      pacc[nt] = __builtin_amdgcn_mfma_f32_16x16x32_bf16(ap, bvv, pacc[nt], 0, 0, 0);
    }
  }
  // partials -> LDS
  #pragma unroll
  for (int nt = 0; nt < 4; ++nt)
    #pragma unroll
    for (int r = 0; r < 4; ++r)
      part[w][lg * 4 + r][nt * 16 + l15] = pacc[nt][r];
  __syncthreads();
  // combine + store: thread t -> 4 outputs (row = o>>6, dh0 = o&63)
  {
    const int o = tid * 4;
    const int row = o >> 6, dh0 = o & 63;
    f32x4 s = *(const f32x4*)&part[0][row][dh0];
    s += *(const f32x4*)&part[1][row][dh0];
    s += *(const f32x4*)&part[2][row][dh0];
    s += *(const f32x4*)&part[3][row][dh0];
    ushort4 st;
    st.x = f2bfu(s[0]); st.y = f2bfu(s[1]); st.z = f2bfu(s[2]); st.w = f2bfu(s[3]);
    *(ushort4*)(aoB + (size_t)(b * Nn + m0 + row) * Dd + h * 64 + dh0) = st;
  }
}

// ---------------------------------------------------------------------------
// bf16-operand MFMA GEMM. Wave = 16(M) x 64(N); block = 4 waves.
// MODE 0: C(f32) = A16 @ B^T (+bias)(+res)   grid (Nc/64, M/64)
// MODE 3: C = (a*gelu(g)) @ B^T (+bias)(+res), A32 = hff f32
// ---------------------------------------------------------------------------
template<int MODE>
__global__ __launch_bounds__(256) void gemm2(
    const ushort_t* __restrict__ A16, const float* __restrict__ A32, int lda,
    const ushort_t* __restrict__ Bm, int ldb,
    float* __restrict__ Cc, int ldc,
    const float* __restrict__ bias,
    const float* __restrict__ res, int ldr,
    int K)
{
  const int tid = threadIdx.x;
  const int lane = tid & 63;
  const int w   = tid >> 6;
  const int l15 = lane & 15, lg = lane >> 4;
  const int m0 = blockIdx.y * 64 + w * 16;
  const int n0 = blockIdx.x * 64;

  f32x4 acc[4] = {};
  const ushort_t* pa16 = A16 + (size_t)(m0 + l15) * lda + lg * 8;
  const float* pa32 = (MODE == 3) ? (A32 + (size_t)(m0 + l15) * lda + lg * 8) : nullptr;

  for (int k0 = 0; k0 < K; k0 += 32) {
    short8 af;
    if (MODE == 3) {
      const float4 a0 = ld4(pa32 + k0);
      const float4 a1 = ld4(pa32 + k0 + 4);
      const float4 g0 = ld4(pa32 + 512 + k0);
      const float4 g1 = ld4(pa32 + 512 + k0 + 4);
      af[0] = f2bf(a0.x * gelu_f(g0.x)); af[1] = f2bf(a0.y * gelu_f(g0.y));
      af[2] = f2bf(a0.z * gelu_f(g0.z)); af[3] = f2bf(a0.w * gelu_f(g0.w));
      af[4] = f2bf(a1.x * gelu_f(g1.x)); af[5] = f2bf(a1.y * gelu_f(g1.y));
      af[6] = f2bf(a1.z * gelu_f(g1.z)); af[7] = f2bf(a1.w * gelu_f(g1.w));
    } else {
      af = *(const short8*)(pa16 + k0);
    }
    #pragma unroll
    for (int nt = 0; nt < 4; ++nt) {
      const short8 bf = *(const short8*)(Bm +
          (size_t)(n0 + nt * 16 + l15) * ldb + k0 + lg * 8);
      acc[nt] = __builtin_amdgcn_mfma_f32_16x16x32_bf16(af, bf, acc[nt], 0, 0, 0);
    }
  }

  #pragma unroll
  for (int nt = 0; nt < 4; ++nt) {
    #pragma unroll
    for (int r = 0; r < 4; ++r) {
      const int m = m0 + lg * 4 + r;
      const int n = n0 + nt * 16 + l15;
      float v = acc[nt][r];
      if (bias) v += bias[n];
      if (res)  v += res[(size_t)m * ldr + n];
      Cc[(size_t)m * ldc + n] = v;
    }
  }
}

// ---------------------------------------------------------------------------
extern "C" void kernel_launch(void* const* d_in, const int* in_sizes, int n_in,
                              void* d_out, int out_size, void* d_ws, size_t ws_size,
                              hipStream_t stream) {
  const float* x    = (const float*)d_in[0];
  const int*   pm   = (const int*)  d_in[1];
  const int*   vld  = (const int*)  d_in[2];
  const float* cont = (const float*)d_in[3];
  const int* dbk = (const int*)d_in[4];
  const int* drk = (const int*)d_in[5];
  const int* rpk = (const int*)d_in[6];
  const int* hdk = (const int*)d_in[7];
  const int* etk = (const int*)d_in[8];
  const int* spk = (const int*)d_in[9];
  const int* sck = (const int*)d_in[10];
  const int* dgk = (const int*)d_in[11];
  const int* ctk = (const int*)d_in[12];
  const float* Wq  = (const float*)d_in[13];
  const float* Wk  = (const float*)d_in[14];
  const float* Wv  = (const float*)d_in[15];
  const float* Wo  = (const float*)d_in[16];
  const float* bo  = (const float*)d_in[17];
  const float* cmW1 = (const float*)d_in[18];
  const float* cmb1 = (const float*)d_in[19];
  const float* cmW2 = (const float*)d_in[20];
  const float* cmb2 = (const float*)d_in[21];
  const float* Ed  = (const float*)d_in[22];
  const float* Edi = (const float*)d_in[23];
  const float* Er  = (const float*)d_in[24];
  const float* Eh  = (const float*)d_in[25];
  const float* Ee  = (const float*)d_in[26];
  const float* Esp = (const float*)d_in[27];
  const float* Edg = (const float*)d_in[28];
  const float* Ec  = (const float*)d_in[29];
  const float* Es  = (const float*)d_in[30];
  const float* blng = (const float*)d_in[31];
  const float* blnb = (const float*)d_in[32];
  const float* bW   = (const float*)d_in[33];
  const float* bb_  = (const float*)d_in[34];
  const float* ln1g = (const float*)d_in[35];
  const float* ln1b = (const float*)d_in[36];
  const float* ln2g = (const float*)d_in[37];
  const float* ln2b = (const float*)d_in[38];
  const float* ffW1 = (const float*)d_in[39];
  const float* ffb1 = (const float*)d_in[40];
  const float* ffW2 = (const float*)d_in[41];
  const float* ffb2 = (const float*)d_in[42];

  float* out   = (float*)d_out;
  float* xout  = out;                       // 393216
  float* attn  = out + 393216;              // 2359296
  float* biasO = out + 393216 + 2359296;    // 2359296

  float* ws = (float*)d_ws;
  // persistent bf16 weights [0, 327680)
  ushort_t* wqB   = (ushort_t*)(ws);             // 65536 ush
  ushort_t* wkB   = (ushort_t*)(ws + 32768);
  ushort_t* wvB   = (ushort_t*)(ws + 65536);
  ushort_t* woB   = (ushort_t*)(ws + 98304);
  ushort_t* ffW1B = (ushort_t*)(ws + 131072);    // 262144 ush
  ushort_t* ffW2B = (ushort_t*)(ws + 262144);    // 131072 ush
  // epoch 1 (pair path; dead after pair_kernel) [327680, 2794304)
  ushort_t* contP = (ushort_t*)(ws + 327680);    // 4718592 ush
  ushort_t* dcP   = (ushort_t*)(ws + 2686976);   // 98304 ush
  ushort_t* dcbP  = (ushort_t*)(ws + 2736128);   // 98304 ush
  ushort_t* EddP  = (ushort_t*)(ws + 2785280);   // 5760 ush
  ushort_t* ErsP  = (ushort_t*)(ws + 2788160);   // 3840 ush
  ushort_t* EhesP = (ushort_t*)(ws + 2790080);   // 3840 ush
  ushort_t* w1bf  = (ushort_t*)(ws + 2792000);   // 512 ush
  ushort_t* w2bf  = (ushort_t*)(ws + 2792256);   // 4096 ush
  // epoch 2 (attention/FFN; lives after pair) [327680, 3276800)
  ushort_t* xnb = (ushort_t*)(ws + 327680);      // 393216 ush
  ushort_t* qbB = (ushort_t*)(ws + 524288);
  ushort_t* kbB = (ushort_t*)(ws + 720896);
  ushort_t* vbT = (ushort_t*)(ws + 917504);
  ushort_t* aoB = (ushort_t*)(ws + 1114112);
  float* x1  = ws + 1310720;                     // 393216 f32
  float* hff = ws + 1703936;                     // 1572864 f32

  // 0) prep + pack (merged)
  prep_kernel<<<3062, 256, 0, stream>>>(dgk, ctk, Edg, Ec, cmb2, cmW1, cmb1,
      cmW2, Ed, Edi, Er, Eh, Ee, Esp, Es, Wq, Wk, Wv, Wo, ffW1, ffW2,
      dbk, drk, rpk, hdk, etk, spk, sck, pm, cont,
      dcP, dcbP, w1bf, w2bf, EddP, ErsP, EhesP,
      wqB, wkB, wvB, woB, ffW1B, ffW2B, contP);
  // 1) pair bias (MFMA, 4 tiles/wave, no-spill bound)
  pair_kernel<<<2304, 256, 0, stream>>>(contP, w1bf, w2bf, EddP, ErsP, EhesP,
      blng, blnb, bW, bb_, dcP, dcbP, biasO);
  // 2) ln1 -> xnb (bf16)
  ln_kernel<<<384, 256, 0, stream>>>(x, ln1g, ln1b, xnb);
  // 3) q, k, V^T projections (all-bf16)
  qkv_kernel<<<dim3(4, 24, 3), 256, 0, stream>>>(xnb, wqB, wkB, wvB,
      qbB, kbB, vbT);
  // 4) fused attention: QK^T + softmax + attn write + PV -> aoB
  attn_kernel<<<dim3(24, 16), 256, 0, stream>>>(qbB, kbB, vbT, biasO, pm, vld,
      attn, aoB);
  // 5) Wo + bo + residual(x) -> x1
  gemm2<0><<<dim3(4, 24), 256, 0, stream>>>(aoB, nullptr, 256, woB, 256,
      x1, 256, bo, x, 256, 256);
  // 6) ln2 -> xnb
  ln_kernel<<<384, 256, 0, stream>>>(x1, ln2g, ln2b, xnb);
  // 7) FF1 -> hff
  gemm2<0><<<dim3(16, 24), 256, 0, stream>>>(xnb, nullptr, 256, ffW1B, 256,
      hff, 1024, ffb1, nullptr, 0, 256);
  // 8) FF2 with fused gate + ffb2 + residual(x1) -> x_out
  gemm2<3><<<dim3(4, 24), 256, 0, stream>>>(nullptr, hff, 1024, ffW2B, 512,
      xout, 256, ffb2, x1, 256, 512);
}